// Round 4
// baseline (534.506 us; speedup 1.0000x reference)
//
#include <hip/hip_runtime.h>
#include <hip/hip_bf16.h>
#include <math.h>

typedef __attribute__((ext_vector_type(8))) short bf16x8;
typedef __attribute__((ext_vector_type(4))) float f32x4;

__device__ __forceinline__ float bf2f(ushort u) {
  union { uint i; float f; } t; t.i = ((uint)u) << 16; return t.f;
}
__device__ __forceinline__ ushort f2bf(float f) {
  __hip_bfloat16 h = __float2bfloat16(f);
  return *reinterpret_cast<ushort*>(&h);
}
__device__ __forceinline__ uint pk(float a, float b) {
  return (uint)f2bf(a) | ((uint)f2bf(b) << 16);
}
constexpr int ilog2c(int v) { int r = 0; while (v > 1) { v >>= 1; ++r; } return r; }

// =====================================================================
// Tiled MFMA conv, fused input-BN+LReLU, fused output batch-stats,
// co-split across blockIdx.y (CS) for occupancy.
// MODE 1: k4s2p1 encoder. MODE 2: up2+3x3 decoder (wave = parity class).
// SIG: fp32 NCHW sigmoid output (cd4, Co padded to 16, real 3).
// R4: WM/WN raised per layer so each weight load feeds >=4 MFMAs (ce3 was
// 1:1 and 95% stalled at MfmaUtil 4%); CS=1 removes duplicate weight traffic.
// =====================================================================
template<int MODE, int Ci, int Co, int HIN, int TR, int WM, int WN, int CS,
         bool BN, bool OSTAT, bool SIG>
__global__ __launch_bounds__(256) void tconv(const ushort* __restrict__ in,
    const ushort* __restrict__ wt, const float* __restrict__ bias,
    const float* __restrict__ st, const float* __restrict__ g,
    const float* __restrict__ bb, void* __restrict__ out_,
    float* __restrict__ stOut) {
  constexpr int W    = (MODE == 1) ? HIN / 2 : HIN;
  constexpr int LW   = ilog2c(W);
  constexpr int R_IN = (MODE == 1) ? 2 * TR + 2 : TR + 2;
  constexpr int W2   = HIN + 2;
  constexpr int MT   = TR * W / 16;
  constexpr int NG   = Co / 16;
  constexpr int NGB  = NG / CS;            // co groups per block
  constexpr int COB  = NGB * 16;           // channels per block
  constexpr int TAPS = (MODE == 1) ? 16 : 4;
  constexpr int RB   = W / TR;
  constexpr int CB   = BN ? Ci : 1;
  constexpr int SB   = OSTAT ? COB : 1;
  static_assert(TR * W % 16 == 0, "mtile");
  static_assert(MODE == 2 ? (WM == MT && WN == NGB)
                          : ((MT % WM == 0) && (NGB % WN == 0) &&
                             (MT / WM) * (NGB / WN) == 4),
                "wave map");

  __shared__ __align__(16) ushort lt[R_IN * W2 * 40];
  __shared__ float lsc[CB], lsh[CB];
  __shared__ float sst[SB], ssq[SB];

  const int tid  = threadIdx.x;
  const int wave = tid >> 6;
  const int ln15 = tid & 15;
  const int quad = (tid & 63) >> 4;
  const int rb = blockIdx.x % RB;
  const int n  = blockIdx.x / RB;
  const int h0 = rb * TR;
  const int cbase = blockIdx.y * NGB;      // co-group base for this block

  if (BN) {
    constexpr float inv_cnt = 1.0f / (float)(512 * HIN * HIN);
    for (int c = tid; c < Ci; c += 256) {
      float s = 0.f, q = 0.f;
#pragma unroll
      for (int sl = 0; sl < 8; ++sl) {
        s += st[sl * 2 * Ci + c];
        q += st[sl * 2 * Ci + Ci + c];
      }
      float m = s * inv_cnt;
      float var = fmaf(q, inv_cnt, -m * m);
      float sc = g[c] * rsqrtf(var + 1e-5f);
      lsc[c] = sc;
      lsh[c] = fmaf(-m, sc, bb[c]);
    }
  }

  int mt0, cg0, ph, pw, pb;
  if (MODE == 2) { mt0 = 0; cg0 = cbase; ph = wave >> 1; pw = wave & 1; pb = wave * 4; }
  else {
    constexpr int MW = MT / WM;
    mt0 = (wave % MW) * WM; cg0 = cbase + (wave / MW) * WN; ph = 0; pw = 0; pb = 0;
  }

  f32x4 acc[WM][WN];
#pragma unroll
  for (int j = 0; j < WN; ++j) {
    f32x4 b4 = *(const f32x4*)&bias[(cg0 + j) * 16 + quad * 4];
#pragma unroll
    for (int i = 0; i < WM; ++i) acc[i][j] = b4;
  }

  const uint4* src4 = (const uint4*)in;
  const int gr0 = (MODE == 1) ? 2 * h0 - 1 : h0 - 1;

#pragma unroll 1
  for (int c0 = 0; c0 < Ci; c0 += 32) {
    __syncthreads();
    constexpr int SN4 = R_IN * W2 * 4;     // 16B units (4 uint4 per pixel-chunk)
    for (int i = tid; i < SN4; i += 256) {
      int ciu4 = i & 3; int t2 = i >> 2; int c = t2 % W2; int r = t2 / W2;
      int gr = gr0 + r, gc = c - 1;
      uint4 v4 = make_uint4(0u, 0u, 0u, 0u);
      if ((unsigned)gr < (unsigned)HIN && (unsigned)gc < (unsigned)HIN) {
        v4 = src4[((size_t)(n * HIN + gr) * HIN + gc) * (Ci / 8) + (c0 >> 3) + ciu4];
        if (BN) {
          uint* pu = (uint*)&v4;
#pragma unroll
          for (int k2 = 0; k2 < 4; ++k2) {
            int cc = c0 + ciu4 * 8 + k2 * 2;
            float f0 = fmaf(bf2f((ushort)(pu[k2] & 0xffffu)), lsc[cc], lsh[cc]);
            float f1 = fmaf(bf2f((ushort)(pu[k2] >> 16)), lsc[cc + 1], lsh[cc + 1]);
            f0 = f0 > 0.f ? f0 : 0.01f * f0;
            f1 = f1 > 0.f ? f1 : 0.01f * f1;
            pu[k2] = pk(f0, f1);
          }
        }
      }
      *(uint4*)&((uint*)lt)[(r * W2 + c) * 20 + ciu4 * 4] = v4;
    }
    __syncthreads();

#pragma unroll
    for (int t = 0; t < TAPS; ++t) {
      const int kh = (MODE == 1) ? (t >> 2) : (t >> 1);
      const int kw = (MODE == 1) ? (t & 3) : (t & 1);
      bf16x8 af[WN];
      const ushort* wb = wt + (size_t)(pb + t) * Co * Ci;
#pragma unroll
      for (int j = 0; j < WN; ++j)
        af[j] = *(const bf16x8*)&wb[(size_t)((cg0 + j) * 16 + ln15) * Ci + c0 + quad * 8];
      bf16x8 bfr[WM];
#pragma unroll
      for (int i = 0; i < WM; ++i) {
        int m = (mt0 + i) * 16 + ln15;
        int hr = m >> LW, wr = m & (W - 1);
        int row, col;
        if (MODE == 1) { row = 2 * hr + kh; col = 2 * wr + kw; }
        else           { row = hr + kh + ph; col = wr + kw + pw; }
        bfr[i] = *(const bf16x8*)&lt[(row * W2 + col) * 40 + quad * 8];
      }
#pragma unroll
      for (int i = 0; i < WM; ++i)
#pragma unroll
        for (int j = 0; j < WN; ++j)
          acc[i][j] = __builtin_amdgcn_mfma_f32_16x16x32_bf16(af[j], bfr[i], acc[i][j], 0, 0, 0);
    }
  }

  if (OSTAT) {
    for (int c = tid; c < COB; c += 256) { sst[c] = 0.f; ssq[c] = 0.f; }
    __syncthreads();
  }

  if (SIG) {
    constexpr int HO2 = 2 * HIN;
    float* outF = (float*)out_;
#pragma unroll
    for (int i = 0; i < WM; ++i) {
      int m = (mt0 + i) * 16 + ln15;
      int hr = m >> LW, wr = m & (W - 1);
      int oh = 2 * (h0 + hr) + ph, ow = 2 * wr + pw;
      size_t base = (size_t)n * 3 * HO2 * HO2 + (size_t)oh * HO2 + ow;
#pragma unroll
      for (int r = 0; r < 4; ++r) {
        int co = quad * 4 + r;
        if (co < 3)
          outF[base + (size_t)co * HO2 * HO2] = 1.f / (1.f + __expf(-acc[i][0][r]));
      }
    }
  } else {
    ushort* out = (ushort*)out_;
#pragma unroll
    for (int i = 0; i < WM; ++i) {
      int m = (mt0 + i) * 16 + ln15;
      int hr = m >> LW, wr = m & (W - 1);
      size_t sp;
      if (MODE == 2) {
        int oh = 2 * (h0 + hr) + ph, ow = 2 * wr + pw;
        sp = ((size_t)n * (2 * HIN) + oh) * (2 * HIN) + ow;
      } else {
        sp = ((size_t)n * W + h0 + hr) * W + wr;
      }
#pragma unroll
      for (int j = 0; j < WN; ++j) {
        f32x4 a = acc[i][j];
        uint2 stv; stv.x = pk(a[0], a[1]); stv.y = pk(a[2], a[3]);
        *(uint2*)&out[sp * Co + (cg0 + j) * 16 + quad * 4] = stv;
      }
    }
  }

  if (OSTAT) {
#pragma unroll
    for (int j = 0; j < WN; ++j)
#pragma unroll
      for (int r = 0; r < 4; ++r) {
        float s = 0.f, q = 0.f;
#pragma unroll
        for (int i = 0; i < WM; ++i) {
          float v = acc[i][j][r];
          s += v; q = fmaf(v, v, q);
        }
#pragma unroll
        for (int mk = 1; mk < 16; mk <<= 1) {
          s += __shfl_xor(s, mk);
          q += __shfl_xor(q, mk);
        }
        if (ln15 == 0) {
          int lc = (cg0 + j) * 16 + quad * 4 + r - cbase * 16;
          atomicAdd(&sst[lc], s);
          atomicAdd(&ssq[lc], q);
        }
      }
    __syncthreads();
    float* d = stOut + (size_t)(blockIdx.x & 7) * 2 * Co;
    for (int c = tid; c < COB; c += 256) {
      atomicAdd(&d[cbase * 16 + c], sst[c]);
      atomicAdd(&d[Co + cbase * 16 + c], ssq[c]);
    }
  }
}

// ===================== 1x1 conv GEMM, fused input-BN + output stats ==========
template<int Ci, int Co, int COT, bool BN, int NPIX, bool OSTAT>
__global__ __launch_bounds__(256) void g1x1(const ushort* __restrict__ in,
    const ushort* __restrict__ wt, const float* __restrict__ bias,
    const float* __restrict__ st, const float* __restrict__ g,
    const float* __restrict__ bb, ushort* __restrict__ out,
    float* __restrict__ stOut) {
  constexpr int NG = COT / 16;
  constexpr int CB = BN ? Ci : 1;
  constexpr int SB = OSTAT ? COT : 1;
  __shared__ __align__(16) ushort lb[64 * 40];
  __shared__ float lsc[CB], lsh[CB];
  __shared__ float sst[SB], ssq[SB];
  const int tid = threadIdx.x, wave = tid >> 6, ln15 = tid & 15, quad = (tid & 63) >> 4;
  const int pixBase = blockIdx.x * 64;
  const int co0 = blockIdx.y * COT;
  if (BN) {
    constexpr float inv_cnt = 1.0f / (float)NPIX;
    for (int c = tid; c < Ci; c += 256) {
      float s = 0.f, q = 0.f;
#pragma unroll
      for (int sl = 0; sl < 8; ++sl) {
        s += st[sl * 2 * Ci + c];
        q += st[sl * 2 * Ci + Ci + c];
      }
      float m = s * inv_cnt;
      float var = fmaf(q, inv_cnt, -m * m);
      float sc = g[c] * rsqrtf(var + 1e-5f);
      lsc[c] = sc;
      lsh[c] = fmaf(-m, sc, bb[c]);
    }
  }
  f32x4 acc[NG];
#pragma unroll
  for (int j = 0; j < NG; ++j) acc[j] = *(const f32x4*)&bias[co0 + j * 16 + quad * 4];
  const uint4* src4 = (const uint4*)in;
#pragma unroll 1
  for (int c0 = 0; c0 < Ci; c0 += 32) {
    __syncthreads();
    {
      int ciu4 = tid & 3, pl = tid >> 2;
      uint4 v4 = src4[(size_t)(pixBase + pl) * (Ci / 8) + (c0 >> 3) + ciu4];
      if (BN) {
        uint* pu = (uint*)&v4;
#pragma unroll
        for (int k2 = 0; k2 < 4; ++k2) {
          int cc = c0 + ciu4 * 8 + k2 * 2;
          float f0 = fmaf(bf2f((ushort)(pu[k2] & 0xffffu)), lsc[cc], lsh[cc]);
          float f1 = fmaf(bf2f((ushort)(pu[k2] >> 16)), lsc[cc + 1], lsh[cc + 1]);
          f0 = f0 > 0.f ? f0 : 0.01f * f0;
          f1 = f1 > 0.f ? f1 : 0.01f * f1;
          pu[k2] = pk(f0, f1);
        }
      }
      *(uint4*)&((uint*)lb)[pl * 20 + ciu4 * 4] = v4;
    }
    __syncthreads();
    bf16x8 bfr = *(const bf16x8*)&lb[(wave * 16 + ln15) * 40 + quad * 8];
#pragma unroll
    for (int j = 0; j < NG; ++j) {
      bf16x8 af = *(const bf16x8*)&wt[(size_t)(co0 + j * 16 + ln15) * Ci + c0 + quad * 8];
      acc[j] = __builtin_amdgcn_mfma_f32_16x16x32_bf16(af, bfr, acc[j], 0, 0, 0);
    }
  }
  if (OSTAT) {
    for (int c = tid; c < COT; c += 256) { sst[c] = 0.f; ssq[c] = 0.f; }
    __syncthreads();
  }
  int pix = pixBase + wave * 16 + ln15;
#pragma unroll
  for (int j = 0; j < NG; ++j) {
    uint2 stv; stv.x = pk(acc[j][0], acc[j][1]); stv.y = pk(acc[j][2], acc[j][3]);
    *(uint2*)&out[(size_t)pix * Co + co0 + j * 16 + quad * 4] = stv;
  }
  if (OSTAT) {
#pragma unroll
    for (int j = 0; j < NG; ++j)
#pragma unroll
      for (int r = 0; r < 4; ++r) {
        float s = acc[j][r];
        float q = s * s;
#pragma unroll
        for (int mk = 1; mk < 16; mk <<= 1) {
          s += __shfl_xor(s, mk);
          q += __shfl_xor(q, mk);
        }
        if (ln15 == 0) {
          int cl = j * 16 + quad * 4 + r;
          atomicAdd(&sst[cl], s);
          atomicAdd(&ssq[cl], q);
        }
      }
    __syncthreads();
    float* d = stOut + (size_t)(blockIdx.x & 7) * 2 * Co;
    for (int c = tid; c < COT; c += 256) {
      atomicAdd(&d[co0 + c], sst[c]);
      atomicAdd(&d[Co + co0 + c], ssq[c]);
    }
  }
}

// ===================== ce1 (MFMA): k4s2p1, Ci=3, fp32 NCHW -> bf16 NHWC + stats ===
__global__ __launch_bounds__(256) void ce1_mfma(const float* __restrict__ x,
    const ushort* __restrict__ wt, const float* __restrict__ bias,
    ushort* __restrict__ out, float* __restrict__ stOut) {
  __shared__ __align__(16) float lt[3 * 18 * 72];   // padded fp32 tile, 15.2 KB
  __shared__ float sst[32], ssq[32];
  const int tid = threadIdx.x, wave = tid >> 6, ln15 = tid & 15, quad = (tid & 63) >> 4;
  const int pixBase = blockIdx.x * 256;     // 8 out rows x 32 cols, one image
  const int n  = pixBase >> 10;
  const int h0 = (pixBase >> 5) & 31;
  if (tid < 32) { sst[tid] = 0.f; ssq[tid] = 0.f; }
  const int gr0 = 2 * h0 - 1;
  for (int i = tid; i < 3 * 18 * 72; i += 256) {
    int c = i % 72; int rem = i / 72; int r = rem % 18; int ci = rem / 18;
    int gr = gr0 + r, gc = c - 1;
    float v = 0.f;
    if ((unsigned)gr < 64u && (unsigned)gc < 64u)
      v = x[(((size_t)n * 3 + ci) << 12) + (gr << 6) + gc];
    lt[i] = v;
  }
  __syncthreads();

  f32x4 acc[4][2];
#pragma unroll
  for (int j = 0; j < 2; ++j) {
    f32x4 b4 = *(const f32x4*)&bias[j * 16 + quad * 4];
#pragma unroll
    for (int i = 0; i < 4; ++i) acc[i][j] = b4;
  }
  bf16x8 af[2][2];
#pragma unroll
  for (int j = 0; j < 2; ++j)
#pragma unroll
    for (int kk = 0; kk < 2; ++kk)
      af[j][kk] = *(const bf16x8*)&wt[(j * 16 + ln15) * 64 + kk * 32 + quad * 8];

  const int mt0 = wave * 4;
#pragma unroll
  for (int i = 0; i < 4; ++i) {
    int p = (mt0 + i) * 16 + ln15;        // px within block
    int h = p >> 5, w = p & 31;           // local out row/col
#pragma unroll
    for (int kk = 0; kk < 2; ++kk) {
      int k0 = kk * 32 + quad * 8;        // k = (ci*16 + kh*4 + kw)
      bf16x8 bfr = (bf16x8)(short)0;
      if (k0 < 48) {
        int ci = k0 >> 4, kh0 = (k0 >> 2) & 3;   // 8 k's = 2 rows x 4 kw
        const float* rp = &lt[(ci * 18 + 2 * h + kh0) * 72 + 2 * w];
        uint4 uu = make_uint4(pk(rp[0], rp[1]), pk(rp[2], rp[3]),
                              pk(rp[72], rp[73]), pk(rp[74], rp[75]));
        bfr = *reinterpret_cast<bf16x8*>(&uu);
      }
#pragma unroll
      for (int j = 0; j < 2; ++j)
        acc[i][j] = __builtin_amdgcn_mfma_f32_16x16x32_bf16(af[j][kk], bfr, acc[i][j], 0, 0, 0);
    }
  }
  // ---- store bf16 NHWC [px][32] ----
#pragma unroll
  for (int i = 0; i < 4; ++i) {
    int sp = pixBase + (mt0 + i) * 16 + ln15;
#pragma unroll
    for (int j = 0; j < 2; ++j) {
      f32x4 a = acc[i][j];
      uint2 stv; stv.x = pk(a[0], a[1]); stv.y = pk(a[2], a[3]);
      *(uint2*)&out[(size_t)sp * 32 + j * 16 + quad * 4] = stv;
    }
  }
  // ---- fused batch stats (16-lane reduce like tconv OSTAT) ----
#pragma unroll
  for (int j = 0; j < 2; ++j)
#pragma unroll
    for (int r = 0; r < 4; ++r) {
      float s = 0.f, q = 0.f;
#pragma unroll
      for (int i = 0; i < 4; ++i) {
        float v = acc[i][j][r];
        s += v; q = fmaf(v, v, q);
      }
#pragma unroll
      for (int mk = 1; mk < 16; mk <<= 1) {
        s += __shfl_xor(s, mk);
        q += __shfl_xor(q, mk);
      }
      if (ln15 == 0) {
        int ch = j * 16 + quad * 4 + r;
        atomicAdd(&sst[ch], s);
        atomicAdd(&ssq[ch], q);
      }
    }
  __syncthreads();
  if (tid < 32) {
    float* d = stOut + (size_t)(blockIdx.x & 7) * 64;
    atomicAdd(&d[tid], sst[tid]);
    atomicAdd(&d[32 + tid], ssq[tid]);
  }
}

// ===================== prep: ALL weight transforms + codebook, one dispatch ======
__device__ __forceinline__ void enc_tr(const float* __restrict__ w,
    ushort* __restrict__ o, int Co, int Ci, int idx) {
  int ci = idx % Ci; int r = idx / Ci; int co = r % Co; int t = r / Co;
  o[idx] = f2bf(w[(co * Ci + ci) * 16 + t]);
}
__device__ __forceinline__ float dec_comb(const float* __restrict__ w,
    int Ci, int co, int ci, int pt) {
  int p = pt >> 2, t = pt & 3;
  int ph = p >> 1, pw = p & 1, rr = t >> 1, cc = t & 1;
  int rs = (rr == 0) ? 0 : (ph == 0 ? 1 : 2);
  int re = (rr == 0) ? (ph == 0 ? 1 : 2) : 3;
  int cs = (cc == 0) ? 0 : (pw == 0 ? 1 : 2);
  int ce = (cc == 0) ? (pw == 0 ? 1 : 2) : 3;
  float s = 0.f;
  for (int kh = rs; kh < re; ++kh)
    for (int kw = cs; kw < ce; ++kw)
      s += w[((co * Ci + ci) * 3 + kh) * 3 + kw];
  return s;
}
__device__ __forceinline__ void dec_tr(const float* __restrict__ w,
    ushort* __restrict__ o, int Co, int Ci, int idx) {
  int ci = idx % Ci; int r = idx / Ci; int co = r % Co; int pt = r / Co;
  o[idx] = f2bf(dec_comb(w, Ci, co, ci, pt));
}

__global__ __launch_bounds__(256) void prep_all(
    const float* __restrict__ ce1_w,
    const float* __restrict__ ce2_w, const float* __restrict__ ce3_w,
    const float* __restrict__ ce4_w, const float* __restrict__ ce5_w,
    const float* __restrict__ cd0_w, const float* __restrict__ cd1_w,
    const float* __restrict__ cd2_w, const float* __restrict__ cd3_w,
    const float* __restrict__ cd4_w, const float* __restrict__ cd4_b,
    const float* __restrict__ codebook,
    ushort* __restrict__ wce1b,
    ushort* __restrict__ wce2, ushort* __restrict__ wce3, ushort* __restrict__ wce4,
    ushort* __restrict__ wce5, ushort* __restrict__ wcd0, ushort* __restrict__ wcd1,
    ushort* __restrict__ wcd2, ushort* __restrict__ wcd3, ushort* __restrict__ wcd4,
    float* __restrict__ cd4bp, ushort* __restrict__ cbbf, float* __restrict__ wsq) {
  __shared__ float sh[4];
  int bx = blockIdx.x, tid = threadIdx.x;
  if (bx < 2048) { int i = bx * 256 + tid; cbbf[i] = f2bf(codebook[i]); return; }
  bx -= 2048;
  if (bx < 512) {
    int k = bx;
    float s = 0.f;
    for (int d = tid; d < 1024; d += 256) {
      float v = codebook[k * 1024 + d];
      s = fmaf(v, v, s);
    }
#pragma unroll
    for (int o = 32; o > 0; o >>= 1) s += __shfl_down(s, o);
    if ((tid & 63) == 0) sh[tid >> 6] = s;
    __syncthreads();
    if (tid == 0) wsq[k] = sh[0] + sh[1] + sh[2] + sh[3];
    return;
  }
  bx -= 512;
  if (bx < 2048) { enc_tr(ce4_w, wce4, 256, 128, bx * 256 + tid); return; }
  bx -= 2048;
  if (bx < 2048) { dec_tr(cd1_w, wcd1, 128, 256, bx * 256 + tid); return; }
  bx -= 2048;
  if (bx < 512)  { enc_tr(ce3_w, wce3, 128, 64, bx * 256 + tid); return; }
  bx -= 512;
  if (bx < 512)  { dec_tr(cd2_w, wcd2, 64, 128, bx * 256 + tid); return; }
  bx -= 512;
  if (bx < 128)  { enc_tr(ce2_w, wce2, 64, 32, bx * 256 + tid); return; }
  bx -= 128;
  if (bx < 128)  { dec_tr(cd3_w, wcd3, 32, 64, bx * 256 + tid); return; }
  bx -= 128;
  if (bx < 64)   { int i = bx * 256 + tid; wce5[i] = f2bf(ce5_w[i]); return; }
  bx -= 64;
  if (bx < 64)   { int i = bx * 256 + tid; wcd0[i] = f2bf(cd0_w[i]); return; }
  bx -= 64;
  if (bx < 32) {                // cd4 padded: [16 taps][16 co][32 ci]
    int idx = bx * 256 + tid;   // 32 blocks
    int ci = idx & 31; int r = idx >> 5; int co = r & 15; int pt = r >> 4;
    wcd4[idx] = (co < 3) ? f2bf(dec_comb(cd4_w, 32, co, ci, pt)) : (ushort)0;
    if (bx == 0 && tid < 16) cd4bp[tid] = (tid < 3) ? cd4_b[tid] : 0.f;
    return;
  }
  bx -= 32;
  {                             // ce1 bf16 weights: [32 co][64 k], k>=48 zero; 8 blocks
    int idx = bx * 256 + tid;   // 0..2047
    int k = idx & 63, co = idx >> 6;
    wce1b[idx] = (k < 48) ? f2bf(ce1_w[co * 48 + k]) : (ushort)0;
  }
}

// ===================== VQ ==========
__global__ __launch_bounds__(256) void zprep(const ushort* __restrict__ r5,
    const float* __restrict__ st, const float* __restrict__ g,
    const float* __restrict__ bb, float* __restrict__ Z, ushort* __restrict__ Zbf) {
  __shared__ float lsc[64], lsh[64];
  int tid = threadIdx.x;
  if (tid < 64) {
    float s = 0.f, q = 0.f;
#pragma unroll
    for (int sl = 0; sl < 8; ++sl) { s += st[sl * 128 + tid]; q += st[sl * 128 + 64 + tid]; }
    float m = s * (1.0f / 8192.f);
    float var = fmaf(q, 1.0f / 8192.f, -m * m);
    float sc = g[tid] * rsqrtf(var + 1e-5f);
    lsc[tid] = sc;
    lsh[tid] = fmaf(-m, sc, bb[tid]);
  }
  __syncthreads();
  int i = blockIdx.x * 256 + tid;
  int c = i & 63;
  float f = fmaf(bf2f(r5[i]), lsc[c], lsh[c]);
  f = f > 0.f ? f : 0.01f * f;
  Z[i] = f;
  Zbf[i] = f2bf(f);
}

// S_ks[b][k] partial dot over K-slice ks (4 slices). Grid (8,8,4).
__global__ __launch_bounds__(256) void vq_gemm(const ushort* __restrict__ Zbf,
    const ushort* __restrict__ cbbf, float* __restrict__ S) {
  __shared__ __align__(16) ushort lZ[64 * 40], lW[64 * 40];
  const int tid = threadIdx.x, wave = tid >> 6, ln15 = tid & 15, quad = (tid & 63) >> 4;
  const int b0 = blockIdx.x * 64, k0 = blockIdx.y * 64, ks = blockIdx.z;
  f32x4 acc[4];
#pragma unroll
  for (int j = 0; j < 4; ++j) acc[j] = (f32x4)(0.f);
  const uint4* zs = (const uint4*)Zbf;
  const uint4* ws = (const uint4*)cbbf;
#pragma unroll 1
  for (int c0 = ks * 256; c0 < ks * 256 + 256; c0 += 32) {
    __syncthreads();
    for (int i = tid; i < 512; i += 256) {
      int ciu4 = i & 3; int rl = (i >> 2) & 63; bool isW = i >= 256;
      uint4 v = (isW ? ws : zs)[(size_t)((isW ? k0 : b0) + rl) * 128 + (c0 >> 3) + ciu4];
      *(uint4*)&((uint*)(isW ? lW : lZ))[rl * 20 + ciu4 * 4] = v;
    }
    __syncthreads();
    bf16x8 bfr = *(const bf16x8*)&lZ[(wave * 16 + ln15) * 40 + quad * 8];
#pragma unroll
    for (int j = 0; j < 4; ++j) {
      bf16x8 af = *(const bf16x8*)&lW[(j * 16 + ln15) * 40 + quad * 8];
      acc[j] = __builtin_amdgcn_mfma_f32_16x16x32_bf16(af, bfr, acc[j], 0, 0, 0);
    }
  }
  int b = b0 + wave * 16 + ln15;
  float* Sk = S + (size_t)ks * 262144;
#pragma unroll
  for (int j = 0; j < 4; ++j)
    *(f32x4*)&Sk[(size_t)b * 512 + k0 + j * 16 + quad * 4] = acc[j];
}

// fused: argmin scan + gather Zq + exact fp32 loss + last-block writes losses
__global__ __launch_bounds__(256) void vq_post(const float* __restrict__ S,
    const float* __restrict__ wsq, const float* __restrict__ Z,
    const float* __restrict__ cb, ushort* __restrict__ Zq,
    float* __restrict__ lossAcc, int* __restrict__ cnt, float* __restrict__ out2) {
  int b = blockIdx.x, tid = threadIdx.x;
  float s1 = 0.f, s2 = 0.f;
#pragma unroll
  for (int sl = 0; sl < 4; ++sl) {
    s1 += S[(size_t)sl * 262144 + (size_t)b * 512 + tid];
    s2 += S[(size_t)sl * 262144 + (size_t)b * 512 + tid + 256];
  }
  float d1 = fmaf(-2.f, s1, wsq[tid]);
  float d2 = fmaf(-2.f, s2, wsq[tid + 256]);
  float bv = d1; int bk = tid;
  if (d2 < bv) { bv = d2; bk = tid + 256; }
  __shared__ float vsh[256]; __shared__ int ish[256];
  vsh[tid] = bv; ish[tid] = bk;
  __syncthreads();
  for (int s = 128; s > 0; s >>= 1) {
    if (tid < s) {
      float ov = vsh[tid + s]; int oi = ish[tid + s];
      if (ov < vsh[tid] || (ov == vsh[tid] && oi < ish[tid])) { vsh[tid] = ov; ish[tid] = oi; }
    }
    __syncthreads();
  }
  int k = ish[0];
  const float* w = cb + ((long)k << 10);
  const float* zp = Z + ((long)b << 10);
  float part = 0.f;
  for (int d = tid; d < 1024; d += 256) {
    float wv = w[d];
    float diff = zp[d] - wv;
    part = fmaf(diff, diff, part);
    Zq[(b << 10) + d] = f2bf(wv);
  }
#pragma unroll
  for (int o = 32; o > 0; o >>= 1) part += __shfl_down(part, o);
  __shared__ float sh[4];
  if ((tid & 63) == 0) sh[tid >> 6] = part;
  __syncthreads();
  if (tid == 0) {
    atomicAdd(lossAcc, sh[0] + sh[1] + sh[2] + sh[3]);
    __threadfence();
    int old = atomicAdd(cnt, 1);
    if (old == 511) {
      float v = *(volatile float*)lossAcc * (1.0f / 512.0f);
      out2[0] = v;
      out2[1] = v;
    }
  }
}

// ===================== launch ==========
extern "C" void kernel_launch(void* const* d_in, const int* in_sizes, int n_in,
                              void* d_out, int out_size, void* d_ws, size_t ws_size,
                              hipStream_t stream) {
  const float* x      = (const float*)d_in[0];
  const float* ce1_w  = (const float*)d_in[1];  const float* ce1_b = (const float*)d_in[2];
  const float* ce2_w  = (const float*)d_in[3];  const float* ce2_b = (const float*)d_in[4];
  const float* ce3_w  = (const float*)d_in[5];  const float* ce3_b = (const float*)d_in[6];
  const float* ce4_w  = (const float*)d_in[7];  const float* ce4_b = (const float*)d_in[8];
  const float* ce5_w  = (const float*)d_in[9];  const float* ce5_b = (const float*)d_in[10];
  const float* cd0_w  = (const float*)d_in[11]; const float* cd0_b = (const float*)d_in[12];
  const float* cd1_w  = (const float*)d_in[13]; const float* cd1_b = (const float*)d_in[14];
  const float* cd2_w  = (const float*)d_in[15]; const float* cd2_b = (const float*)d_in[16];
  const float* cd3_w  = (const float*)d_in[17]; const float* cd3_b = (const float*)d_in[18];
  const float* cd4_w  = (const float*)d_in[19]; const float* cd4_b = (const float*)d_in[20];
  const float* bn_e1_g = (const float*)d_in[21]; const float* bn_e1_b = (const float*)d_in[22];
  const float* bn_e2_g = (const float*)d_in[23]; const float* bn_e2_b = (const float*)d_in[24];
  const float* bn_e3_g = (const float*)d_in[25]; const float* bn_e3_b = (const float*)d_in[26];
  const float* bn_e4_g = (const float*)d_in[27]; const float* bn_e4_b = (const float*)d_in[28];
  const float* bn_e5_g = (const float*)d_in[29]; const float* bn_e5_b = (const float*)d_in[30];
  const float* bn_d0_g = (const float*)d_in[31]; const float* bn_d0_b = (const float*)d_in[32];
  const float* bn_d1_g = (const float*)d_in[33]; const float* bn_d1_b = (const float*)d_in[34];
  const float* bn_d2_g = (const float*)d_in[35]; const float* bn_d2_b = (const float*)d_in[36];
  const float* bn_d3_g = (const float*)d_in[37]; const float* bn_d3_b = (const float*)d_in[38];
  const float* codebook = (const float*)d_in[39];

  float* out = (float*)d_out;

  // ---- workspace carve ----
  char* p = (char*)d_ws;
  auto alloc = [&](size_t bytes) { void* r = p; p += (bytes + 255) & ~(size_t)255; return r; };
  ushort* r1 = (ushort*)alloc((size_t)524288 * 32 * 2);
  ushort* r2 = (ushort*)alloc((size_t)131072 * 64 * 2);
  ushort* r3 = (ushort*)alloc((size_t)32768 * 128 * 2);
  ushort* r4 = (ushort*)alloc((size_t)8192 * 256 * 2);
  ushort* r5 = (ushort*)alloc((size_t)8192 * 64 * 2);
  ushort* d0 = (ushort*)alloc((size_t)8192 * 256 * 2);
  ushort* d1 = (ushort*)alloc((size_t)32768 * 128 * 2);
  ushort* d2 = (ushort*)alloc((size_t)131072 * 64 * 2);
  ushort* d3 = (ushort*)alloc((size_t)524288 * 32 * 2);
  float*  Z    = (float*)alloc((size_t)524288 * 4);
  ushort* Zbf  = (ushort*)alloc((size_t)524288 * 2);
  ushort* cbbf = (ushort*)alloc((size_t)524288 * 2);
  float*  S    = (float*)alloc((size_t)4 * 262144 * 4);   // 4 K-slices
  ushort* Zq   = (ushort*)alloc((size_t)524288 * 2);
  float*  wsq  = (float*)alloc((size_t)512 * 4);
  ushort* wce2 = (ushort*)alloc((size_t)16 * 64 * 32 * 2);
  ushort* wce3 = (ushort*)alloc((size_t)16 * 128 * 64 * 2);
  ushort* wce4 = (ushort*)alloc((size_t)16 * 256 * 128 * 2);
  ushort* wce5 = (ushort*)alloc((size_t)64 * 256 * 2);
  ushort* wcd0 = (ushort*)alloc((size_t)256 * 64 * 2);
  ushort* wcd1 = (ushort*)alloc((size_t)16 * 128 * 256 * 2);
  ushort* wcd2 = (ushort*)alloc((size_t)16 * 64 * 128 * 2);
  ushort* wcd3 = (ushort*)alloc((size_t)16 * 32 * 64 * 2);
  ushort* wcd4 = (ushort*)alloc((size_t)16 * 16 * 32 * 2);
  ushort* wce1b = (ushort*)alloc((size_t)32 * 64 * 2);
  float*  cd4bp = (float*)alloc(64);
  float*  statsAll = (float*)alloc((size_t)(9 * 4096 + 64) * 4);
  int*    jbuf = (int*)alloc((size_t)512 * 4);

  float* st_e1 = statsAll + 0 * 4096;
  float* st_e2 = statsAll + 1 * 4096;
  float* st_e3 = statsAll + 2 * 4096;
  float* st_e4 = statsAll + 3 * 4096;
  float* st_e5 = statsAll + 4 * 4096;
  float* st_d0 = statsAll + 5 * 4096;
  float* st_d1 = statsAll + 6 * 4096;
  float* st_d2 = statsAll + 7 * 4096;
  float* st_d3 = statsAll + 8 * 4096;
  float* lossAcc = statsAll + 9 * 4096;
  int*   cnt = (int*)(lossAcc + 1);

  hipMemsetAsync(statsAll, 0, (size_t)(9 * 4096 + 64) * 4, stream);

  prep_all<<<8104, 256, 0, stream>>>(ce1_w, ce2_w, ce3_w, ce4_w, ce5_w, cd0_w, cd1_w,
      cd2_w, cd3_w, cd4_w, cd4_b, codebook,
      wce1b, wce2, wce3, wce4, wce5, wcd0, wcd1, wcd2, wcd3, wcd4, cd4bp, cbbf, wsq);

  // ---- encoder ----
  ce1_mfma<<<2048, 256, 0, stream>>>(x, wce1b, ce1_b, r1, st_e1);
  // ce2: TR=8, WM=4 (4 MFMA per weight load), grid 1024
  tconv<1, 32, 64, 32, 8, 4, 2, 1, true, true, false><<<dim3(1024, 1), 256, 0, stream>>>(
      r1, wce2, ce2_b, st_e1, bn_e1_g, bn_e1_b, r2, st_e2);
  // ce3: whole-image tile TR=8, WM=4, CS=1, grid 512 (was 78.8us @ MfmaUtil 4%)
  tconv<1, 64, 128, 16, 8, 4, 2, 1, true, true, false><<<dim3(512, 1), 256, 0, stream>>>(
      r2, wce3, ce3_b, st_e2, bn_e2_g, bn_e2_b, r3, st_e3);
  // ce4: WN=4, CS=1, grid 512
  tconv<1, 128, 256, 8, 4, 1, 4, 1, true, true, false><<<dim3(512, 1), 256, 0, stream>>>(
      r3, wce4, ce4_b, st_e3, bn_e3_g, bn_e3_b, r4, st_e4);
  g1x1<256, 64, 16, true, 8192, true><<<dim3(128, 4), 256, 0, stream>>>(
      r4, wce5, ce5_b, st_e4, bn_e4_g, bn_e4_b, r5, st_e5);

  // ---- VQ ----
  zprep<<<2048, 256, 0, stream>>>(r5, st_e5, bn_e5_g, bn_e5_b, Z, Zbf);
  vq_gemm<<<dim3(8, 8, 4), 256, 0, stream>>>(Zbf, cbbf, S);
  vq_post<<<512, 256, 0, stream>>>(S, wsq, Z, codebook, Zq, lossAcc, cnt, out + 6291456);

  // ---- decoder ----
  g1x1<64, 256, 32, false, 1, true><<<dim3(128, 8), 256, 0, stream>>>(
      Zq, wcd0, cd0_b, nullptr, nullptr, nullptr, d0, st_d0);
  // cd1: WN=8, CS=1, grid 512
  tconv<2, 256, 128, 4, 4, 1, 8, 1, true, true, false><<<dim3(512, 1), 256, 0, stream>>>(
      d0, wcd1, cd1_b, st_d0, bn_d0_g, bn_d0_b, d1, st_d1);
  // cd2: WN=4, CS=1, grid 512
  tconv<2, 128, 64, 8, 8, 4, 4, 1, true, true, false><<<dim3(512, 1), 256, 0, stream>>>(
      d1, wcd2, cd2_b, st_d1, bn_d1_g, bn_d1_b, d2, st_d2);
  tconv<2, 64, 32, 16, 8, 8, 2, 1, true, true, false><<<dim3(1024, 1), 256, 0, stream>>>(
      d2, wcd3, cd3_b, st_d2, bn_d2_g, bn_d2_b, d3, st_d3);
  tconv<2, 32, 16, 32, 4, 8, 1, 1, true, false, true><<<dim3(4096, 1), 256, 0, stream>>>(
      d3, wcd4, cd4bp, st_d3, bn_d3_g, bn_d3_b, out, nullptr);
}

// Round 5
// 463.168 us; speedup vs baseline: 1.1540x; 1.1540x over previous
//
#include <hip/hip_runtime.h>
#include <hip/hip_bf16.h>
#include <math.h>

typedef __attribute__((ext_vector_type(8))) short bf16x8;
typedef __attribute__((ext_vector_type(4))) float f32x4;

__device__ __forceinline__ float bf2f(ushort u) {
  union { uint i; float f; } t; t.i = ((uint)u) << 16; return t.f;
}
__device__ __forceinline__ ushort f2bf(float f) {
  __hip_bfloat16 h = __float2bfloat16(f);
  return *reinterpret_cast<ushort*>(&h);
}
__device__ __forceinline__ uint pk(float a, float b) {
  return (uint)f2bf(a) | ((uint)f2bf(b) << 16);
}
constexpr int ilog2c(int v) { int r = 0; while (v > 1) { v >>= 1; ++r; } return r; }

// =====================================================================
// Tiled MFMA conv, fused input-BN+LReLU, fused output batch-stats,
// co-split across blockIdx.y (CS) for occupancy.
// MODE 1: k4s2p1 encoder. MODE 2: up2+3x3 decoder (wave = parity class).
// NB: images per block (MODE 2): raises WM so each weight load feeds WM
// MFMAs (cd1 has 1 M-tile/image; NB=1 gave 1:1 load:MFMA at VGPR=56 ->
// serialized vmcnt waits, 83us). SIG: fp32 NCHW sigmoid output (cd4).
// =====================================================================
template<int MODE, int Ci, int Co, int HIN, int TR, int WM, int WN, int CS,
         int NB, bool BN, bool OSTAT, bool SIG>
__global__ __launch_bounds__(256) void tconv(const ushort* __restrict__ in,
    const ushort* __restrict__ wt, const float* __restrict__ bias,
    const float* __restrict__ st, const float* __restrict__ g,
    const float* __restrict__ bb, void* __restrict__ out_,
    float* __restrict__ stOut) {
  constexpr int W    = (MODE == 1) ? HIN / 2 : HIN;
  constexpr int LW   = ilog2c(W);
  constexpr int R_IN = (MODE == 1) ? 2 * TR + 2 : TR + 2;
  constexpr int W2   = HIN + 2;
  constexpr int MTPI = TR * W / 16;        // M-tiles per image
  constexpr int MT   = NB * MTPI;          // M-tiles per block
  constexpr int NG   = Co / 16;
  constexpr int NGB  = NG / CS;            // co groups per block
  constexpr int COB  = NGB * 16;           // channels per block
  constexpr int TAPS = (MODE == 1) ? 16 : 4;
  constexpr int RB   = W / TR;
  constexpr int CB   = BN ? Ci : 1;
  constexpr int SB   = OSTAT ? COB : 1;
  constexpr int SN4P = R_IN * W2 * 4;      // 16B staging units per image
  static_assert(TR * W % 16 == 0, "mtile");
  static_assert(MODE == 1 ? NB == 1 : true, "NB only for MODE 2");
  static_assert(MODE == 2 ? (WM == MT && WN == NGB)
                          : ((MT % WM == 0) && (NGB % WN == 0) &&
                             (MT / WM) * (NGB / WN) == 4),
                "wave map");

  __shared__ __align__(16) ushort lt[NB * R_IN * W2 * 40];
  __shared__ float lsc[CB], lsh[CB];
  __shared__ float sst[SB], ssq[SB];

  const int tid  = threadIdx.x;
  const int wave = tid >> 6;
  const int ln15 = tid & 15;
  const int quad = (tid & 63) >> 4;
  const int rb = blockIdx.x % RB;
  const int n0 = (blockIdx.x / RB) * NB;
  const int h0 = rb * TR;
  const int cbase = blockIdx.y * NGB;      // co-group base for this block

  if (BN) {
    constexpr float inv_cnt = 1.0f / (float)(512 * HIN * HIN);
    for (int c = tid; c < Ci; c += 256) {
      float s = 0.f, q = 0.f;
#pragma unroll
      for (int sl = 0; sl < 8; ++sl) {
        s += st[sl * 2 * Ci + c];
        q += st[sl * 2 * Ci + Ci + c];
      }
      float m = s * inv_cnt;
      float var = fmaf(q, inv_cnt, -m * m);
      float sc = g[c] * rsqrtf(var + 1e-5f);
      lsc[c] = sc;
      lsh[c] = fmaf(-m, sc, bb[c]);
    }
  }

  int mt0, cg0, ph, pw, pb;
  if (MODE == 2) { mt0 = 0; cg0 = cbase; ph = wave >> 1; pw = wave & 1; pb = wave * 4; }
  else {
    constexpr int MW = MT / WM;
    mt0 = (wave % MW) * WM; cg0 = cbase + (wave / MW) * WN; ph = 0; pw = 0; pb = 0;
  }

  f32x4 acc[WM][WN];
#pragma unroll
  for (int j = 0; j < WN; ++j) {
    f32x4 b4 = *(const f32x4*)&bias[(cg0 + j) * 16 + quad * 4];
#pragma unroll
    for (int i = 0; i < WM; ++i) acc[i][j] = b4;
  }

  const uint4* src4 = (const uint4*)in;
  const int gr0 = (MODE == 1) ? 2 * h0 - 1 : h0 - 1;

#pragma unroll 1
  for (int c0 = 0; c0 < Ci; c0 += 32) {
    __syncthreads();
    for (int i = tid; i < NB * SN4P; i += 256) {
      int img = (NB == 1) ? 0 : (i / SN4P);
      int ii  = (NB == 1) ? i : (i % SN4P);
      int ciu4 = ii & 3; int t2 = ii >> 2; int c = t2 % W2; int r = t2 / W2;
      int gr = gr0 + r, gc = c - 1;
      uint4 v4 = make_uint4(0u, 0u, 0u, 0u);
      if ((unsigned)gr < (unsigned)HIN && (unsigned)gc < (unsigned)HIN) {
        v4 = src4[((size_t)((n0 + img) * HIN + gr) * HIN + gc) * (Ci / 8) + (c0 >> 3) + ciu4];
        if (BN) {
          uint* pu = (uint*)&v4;
#pragma unroll
          for (int k2 = 0; k2 < 4; ++k2) {
            int cc = c0 + ciu4 * 8 + k2 * 2;
            float f0 = fmaf(bf2f((ushort)(pu[k2] & 0xffffu)), lsc[cc], lsh[cc]);
            float f1 = fmaf(bf2f((ushort)(pu[k2] >> 16)), lsc[cc + 1], lsh[cc + 1]);
            f0 = f0 > 0.f ? f0 : 0.01f * f0;
            f1 = f1 > 0.f ? f1 : 0.01f * f1;
            pu[k2] = pk(f0, f1);
          }
        }
      }
      *(uint4*)&((uint*)lt)[((img * R_IN + r) * W2 + c) * 20 + ciu4 * 4] = v4;
    }
    __syncthreads();

#pragma unroll
    for (int t = 0; t < TAPS; ++t) {
      const int kh = (MODE == 1) ? (t >> 2) : (t >> 1);
      const int kw = (MODE == 1) ? (t & 3) : (t & 1);
      bf16x8 af[WN];
      const ushort* wb = wt + (size_t)(pb + t) * Co * Ci;
#pragma unroll
      for (int j = 0; j < WN; ++j)
        af[j] = *(const bf16x8*)&wb[(size_t)((cg0 + j) * 16 + ln15) * Ci + c0 + quad * 8];
      bf16x8 bfr[WM];
#pragma unroll
      for (int i = 0; i < WM; ++i) {
        int mtile = mt0 + i;
        int img = (NB == 1) ? 0 : (mtile / MTPI);
        int lm  = (NB == 1) ? mtile : (mtile % MTPI);
        int m = lm * 16 + ln15;
        int hr = m >> LW, wr = m & (W - 1);
        int row, col;
        if (MODE == 1) { row = 2 * hr + kh; col = 2 * wr + kw; }
        else           { row = hr + kh + ph; col = wr + kw + pw; }
        bfr[i] = *(const bf16x8*)&lt[((img * R_IN + row) * W2 + col) * 40 + quad * 8];
      }
#pragma unroll
      for (int i = 0; i < WM; ++i)
#pragma unroll
        for (int j = 0; j < WN; ++j)
          acc[i][j] = __builtin_amdgcn_mfma_f32_16x16x32_bf16(af[j], bfr[i], acc[i][j], 0, 0, 0);
    }
  }

  if (OSTAT) {
    for (int c = tid; c < COB; c += 256) { sst[c] = 0.f; ssq[c] = 0.f; }
    __syncthreads();
  }

  if (SIG) {
    constexpr int HO2 = 2 * HIN;
    float* outF = (float*)out_;
#pragma unroll
    for (int i = 0; i < WM; ++i) {
      int mtile = mt0 + i;
      int img = (NB == 1) ? 0 : (mtile / MTPI);
      int lm  = (NB == 1) ? mtile : (mtile % MTPI);
      int m = lm * 16 + ln15;
      int hr = m >> LW, wr = m & (W - 1);
      int oh = 2 * (h0 + hr) + ph, ow = 2 * wr + pw;
      size_t base = (size_t)(n0 + img) * 3 * HO2 * HO2 + (size_t)oh * HO2 + ow;
#pragma unroll
      for (int r = 0; r < 4; ++r) {
        int co = quad * 4 + r;
        if (co < 3)
          outF[base + (size_t)co * HO2 * HO2] = 1.f / (1.f + __expf(-acc[i][0][r]));
      }
    }
  } else {
    ushort* out = (ushort*)out_;
#pragma unroll
    for (int i = 0; i < WM; ++i) {
      int mtile = mt0 + i;
      int img = (NB == 1) ? 0 : (mtile / MTPI);
      int lm  = (NB == 1) ? mtile : (mtile % MTPI);
      int m = lm * 16 + ln15;
      int hr = m >> LW, wr = m & (W - 1);
      size_t sp;
      if (MODE == 2) {
        int oh = 2 * (h0 + hr) + ph, ow = 2 * wr + pw;
        sp = ((size_t)(n0 + img) * (2 * HIN) + oh) * (2 * HIN) + ow;
      } else {
        sp = ((size_t)(n0 + img) * W + h0 + hr) * W + wr;
      }
#pragma unroll
      for (int j = 0; j < WN; ++j) {
        f32x4 a = acc[i][j];
        uint2 stv; stv.x = pk(a[0], a[1]); stv.y = pk(a[2], a[3]);
        *(uint2*)&out[sp * Co + (cg0 + j) * 16 + quad * 4] = stv;
      }
    }
  }

  if (OSTAT) {
#pragma unroll
    for (int j = 0; j < WN; ++j)
#pragma unroll
      for (int r = 0; r < 4; ++r) {
        float s = 0.f, q = 0.f;
#pragma unroll
        for (int i = 0; i < WM; ++i) {
          float v = acc[i][j][r];
          s += v; q = fmaf(v, v, q);
        }
#pragma unroll
        for (int mk = 1; mk < 16; mk <<= 1) {
          s += __shfl_xor(s, mk);
          q += __shfl_xor(q, mk);
        }
        if (ln15 == 0) {
          int lc = (cg0 + j) * 16 + quad * 4 + r - cbase * 16;
          atomicAdd(&sst[lc], s);
          atomicAdd(&ssq[lc], q);
        }
      }
    __syncthreads();
    float* d = stOut + (size_t)(blockIdx.x & 7) * 2 * Co;
    for (int c = tid; c < COB; c += 256) {
      atomicAdd(&d[cbase * 16 + c], sst[c]);
      atomicAdd(&d[Co + cbase * 16 + c], ssq[c]);
    }
  }
}

// ===================== 1x1 conv GEMM, fused input-BN + output stats ==========
template<int Ci, int Co, int COT, bool BN, int NPIX, bool OSTAT>
__global__ __launch_bounds__(256) void g1x1(const ushort* __restrict__ in,
    const ushort* __restrict__ wt, const float* __restrict__ bias,
    const float* __restrict__ st, const float* __restrict__ g,
    const float* __restrict__ bb, ushort* __restrict__ out,
    float* __restrict__ stOut) {
  constexpr int NG = COT / 16;
  constexpr int CB = BN ? Ci : 1;
  constexpr int SB = OSTAT ? COT : 1;
  __shared__ __align__(16) ushort lb[64 * 40];
  __shared__ float lsc[CB], lsh[CB];
  __shared__ float sst[SB], ssq[SB];
  const int tid = threadIdx.x, wave = tid >> 6, ln15 = tid & 15, quad = (tid & 63) >> 4;
  const int pixBase = blockIdx.x * 64;
  const int co0 = blockIdx.y * COT;
  if (BN) {
    constexpr float inv_cnt = 1.0f / (float)NPIX;
    for (int c = tid; c < Ci; c += 256) {
      float s = 0.f, q = 0.f;
#pragma unroll
      for (int sl = 0; sl < 8; ++sl) {
        s += st[sl * 2 * Ci + c];
        q += st[sl * 2 * Ci + Ci + c];
      }
      float m = s * inv_cnt;
      float var = fmaf(q, inv_cnt, -m * m);
      float sc = g[c] * rsqrtf(var + 1e-5f);
      lsc[c] = sc;
      lsh[c] = fmaf(-m, sc, bb[c]);
    }
  }
  f32x4 acc[NG];
#pragma unroll
  for (int j = 0; j < NG; ++j) acc[j] = *(const f32x4*)&bias[co0 + j * 16 + quad * 4];
  const uint4* src4 = (const uint4*)in;
#pragma unroll 1
  for (int c0 = 0; c0 < Ci; c0 += 32) {
    __syncthreads();
    {
      int ciu4 = tid & 3, pl = tid >> 2;
      uint4 v4 = src4[(size_t)(pixBase + pl) * (Ci / 8) + (c0 >> 3) + ciu4];
      if (BN) {
        uint* pu = (uint*)&v4;
#pragma unroll
        for (int k2 = 0; k2 < 4; ++k2) {
          int cc = c0 + ciu4 * 8 + k2 * 2;
          float f0 = fmaf(bf2f((ushort)(pu[k2] & 0xffffu)), lsc[cc], lsh[cc]);
          float f1 = fmaf(bf2f((ushort)(pu[k2] >> 16)), lsc[cc + 1], lsh[cc + 1]);
          f0 = f0 > 0.f ? f0 : 0.01f * f0;
          f1 = f1 > 0.f ? f1 : 0.01f * f1;
          pu[k2] = pk(f0, f1);
        }
      }
      *(uint4*)&((uint*)lb)[pl * 20 + ciu4 * 4] = v4;
    }
    __syncthreads();
    bf16x8 bfr = *(const bf16x8*)&lb[(wave * 16 + ln15) * 40 + quad * 8];
#pragma unroll
    for (int j = 0; j < NG; ++j) {
      bf16x8 af = *(const bf16x8*)&wt[(size_t)(co0 + j * 16 + ln15) * Ci + c0 + quad * 8];
      acc[j] = __builtin_amdgcn_mfma_f32_16x16x32_bf16(af, bfr, acc[j], 0, 0, 0);
    }
  }
  if (OSTAT) {
    for (int c = tid; c < COT; c += 256) { sst[c] = 0.f; ssq[c] = 0.f; }
    __syncthreads();
  }
  int pix = pixBase + wave * 16 + ln15;
#pragma unroll
  for (int j = 0; j < NG; ++j) {
    uint2 stv; stv.x = pk(acc[j][0], acc[j][1]); stv.y = pk(acc[j][2], acc[j][3]);
    *(uint2*)&out[(size_t)pix * Co + co0 + j * 16 + quad * 4] = stv;
  }
  if (OSTAT) {
#pragma unroll
    for (int j = 0; j < NG; ++j)
#pragma unroll
      for (int r = 0; r < 4; ++r) {
        float s = acc[j][r];
        float q = s * s;
#pragma unroll
        for (int mk = 1; mk < 16; mk <<= 1) {
          s += __shfl_xor(s, mk);
          q += __shfl_xor(q, mk);
        }
        if (ln15 == 0) {
          int cl = j * 16 + quad * 4 + r;
          atomicAdd(&sst[cl], s);
          atomicAdd(&ssq[cl], q);
        }
      }
    __syncthreads();
    float* d = stOut + (size_t)(blockIdx.x & 7) * 2 * Co;
    for (int c = tid; c < COT; c += 256) {
      atomicAdd(&d[co0 + c], sst[c]);
      atomicAdd(&d[Co + co0 + c], ssq[c]);
    }
  }
}

// ===================== ce1 (MFMA): k4s2p1, Ci=3, fp32 NCHW -> bf16 NHWC + stats ===
__global__ __launch_bounds__(256) void ce1_mfma(const float* __restrict__ x,
    const ushort* __restrict__ wt, const float* __restrict__ bias,
    ushort* __restrict__ out, float* __restrict__ stOut) {
  __shared__ __align__(16) float lt[3 * 18 * 72];   // padded fp32 tile, 15.2 KB
  __shared__ float sst[32], ssq[32];
  const int tid = threadIdx.x, wave = tid >> 6, ln15 = tid & 15, quad = (tid & 63) >> 4;
  const int pixBase = blockIdx.x * 256;     // 8 out rows x 32 cols, one image
  const int n  = pixBase >> 10;
  const int h0 = (pixBase >> 5) & 31;
  if (tid < 32) { sst[tid] = 0.f; ssq[tid] = 0.f; }
  const int gr0 = 2 * h0 - 1;
  for (int i = tid; i < 3 * 18 * 72; i += 256) {
    int c = i % 72; int rem = i / 72; int r = rem % 18; int ci = rem / 18;
    int gr = gr0 + r, gc = c - 1;
    float v = 0.f;
    if ((unsigned)gr < 64u && (unsigned)gc < 64u)
      v = x[(((size_t)n * 3 + ci) << 12) + (gr << 6) + gc];
    lt[i] = v;
  }
  __syncthreads();

  f32x4 acc[4][2];
#pragma unroll
  for (int j = 0; j < 2; ++j) {
    f32x4 b4 = *(const f32x4*)&bias[j * 16 + quad * 4];
#pragma unroll
    for (int i = 0; i < 4; ++i) acc[i][j] = b4;
  }
  bf16x8 af[2][2];
#pragma unroll
  for (int j = 0; j < 2; ++j)
#pragma unroll
    for (int kk = 0; kk < 2; ++kk)
      af[j][kk] = *(const bf16x8*)&wt[(j * 16 + ln15) * 64 + kk * 32 + quad * 8];

  const int mt0 = wave * 4;
#pragma unroll
  for (int i = 0; i < 4; ++i) {
    int p = (mt0 + i) * 16 + ln15;        // px within block
    int h = p >> 5, w = p & 31;           // local out row/col
#pragma unroll
    for (int kk = 0; kk < 2; ++kk) {
      int k0 = kk * 32 + quad * 8;        // k = (ci*16 + kh*4 + kw)
      bf16x8 bfr = (bf16x8)(short)0;
      if (k0 < 48) {
        int ci = k0 >> 4, kh0 = (k0 >> 2) & 3;   // 8 k's = 2 rows x 4 kw
        const float* rp = &lt[(ci * 18 + 2 * h + kh0) * 72 + 2 * w];
        uint4 uu = make_uint4(pk(rp[0], rp[1]), pk(rp[2], rp[3]),
                              pk(rp[72], rp[73]), pk(rp[74], rp[75]));
        bfr = *reinterpret_cast<bf16x8*>(&uu);
      }
#pragma unroll
      for (int j = 0; j < 2; ++j)
        acc[i][j] = __builtin_amdgcn_mfma_f32_16x16x32_bf16(af[j][kk], bfr, acc[i][j], 0, 0, 0);
    }
  }
  // ---- store bf16 NHWC [px][32] ----
#pragma unroll
  for (int i = 0; i < 4; ++i) {
    int sp = pixBase + (mt0 + i) * 16 + ln15;
#pragma unroll
    for (int j = 0; j < 2; ++j) {
      f32x4 a = acc[i][j];
      uint2 stv; stv.x = pk(a[0], a[1]); stv.y = pk(a[2], a[3]);
      *(uint2*)&out[(size_t)sp * 32 + j * 16 + quad * 4] = stv;
    }
  }
  // ---- fused batch stats (16-lane reduce like tconv OSTAT) ----
#pragma unroll
  for (int j = 0; j < 2; ++j)
#pragma unroll
    for (int r = 0; r < 4; ++r) {
      float s = 0.f, q = 0.f;
#pragma unroll
      for (int i = 0; i < 4; ++i) {
        float v = acc[i][j][r];
        s += v; q = fmaf(v, v, q);
      }
#pragma unroll
      for (int mk = 1; mk < 16; mk <<= 1) {
        s += __shfl_xor(s, mk);
        q += __shfl_xor(q, mk);
      }
      if (ln15 == 0) {
        int ch = j * 16 + quad * 4 + r;
        atomicAdd(&sst[ch], s);
        atomicAdd(&ssq[ch], q);
      }
    }
  __syncthreads();
  if (tid < 32) {
    float* d = stOut + (size_t)(blockIdx.x & 7) * 64;
    atomicAdd(&d[tid], sst[tid]);
    atomicAdd(&d[32 + tid], ssq[tid]);
  }
}

// ===================== prep: ALL weight transforms + codebook, one dispatch ======
__device__ __forceinline__ void enc_tr(const float* __restrict__ w,
    ushort* __restrict__ o, int Co, int Ci, int idx) {
  int ci = idx % Ci; int r = idx / Ci; int co = r % Co; int t = r / Co;
  o[idx] = f2bf(w[(co * Ci + ci) * 16 + t]);
}
__device__ __forceinline__ float dec_comb(const float* __restrict__ w,
    int Ci, int co, int ci, int pt) {
  int p = pt >> 2, t = pt & 3;
  int ph = p >> 1, pw = p & 1, rr = t >> 1, cc = t & 1;
  int rs = (rr == 0) ? 0 : (ph == 0 ? 1 : 2);
  int re = (rr == 0) ? (ph == 0 ? 1 : 2) : 3;
  int cs = (cc == 0) ? 0 : (pw == 0 ? 1 : 2);
  int ce = (cc == 0) ? (pw == 0 ? 1 : 2) : 3;
  float s = 0.f;
  for (int kh = rs; kh < re; ++kh)
    for (int kw = cs; kw < ce; ++kw)
      s += w[((co * Ci + ci) * 3 + kh) * 3 + kw];
  return s;
}
__device__ __forceinline__ void dec_tr(const float* __restrict__ w,
    ushort* __restrict__ o, int Co, int Ci, int idx) {
  int ci = idx % Ci; int r = idx / Ci; int co = r % Co; int pt = r / Co;
  o[idx] = f2bf(dec_comb(w, Ci, co, ci, pt));
}

__global__ __launch_bounds__(256) void prep_all(
    const float* __restrict__ ce1_w,
    const float* __restrict__ ce2_w, const float* __restrict__ ce3_w,
    const float* __restrict__ ce4_w, const float* __restrict__ ce5_w,
    const float* __restrict__ cd0_w, const float* __restrict__ cd1_w,
    const float* __restrict__ cd2_w, const float* __restrict__ cd3_w,
    const float* __restrict__ cd4_w, const float* __restrict__ cd4_b,
    const float* __restrict__ codebook,
    ushort* __restrict__ wce1b,
    ushort* __restrict__ wce2, ushort* __restrict__ wce3, ushort* __restrict__ wce4,
    ushort* __restrict__ wce5, ushort* __restrict__ wcd0, ushort* __restrict__ wcd1,
    ushort* __restrict__ wcd2, ushort* __restrict__ wcd3, ushort* __restrict__ wcd4,
    float* __restrict__ cd4bp, ushort* __restrict__ cbbf, float* __restrict__ wsq) {
  __shared__ float sh[4];
  int bx = blockIdx.x, tid = threadIdx.x;
  if (bx < 2048) { int i = bx * 256 + tid; cbbf[i] = f2bf(codebook[i]); return; }
  bx -= 2048;
  if (bx < 512) {
    int k = bx;
    float s = 0.f;
    for (int d = tid; d < 1024; d += 256) {
      float v = codebook[k * 1024 + d];
      s = fmaf(v, v, s);
    }
#pragma unroll
    for (int o = 32; o > 0; o >>= 1) s += __shfl_down(s, o);
    if ((tid & 63) == 0) sh[tid >> 6] = s;
    __syncthreads();
    if (tid == 0) wsq[k] = sh[0] + sh[1] + sh[2] + sh[3];
    return;
  }
  bx -= 512;
  if (bx < 2048) { enc_tr(ce4_w, wce4, 256, 128, bx * 256 + tid); return; }
  bx -= 2048;
  if (bx < 2048) { dec_tr(cd1_w, wcd1, 128, 256, bx * 256 + tid); return; }
  bx -= 2048;
  if (bx < 512)  { enc_tr(ce3_w, wce3, 128, 64, bx * 256 + tid); return; }
  bx -= 512;
  if (bx < 512)  { dec_tr(cd2_w, wcd2, 64, 128, bx * 256 + tid); return; }
  bx -= 512;
  if (bx < 128)  { enc_tr(ce2_w, wce2, 64, 32, bx * 256 + tid); return; }
  bx -= 128;
  if (bx < 128)  { dec_tr(cd3_w, wcd3, 32, 64, bx * 256 + tid); return; }
  bx -= 128;
  if (bx < 64)   { int i = bx * 256 + tid; wce5[i] = f2bf(ce5_w[i]); return; }
  bx -= 64;
  if (bx < 64)   { int i = bx * 256 + tid; wcd0[i] = f2bf(cd0_w[i]); return; }
  bx -= 64;
  if (bx < 32) {                // cd4 padded: [16 taps][16 co][32 ci]
    int idx = bx * 256 + tid;   // 32 blocks
    int ci = idx & 31; int r = idx >> 5; int co = r & 15; int pt = r >> 4;
    wcd4[idx] = (co < 3) ? f2bf(dec_comb(cd4_w, 32, co, ci, pt)) : (ushort)0;
    if (bx == 0 && tid < 16) cd4bp[tid] = (tid < 3) ? cd4_b[tid] : 0.f;
    return;
  }
  bx -= 32;
  {                             // ce1 bf16 weights: [32 co][64 k], k>=48 zero; 8 blocks
    int idx = bx * 256 + tid;   // 0..2047
    int k = idx & 63, co = idx >> 6;
    wce1b[idx] = (k < 48) ? f2bf(ce1_w[co * 48 + k]) : (ushort)0;
  }
}

// ===================== VQ ==========
__global__ __launch_bounds__(256) void zprep(const ushort* __restrict__ r5,
    const float* __restrict__ st, const float* __restrict__ g,
    const float* __restrict__ bb, float* __restrict__ Z, ushort* __restrict__ Zbf) {
  __shared__ float lsc[64], lsh[64];
  int tid = threadIdx.x;
  if (tid < 64) {
    float s = 0.f, q = 0.f;
#pragma unroll
    for (int sl = 0; sl < 8; ++sl) { s += st[sl * 128 + tid]; q += st[sl * 128 + 64 + tid]; }
    float m = s * (1.0f / 8192.f);
    float var = fmaf(q, 1.0f / 8192.f, -m * m);
    float sc = g[tid] * rsqrtf(var + 1e-5f);
    lsc[tid] = sc;
    lsh[tid] = fmaf(-m, sc, bb[tid]);
  }
  __syncthreads();
  int i = blockIdx.x * 256 + tid;
  int c = i & 63;
  float f = fmaf(bf2f(r5[i]), lsc[c], lsh[c]);
  f = f > 0.f ? f : 0.01f * f;
  Z[i] = f;
  Zbf[i] = f2bf(f);
}

// S_ks[b][k] partial dot over K-slice ks (4 slices). Grid (8,8,4).
__global__ __launch_bounds__(256) void vq_gemm(const ushort* __restrict__ Zbf,
    const ushort* __restrict__ cbbf, float* __restrict__ S) {
  __shared__ __align__(16) ushort lZ[64 * 40], lW[64 * 40];
  const int tid = threadIdx.x, wave = tid >> 6, ln15 = tid & 15, quad = (tid & 63) >> 4;
  const int b0 = blockIdx.x * 64, k0 = blockIdx.y * 64, ks = blockIdx.z;
  f32x4 acc[4];
#pragma unroll
  for (int j = 0; j < 4; ++j) acc[j] = (f32x4)(0.f);
  const uint4* zs = (const uint4*)Zbf;
  const uint4* ws = (const uint4*)cbbf;
#pragma unroll 1
  for (int c0 = ks * 256; c0 < ks * 256 + 256; c0 += 32) {
    __syncthreads();
    for (int i = tid; i < 512; i += 256) {
      int ciu4 = i & 3; int rl = (i >> 2) & 63; bool isW = i >= 256;
      uint4 v = (isW ? ws : zs)[(size_t)((isW ? k0 : b0) + rl) * 128 + (c0 >> 3) + ciu4];
      *(uint4*)&((uint*)(isW ? lW : lZ))[rl * 20 + ciu4 * 4] = v;
    }
    __syncthreads();
    bf16x8 bfr = *(const bf16x8*)&lZ[(wave * 16 + ln15) * 40 + quad * 8];
#pragma unroll
    for (int j = 0; j < 4; ++j) {
      bf16x8 af = *(const bf16x8*)&lW[(j * 16 + ln15) * 40 + quad * 8];
      acc[j] = __builtin_amdgcn_mfma_f32_16x16x32_bf16(af, bfr, acc[j], 0, 0, 0);
    }
  }
  int b = b0 + wave * 16 + ln15;
  float* Sk = S + (size_t)ks * 262144;
#pragma unroll
  for (int j = 0; j < 4; ++j)
    *(f32x4*)&Sk[(size_t)b * 512 + k0 + j * 16 + quad * 4] = acc[j];
}

// fused: argmin scan + gather Zq + exact fp32 loss + last-block writes losses
__global__ __launch_bounds__(256) void vq_post(const float* __restrict__ S,
    const float* __restrict__ wsq, const float* __restrict__ Z,
    const float* __restrict__ cb, ushort* __restrict__ Zq,
    float* __restrict__ lossAcc, int* __restrict__ cnt, float* __restrict__ out2) {
  int b = blockIdx.x, tid = threadIdx.x;
  float s1 = 0.f, s2 = 0.f;
#pragma unroll
  for (int sl = 0; sl < 4; ++sl) {
    s1 += S[(size_t)sl * 262144 + (size_t)b * 512 + tid];
    s2 += S[(size_t)sl * 262144 + (size_t)b * 512 + tid + 256];
  }
  float d1 = fmaf(-2.f, s1, wsq[tid]);
  float d2 = fmaf(-2.f, s2, wsq[tid + 256]);
  float bv = d1; int bk = tid;
  if (d2 < bv) { bv = d2; bk = tid + 256; }
  __shared__ float vsh[256]; __shared__ int ish[256];
  vsh[tid] = bv; ish[tid] = bk;
  __syncthreads();
  for (int s = 128; s > 0; s >>= 1) {
    if (tid < s) {
      float ov = vsh[tid + s]; int oi = ish[tid + s];
      if (ov < vsh[tid] || (ov == vsh[tid] && oi < ish[tid])) { vsh[tid] = ov; ish[tid] = oi; }
    }
    __syncthreads();
  }
  int k = ish[0];
  const float* w = cb + ((long)k << 10);
  const float* zp = Z + ((long)b << 10);
  float part = 0.f;
  for (int d = tid; d < 1024; d += 256) {
    float wv = w[d];
    float diff = zp[d] - wv;
    part = fmaf(diff, diff, part);
    Zq[(b << 10) + d] = f2bf(wv);
  }
#pragma unroll
  for (int o = 32; o > 0; o >>= 1) part += __shfl_down(part, o);
  __shared__ float sh[4];
  if ((tid & 63) == 0) sh[tid >> 6] = part;
  __syncthreads();
  if (tid == 0) {
    atomicAdd(lossAcc, sh[0] + sh[1] + sh[2] + sh[3]);
    __threadfence();
    int old = atomicAdd(cnt, 1);
    if (old == 511) {
      float v = *(volatile float*)lossAcc * (1.0f / 512.0f);
      out2[0] = v;
      out2[1] = v;
    }
  }
}

// ===================== launch ==========
extern "C" void kernel_launch(void* const* d_in, const int* in_sizes, int n_in,
                              void* d_out, int out_size, void* d_ws, size_t ws_size,
                              hipStream_t stream) {
  const float* x      = (const float*)d_in[0];
  const float* ce1_w  = (const float*)d_in[1];  const float* ce1_b = (const float*)d_in[2];
  const float* ce2_w  = (const float*)d_in[3];  const float* ce2_b = (const float*)d_in[4];
  const float* ce3_w  = (const float*)d_in[5];  const float* ce3_b = (const float*)d_in[6];
  const float* ce4_w  = (const float*)d_in[7];  const float* ce4_b = (const float*)d_in[8];
  const float* ce5_w  = (const float*)d_in[9];  const float* ce5_b = (const float*)d_in[10];
  const float* cd0_w  = (const float*)d_in[11]; const float* cd0_b = (const float*)d_in[12];
  const float* cd1_w  = (const float*)d_in[13]; const float* cd1_b = (const float*)d_in[14];
  const float* cd2_w  = (const float*)d_in[15]; const float* cd2_b = (const float*)d_in[16];
  const float* cd3_w  = (const float*)d_in[17]; const float* cd3_b = (const float*)d_in[18];
  const float* cd4_w  = (const float*)d_in[19]; const float* cd4_b = (const float*)d_in[20];
  const float* bn_e1_g = (const float*)d_in[21]; const float* bn_e1_b = (const float*)d_in[22];
  const float* bn_e2_g = (const float*)d_in[23]; const float* bn_e2_b = (const float*)d_in[24];
  const float* bn_e3_g = (const float*)d_in[25]; const float* bn_e3_b = (const float*)d_in[26];
  const float* bn_e4_g = (const float*)d_in[27]; const float* bn_e4_b = (const float*)d_in[28];
  const float* bn_e5_g = (const float*)d_in[29]; const float* bn_e5_b = (const float*)d_in[30];
  const float* bn_d0_g = (const float*)d_in[31]; const float* bn_d0_b = (const float*)d_in[32];
  const float* bn_d1_g = (const float*)d_in[33]; const float* bn_d1_b = (const float*)d_in[34];
  const float* bn_d2_g = (const float*)d_in[35]; const float* bn_d2_b = (const float*)d_in[36];
  const float* bn_d3_g = (const float*)d_in[37]; const float* bn_d3_b = (const float*)d_in[38];
  const float* codebook = (const float*)d_in[39];

  float* out = (float*)d_out;

  // ---- workspace carve ----
  char* p = (char*)d_ws;
  auto alloc = [&](size_t bytes) { void* r = p; p += (bytes + 255) & ~(size_t)255; return r; };
  ushort* r1 = (ushort*)alloc((size_t)524288 * 32 * 2);
  ushort* r2 = (ushort*)alloc((size_t)131072 * 64 * 2);
  ushort* r3 = (ushort*)alloc((size_t)32768 * 128 * 2);
  ushort* r4 = (ushort*)alloc((size_t)8192 * 256 * 2);
  ushort* r5 = (ushort*)alloc((size_t)8192 * 64 * 2);
  ushort* d0 = (ushort*)alloc((size_t)8192 * 256 * 2);
  ushort* d1 = (ushort*)alloc((size_t)32768 * 128 * 2);
  ushort* d2 = (ushort*)alloc((size_t)131072 * 64 * 2);
  ushort* d3 = (ushort*)alloc((size_t)524288 * 32 * 2);
  float*  Z    = (float*)alloc((size_t)524288 * 4);
  ushort* Zbf  = (ushort*)alloc((size_t)524288 * 2);
  ushort* cbbf = (ushort*)alloc((size_t)524288 * 2);
  float*  S    = (float*)alloc((size_t)4 * 262144 * 4);   // 4 K-slices
  ushort* Zq   = (ushort*)alloc((size_t)524288 * 2);
  float*  wsq  = (float*)alloc((size_t)512 * 4);
  ushort* wce2 = (ushort*)alloc((size_t)16 * 64 * 32 * 2);
  ushort* wce3 = (ushort*)alloc((size_t)16 * 128 * 64 * 2);
  ushort* wce4 = (ushort*)alloc((size_t)16 * 256 * 128 * 2);
  ushort* wce5 = (ushort*)alloc((size_t)64 * 256 * 2);
  ushort* wcd0 = (ushort*)alloc((size_t)256 * 64 * 2);
  ushort* wcd1 = (ushort*)alloc((size_t)16 * 128 * 256 * 2);
  ushort* wcd2 = (ushort*)alloc((size_t)16 * 64 * 128 * 2);
  ushort* wcd3 = (ushort*)alloc((size_t)16 * 32 * 64 * 2);
  ushort* wcd4 = (ushort*)alloc((size_t)16 * 16 * 32 * 2);
  ushort* wce1b = (ushort*)alloc((size_t)32 * 64 * 2);
  float*  cd4bp = (float*)alloc(64);
  float*  statsAll = (float*)alloc((size_t)(9 * 4096 + 64) * 4);
  int*    jbuf = (int*)alloc((size_t)512 * 4);

  float* st_e1 = statsAll + 0 * 4096;
  float* st_e2 = statsAll + 1 * 4096;
  float* st_e3 = statsAll + 2 * 4096;
  float* st_e4 = statsAll + 3 * 4096;
  float* st_e5 = statsAll + 4 * 4096;
  float* st_d0 = statsAll + 5 * 4096;
  float* st_d1 = statsAll + 6 * 4096;
  float* st_d2 = statsAll + 7 * 4096;
  float* st_d3 = statsAll + 8 * 4096;
  float* lossAcc = statsAll + 9 * 4096;
  int*   cnt = (int*)(lossAcc + 1);

  hipMemsetAsync(statsAll, 0, (size_t)(9 * 4096 + 64) * 4, stream);

  prep_all<<<8104, 256, 0, stream>>>(ce1_w, ce2_w, ce3_w, ce4_w, ce5_w, cd0_w, cd1_w,
      cd2_w, cd3_w, cd4_w, cd4_b, codebook,
      wce1b, wce2, wce3, wce4, wce5, wcd0, wcd1, wcd2, wcd3, wcd4, cd4bp, cbbf, wsq);

  // ---- encoder ----
  ce1_mfma<<<2048, 256, 0, stream>>>(x, wce1b, ce1_b, r1, st_e1);
  tconv<1, 32, 64, 32, 8, 4, 2, 1, 1, true, true, false><<<dim3(1024, 1), 256, 0, stream>>>(
      r1, wce2, ce2_b, st_e1, bn_e1_g, bn_e1_b, r2, st_e2);
  tconv<1, 64, 128, 16, 8, 4, 2, 1, 1, true, true, false><<<dim3(512, 1), 256, 0, stream>>>(
      r2, wce3, ce3_b, st_e2, bn_e2_g, bn_e2_b, r3, st_e3);
  tconv<1, 128, 256, 8, 4, 1, 4, 1, 1, true, true, false><<<dim3(512, 1), 256, 0, stream>>>(
      r3, wce4, ce4_b, st_e3, bn_e3_g, bn_e3_b, r4, st_e4);
  g1x1<256, 64, 16, true, 8192, true><<<dim3(128, 4), 256, 0, stream>>>(
      r4, wce5, ce5_b, st_e4, bn_e4_g, bn_e4_b, r5, st_e5);

  // ---- VQ ----
  zprep<<<2048, 256, 0, stream>>>(r5, st_e5, bn_e5_g, bn_e5_b, Z, Zbf);
  vq_gemm<<<dim3(8, 8, 4), 256, 0, stream>>>(Zbf, cbbf, S);
  vq_post<<<512, 256, 0, stream>>>(S, wsq, Z, codebook, Zq, lossAcc, cnt, out + 6291456);

  // ---- decoder ----
  g1x1<64, 256, 32, false, 1, true><<<dim3(128, 8), 256, 0, stream>>>(
      Zq, wcd0, cd0_b, nullptr, nullptr, nullptr, d0, st_d0);
  // cd1: NB=4 images/block -> WM=4 (4 MFMA per weight load), WN=4, CS=2
  tconv<2, 256, 128, 4, 4, 4, 4, 2, 4, true, true, false><<<dim3(128, 2), 256, 0, stream>>>(
      d0, wcd1, cd1_b, st_d0, bn_d0_g, bn_d0_b, d1, st_d1);
  tconv<2, 128, 64, 8, 8, 4, 4, 1, 1, true, true, false><<<dim3(512, 1), 256, 0, stream>>>(
      d1, wcd2, cd2_b, st_d1, bn_d1_g, bn_d1_b, d2, st_d2);
  tconv<2, 64, 32, 16, 8, 8, 2, 1, 1, true, true, false><<<dim3(1024, 1), 256, 0, stream>>>(
      d2, wcd3, cd3_b, st_d2, bn_d2_g, bn_d2_b, d3, st_d3);
  tconv<2, 32, 16, 32, 4, 8, 1, 1, 1, true, false, true><<<dim3(4096, 1), 256, 0, stream>>>(
      d3, wcd4, cd4bp, st_d3, bn_d3_g, bn_d3_b, out, nullptr);
}

// Round 7
// 454.343 us; speedup vs baseline: 1.1764x; 1.0194x over previous
//
#include <hip/hip_runtime.h>
#include <hip/hip_bf16.h>
#include <math.h>

typedef __attribute__((ext_vector_type(8))) short bf16x8;
typedef __attribute__((ext_vector_type(4))) float f32x4;

__device__ __forceinline__ float bf2f(ushort u) {
  union { uint i; float f; } t; t.i = ((uint)u) << 16; return t.f;
}
__device__ __forceinline__ ushort f2bf(float f) {
  __hip_bfloat16 h = __float2bfloat16(f);
  return *reinterpret_cast<ushort*>(&h);
}
__device__ __forceinline__ uint pk(float a, float b) {
  return (uint)f2bf(a) | ((uint)f2bf(b) << 16);
}
constexpr int ilog2c(int v) { int r = 0; while (v > 1) { v >>= 1; ++r; } return r; }

// =====================================================================
// Tiled MFMA conv, fused input-BN+LReLU, fused output batch-stats,
// co-split across blockIdx.y (CS) for occupancy.
// MODE 1: k4s2p1 encoder. MODE 2: up2+3x3 decoder (wave = parity class).
// NB: images per block (both modes): raises WM so each weight load feeds
// WM MFMAs. Layers whose whole image is one M-tile (cd1 4x4, ce4 4x4 out)
// are 1:1 load:MFMA at NB=1 -> serialized vmcnt waits (cd1 83us, ce4 69us).
// SIG: fp32 NCHW sigmoid output (cd4, Co padded to 16, real 3).
// =====================================================================
template<int MODE, int Ci, int Co, int HIN, int TR, int WM, int WN, int CS,
         int NB, bool BN, bool OSTAT, bool SIG>
__global__ __launch_bounds__(256) void tconv(const ushort* __restrict__ in,
    const ushort* __restrict__ wt, const float* __restrict__ bias,
    const float* __restrict__ st, const float* __restrict__ g,
    const float* __restrict__ bb, void* __restrict__ out_,
    float* __restrict__ stOut) {
  constexpr int W    = (MODE == 1) ? HIN / 2 : HIN;
  constexpr int LW   = ilog2c(W);
  constexpr int R_IN = (MODE == 1) ? 2 * TR + 2 : TR + 2;
  constexpr int W2   = HIN + 2;
  constexpr int MTPI = TR * W / 16;        // M-tiles per image
  constexpr int MT   = NB * MTPI;          // M-tiles per block
  constexpr int NG   = Co / 16;
  constexpr int NGB  = NG / CS;            // co groups per block
  constexpr int COB  = NGB * 16;           // channels per block
  constexpr int TAPS = (MODE == 1) ? 16 : 4;
  constexpr int RB   = W / TR;
  constexpr int CB   = BN ? Ci : 1;
  constexpr int SB   = OSTAT ? COB : 1;
  constexpr int SN4P = R_IN * W2 * 4;      // 16B staging units per image
  static_assert(TR * W % 16 == 0, "mtile");
  static_assert(MODE == 2 ? (WM == MT && WN == NGB)
                          : ((MT % WM == 0) && (NGB % WN == 0) &&
                             (MT / WM) * (NGB / WN) == 4),
                "wave map");

  __shared__ __align__(16) ushort lt[NB * R_IN * W2 * 40];
  __shared__ float lsc[CB], lsh[CB];
  __shared__ float sst[SB], ssq[SB];

  const int tid  = threadIdx.x;
  const int wave = tid >> 6;
  const int ln15 = tid & 15;
  const int quad = (tid & 63) >> 4;
  const int rb = blockIdx.x % RB;
  const int n0 = (blockIdx.x / RB) * NB;
  const int h0 = rb * TR;
  const int cbase = blockIdx.y * NGB;      // co-group base for this block

  if (BN) {
    constexpr float inv_cnt = 1.0f / (float)(512 * HIN * HIN);
    for (int c = tid; c < Ci; c += 256) {
      float s = 0.f, q = 0.f;
#pragma unroll
      for (int sl = 0; sl < 8; ++sl) {
        s += st[sl * 2 * Ci + c];
        q += st[sl * 2 * Ci + Ci + c];
      }
      float m = s * inv_cnt;
      float var = fmaf(q, inv_cnt, -m * m);
      float sc = g[c] * rsqrtf(var + 1e-5f);
      lsc[c] = sc;
      lsh[c] = fmaf(-m, sc, bb[c]);
    }
  }

  int mt0, cg0, ph, pw, pb;
  if (MODE == 2) { mt0 = 0; cg0 = cbase; ph = wave >> 1; pw = wave & 1; pb = wave * 4; }
  else {
    constexpr int MW = MT / WM;
    mt0 = (wave % MW) * WM; cg0 = cbase + (wave / MW) * WN; ph = 0; pw = 0; pb = 0;
  }

  f32x4 acc[WM][WN];
#pragma unroll
  for (int j = 0; j < WN; ++j) {
    f32x4 b4 = *(const f32x4*)&bias[(cg0 + j) * 16 + quad * 4];
#pragma unroll
    for (int i = 0; i < WM; ++i) acc[i][j] = b4;
  }

  const uint4* src4 = (const uint4*)in;
  const int gr0 = (MODE == 1) ? 2 * h0 - 1 : h0 - 1;

#pragma unroll 1
  for (int c0 = 0; c0 < Ci; c0 += 32) {
    __syncthreads();
    for (int i = tid; i < NB * SN4P; i += 256) {
      int img = (NB == 1) ? 0 : (i / SN4P);
      int ii  = (NB == 1) ? i : (i % SN4P);
      int ciu4 = ii & 3; int t2 = ii >> 2; int c = t2 % W2; int r = t2 / W2;
      int gr = gr0 + r, gc = c - 1;
      uint4 v4 = make_uint4(0u, 0u, 0u, 0u);
      if ((unsigned)gr < (unsigned)HIN && (unsigned)gc < (unsigned)HIN) {
        v4 = src4[((size_t)((n0 + img) * HIN + gr) * HIN + gc) * (Ci / 8) + (c0 >> 3) + ciu4];
        if (BN) {
          uint* pu = (uint*)&v4;
#pragma unroll
          for (int k2 = 0; k2 < 4; ++k2) {
            int cc = c0 + ciu4 * 8 + k2 * 2;
            float f0 = fmaf(bf2f((ushort)(pu[k2] & 0xffffu)), lsc[cc], lsh[cc]);
            float f1 = fmaf(bf2f((ushort)(pu[k2] >> 16)), lsc[cc + 1], lsh[cc + 1]);
            f0 = f0 > 0.f ? f0 : 0.01f * f0;
            f1 = f1 > 0.f ? f1 : 0.01f * f1;
            pu[k2] = pk(f0, f1);
          }
        }
      }
      *(uint4*)&((uint*)lt)[((img * R_IN + r) * W2 + c) * 20 + ciu4 * 4] = v4;
    }
    __syncthreads();

#pragma unroll
    for (int t = 0; t < TAPS; ++t) {
      const int kh = (MODE == 1) ? (t >> 2) : (t >> 1);
      const int kw = (MODE == 1) ? (t & 3) : (t & 1);
      bf16x8 af[WN];
      const ushort* wb = wt + (size_t)(pb + t) * Co * Ci;
#pragma unroll
      for (int j = 0; j < WN; ++j)
        af[j] = *(const bf16x8*)&wb[(size_t)((cg0 + j) * 16 + ln15) * Ci + c0 + quad * 8];
      bf16x8 bfr[WM];
#pragma unroll
      for (int i = 0; i < WM; ++i) {
        int mtile = mt0 + i;
        int img = (NB == 1) ? 0 : (mtile / MTPI);
        int lm  = (NB == 1) ? mtile : (mtile % MTPI);
        int m = lm * 16 + ln15;
        int hr = m >> LW, wr = m & (W - 1);
        int row, col;
        if (MODE == 1) { row = 2 * hr + kh; col = 2 * wr + kw; }
        else           { row = hr + kh + ph; col = wr + kw + pw; }
        bfr[i] = *(const bf16x8*)&lt[((img * R_IN + row) * W2 + col) * 40 + quad * 8];
      }
#pragma unroll
      for (int i = 0; i < WM; ++i)
#pragma unroll
        for (int j = 0; j < WN; ++j)
          acc[i][j] = __builtin_amdgcn_mfma_f32_16x16x32_bf16(af[j], bfr[i], acc[i][j], 0, 0, 0);
    }
  }

  if (OSTAT) {
    for (int c = tid; c < COB; c += 256) { sst[c] = 0.f; ssq[c] = 0.f; }
    __syncthreads();
  }

  if (SIG) {
    constexpr int HO2 = 2 * HIN;
    float* outF = (float*)out_;
#pragma unroll
    for (int i = 0; i < WM; ++i) {
      int mtile = mt0 + i;
      int img = (NB == 1) ? 0 : (mtile / MTPI);
      int lm  = (NB == 1) ? mtile : (mtile % MTPI);
      int m = lm * 16 + ln15;
      int hr = m >> LW, wr = m & (W - 1);
      int oh = 2 * (h0 + hr) + ph, ow = 2 * wr + pw;
      size_t base = (size_t)(n0 + img) * 3 * HO2 * HO2 + (size_t)oh * HO2 + ow;
#pragma unroll
      for (int r = 0; r < 4; ++r) {
        int co = quad * 4 + r;
        if (co < 3)
          outF[base + (size_t)co * HO2 * HO2] = 1.f / (1.f + __expf(-acc[i][0][r]));
      }
    }
  } else {
    ushort* out = (ushort*)out_;
#pragma unroll
    for (int i = 0; i < WM; ++i) {
      int mtile = mt0 + i;
      int img = (NB == 1) ? 0 : (mtile / MTPI);
      int lm  = (NB == 1) ? mtile : (mtile % MTPI);
      int m = lm * 16 + ln15;
      int hr = m >> LW, wr = m & (W - 1);
      size_t sp;
      if (MODE == 2) {
        int oh = 2 * (h0 + hr) + ph, ow = 2 * wr + pw;
        sp = ((size_t)(n0 + img) * (2 * HIN) + oh) * (2 * HIN) + ow;
      } else {
        sp = ((size_t)(n0 + img) * W + h0 + hr) * W + wr;
      }
#pragma unroll
      for (int j = 0; j < WN; ++j) {
        f32x4 a = acc[i][j];
        uint2 stv; stv.x = pk(a[0], a[1]); stv.y = pk(a[2], a[3]);
        *(uint2*)&out[sp * Co + (cg0 + j) * 16 + quad * 4] = stv;
      }
    }
  }

  if (OSTAT) {
#pragma unroll
    for (int j = 0; j < WN; ++j)
#pragma unroll
      for (int r = 0; r < 4; ++r) {
        float s = 0.f, q = 0.f;
#pragma unroll
        for (int i = 0; i < WM; ++i) {
          float v = acc[i][j][r];
          s += v; q = fmaf(v, v, q);
        }
#pragma unroll
        for (int mk = 1; mk < 16; mk <<= 1) {
          s += __shfl_xor(s, mk);
          q += __shfl_xor(q, mk);
        }
        if (ln15 == 0) {
          int lc = (cg0 + j) * 16 + quad * 4 + r - cbase * 16;
          atomicAdd(&sst[lc], s);
          atomicAdd(&ssq[lc], q);
        }
      }
    __syncthreads();
    float* d = stOut + (size_t)(blockIdx.x & 7) * 2 * Co;
    for (int c = tid; c < COB; c += 256) {
      atomicAdd(&d[cbase * 16 + c], sst[c]);
      atomicAdd(&d[Co + cbase * 16 + c], ssq[c]);
    }
  }
}

// ===================== 1x1 conv GEMM, fused input-BN + output stats ==========
template<int Ci, int Co, int COT, bool BN, int NPIX, bool OSTAT>
__global__ __launch_bounds__(256) void g1x1(const ushort* __restrict__ in,
    const ushort* __restrict__ wt, const float* __restrict__ bias,
    const float* __restrict__ st, const float* __restrict__ g,
    const float* __restrict__ bb, ushort* __restrict__ out,
    float* __restrict__ stOut) {
  constexpr int NG = COT / 16;
  constexpr int CB = BN ? Ci : 1;
  constexpr int SB = OSTAT ? COT : 1;
  __shared__ __align__(16) ushort lb[64 * 40];
  __shared__ float lsc[CB], lsh[CB];
  __shared__ float sst[SB], ssq[SB];
  const int tid = threadIdx.x, wave = tid >> 6, ln15 = tid & 15, quad = (tid & 63) >> 4;
  const int pixBase = blockIdx.x * 64;
  const int co0 = blockIdx.y * COT;
  if (BN) {
    constexpr float inv_cnt = 1.0f / (float)NPIX;
    for (int c = tid; c < Ci; c += 256) {
      float s = 0.f, q = 0.f;
#pragma unroll
      for (int sl = 0; sl < 8; ++sl) {
        s += st[sl * 2 * Ci + c];
        q += st[sl * 2 * Ci + Ci + c];
      }
      float m = s * inv_cnt;
      float var = fmaf(q, inv_cnt, -m * m);
      float sc = g[c] * rsqrtf(var + 1e-5f);
      lsc[c] = sc;
      lsh[c] = fmaf(-m, sc, bb[c]);
    }
  }
  f32x4 acc[NG];
#pragma unroll
  for (int j = 0; j < NG; ++j) acc[j] = *(const f32x4*)&bias[co0 + j * 16 + quad * 4];
  const uint4* src4 = (const uint4*)in;
#pragma unroll 1
  for (int c0 = 0; c0 < Ci; c0 += 32) {
    __syncthreads();
    {
      int ciu4 = tid & 3, pl = tid >> 2;
      uint4 v4 = src4[(size_t)(pixBase + pl) * (Ci / 8) + (c0 >> 3) + ciu4];
      if (BN) {
        uint* pu = (uint*)&v4;
#pragma unroll
        for (int k2 = 0; k2 < 4; ++k2) {
          int cc = c0 + ciu4 * 8 + k2 * 2;
          float f0 = fmaf(bf2f((ushort)(pu[k2] & 0xffffu)), lsc[cc], lsh[cc]);
          float f1 = fmaf(bf2f((ushort)(pu[k2] >> 16)), lsc[cc + 1], lsh[cc + 1]);
          f0 = f0 > 0.f ? f0 : 0.01f * f0;
          f1 = f1 > 0.f ? f1 : 0.01f * f1;
          pu[k2] = pk(f0, f1);
        }
      }
      *(uint4*)&((uint*)lb)[pl * 20 + ciu4 * 4] = v4;
    }
    __syncthreads();
    bf16x8 bfr = *(const bf16x8*)&lb[(wave * 16 + ln15) * 40 + quad * 8];
#pragma unroll
    for (int j = 0; j < NG; ++j) {
      bf16x8 af = *(const bf16x8*)&wt[(size_t)(co0 + j * 16 + ln15) * Ci + c0 + quad * 8];
      acc[j] = __builtin_amdgcn_mfma_f32_16x16x32_bf16(af, bfr, acc[j], 0, 0, 0);
    }
  }
  if (OSTAT) {
    for (int c = tid; c < COT; c += 256) { sst[c] = 0.f; ssq[c] = 0.f; }
    __syncthreads();
  }
  int pix = pixBase + wave * 16 + ln15;
#pragma unroll
  for (int j = 0; j < NG; ++j) {
    uint2 stv; stv.x = pk(acc[j][0], acc[j][1]); stv.y = pk(acc[j][2], acc[j][3]);
    *(uint2*)&out[(size_t)pix * Co + co0 + j * 16 + quad * 4] = stv;
  }
  if (OSTAT) {
#pragma unroll
    for (int j = 0; j < NG; ++j)
#pragma unroll
      for (int r = 0; r < 4; ++r) {
        float s = acc[j][r];
        float q = s * s;
#pragma unroll
        for (int mk = 1; mk < 16; mk <<= 1) {
          s += __shfl_xor(s, mk);
          q += __shfl_xor(q, mk);
        }
        if (ln15 == 0) {
          int cl = j * 16 + quad * 4 + r;
          atomicAdd(&sst[cl], s);
          atomicAdd(&ssq[cl], q);
        }
      }
    __syncthreads();
    float* d = stOut + (size_t)(blockIdx.x & 7) * 2 * Co;
    for (int c = tid; c < COT; c += 256) {
      atomicAdd(&d[co0 + c], sst[c]);
      atomicAdd(&d[Co + co0 + c], ssq[c]);
    }
  }
}

// ===================== ce1 (MFMA): k4s2p1, Ci=3, fp32 NCHW -> bf16 NHWC + stats ===
__global__ __launch_bounds__(256) void ce1_mfma(const float* __restrict__ x,
    const ushort* __restrict__ wt, const float* __restrict__ bias,
    ushort* __restrict__ out, float* __restrict__ stOut) {
  __shared__ __align__(16) float lt[3 * 18 * 72];   // padded fp32 tile, 15.2 KB
  __shared__ float sst[32], ssq[32];
  const int tid = threadIdx.x, wave = tid >> 6, ln15 = tid & 15, quad = (tid & 63) >> 4;
  const int pixBase = blockIdx.x * 256;     // 8 out rows x 32 cols, one image
  const int n  = pixBase >> 10;
  const int h0 = (pixBase >> 5) & 31;
  if (tid < 32) { sst[tid] = 0.f; ssq[tid] = 0.f; }
  const int gr0 = 2 * h0 - 1;
  for (int i = tid; i < 3 * 18 * 72; i += 256) {
    int c = i % 72; int rem = i / 72; int r = rem % 18; int ci = rem / 18;
    int gr = gr0 + r, gc = c - 1;
    float v = 0.f;
    if ((unsigned)gr < 64u && (unsigned)gc < 64u)
      v = x[(((size_t)n * 3 + ci) << 12) + (gr << 6) + gc];
    lt[i] = v;
  }
  __syncthreads();

  f32x4 acc[4][2];
#pragma unroll
  for (int j = 0; j < 2; ++j) {
    f32x4 b4 = *(const f32x4*)&bias[j * 16 + quad * 4];
#pragma unroll
    for (int i = 0; i < 4; ++i) acc[i][j] = b4;
  }
  bf16x8 af[2][2];
#pragma unroll
  for (int j = 0; j < 2; ++j)
#pragma unroll
    for (int kk = 0; kk < 2; ++kk)
      af[j][kk] = *(const bf16x8*)&wt[(j * 16 + ln15) * 64 + kk * 32 + quad * 8];

  const int mt0 = wave * 4;
#pragma unroll
  for (int i = 0; i < 4; ++i) {
    int p = (mt0 + i) * 16 + ln15;        // px within block
    int h = p >> 5, w = p & 31;           // local out row/col
#pragma unroll
    for (int kk = 0; kk < 2; ++kk) {
      int k0 = kk * 32 + quad * 8;        // k = (ci*16 + kh*4 + kw)
      bf16x8 bfr = (bf16x8)(short)0;
      if (k0 < 48) {
        int ci = k0 >> 4, kh0 = (k0 >> 2) & 3;   // 8 k's = 2 rows x 4 kw
        const float* rp = &lt[(ci * 18 + 2 * h + kh0) * 72 + 2 * w];
        uint4 uu = make_uint4(pk(rp[0], rp[1]), pk(rp[2], rp[3]),
                              pk(rp[72], rp[73]), pk(rp[74], rp[75]));
        bfr = *reinterpret_cast<bf16x8*>(&uu);
      }
#pragma unroll
      for (int j = 0; j < 2; ++j)
        acc[i][j] = __builtin_amdgcn_mfma_f32_16x16x32_bf16(af[j][kk], bfr, acc[i][j], 0, 0, 0);
    }
  }
  // ---- store bf16 NHWC [px][32] ----
#pragma unroll
  for (int i = 0; i < 4; ++i) {
    int sp = pixBase + (mt0 + i) * 16 + ln15;
#pragma unroll
    for (int j = 0; j < 2; ++j) {
      f32x4 a = acc[i][j];
      uint2 stv; stv.x = pk(a[0], a[1]); stv.y = pk(a[2], a[3]);
      *(uint2*)&out[(size_t)sp * 32 + j * 16 + quad * 4] = stv;
    }
  }
  // ---- fused batch stats (16-lane reduce like tconv OSTAT) ----
#pragma unroll
  for (int j = 0; j < 2; ++j)
#pragma unroll
    for (int r = 0; r < 4; ++r) {
      float s = 0.f, q = 0.f;
#pragma unroll
      for (int i = 0; i < 4; ++i) {
        float v = acc[i][j][r];
        s += v; q = fmaf(v, v, q);
      }
#pragma unroll
      for (int mk = 1; mk < 16; mk <<= 1) {
        s += __shfl_xor(s, mk);
        q += __shfl_xor(q, mk);
      }
      if (ln15 == 0) {
        int ch = j * 16 + quad * 4 + r;
        atomicAdd(&sst[ch], s);
        atomicAdd(&ssq[ch], q);
      }
    }
  __syncthreads();
  if (tid < 32) {
    float* d = stOut + (size_t)(blockIdx.x & 7) * 64;
    atomicAdd(&d[tid], sst[tid]);
    atomicAdd(&d[32 + tid], ssq[tid]);
  }
}

// ===================== prep: ALL weight transforms + codebook, one dispatch ======
__device__ __forceinline__ void enc_tr(const float* __restrict__ w,
    ushort* __restrict__ o, int Co, int Ci, int idx) {
  int ci = idx % Ci; int r = idx / Ci; int co = r % Co; int t = r / Co;
  o[idx] = f2bf(w[(co * Ci + ci) * 16 + t]);
}
__device__ __forceinline__ float dec_comb(const float* __restrict__ w,
    int Ci, int co, int ci, int pt) {
  int p = pt >> 2, t = pt & 3;
  int ph = p >> 1, pw = p & 1, rr = t >> 1, cc = t & 1;
  int rs = (rr == 0) ? 0 : (ph == 0 ? 1 : 2);
  int re = (rr == 0) ? (ph == 0 ? 1 : 2) : 3;
  int cs = (cc == 0) ? 0 : (pw == 0 ? 1 : 2);
  int ce = (cc == 0) ? (pw == 0 ? 1 : 2) : 3;
  float s = 0.f;
  for (int kh = rs; kh < re; ++kh)
    for (int kw = cs; kw < ce; ++kw)
      s += w[((co * Ci + ci) * 3 + kh) * 3 + kw];
  return s;
}
__device__ __forceinline__ void dec_tr(const float* __restrict__ w,
    ushort* __restrict__ o, int Co, int Ci, int idx) {
  int ci = idx % Ci; int r = idx / Ci; int co = r % Co; int pt = r / Co;
  o[idx] = f2bf(dec_comb(w, Ci, co, ci, pt));
}

__global__ __launch_bounds__(256) void prep_all(
    const float* __restrict__ ce1_w,
    const float* __restrict__ ce2_w, const float* __restrict__ ce3_w,
    const float* __restrict__ ce4_w, const float* __restrict__ ce5_w,
    const float* __restrict__ cd0_w, const float* __restrict__ cd1_w,
    const float* __restrict__ cd2_w, const float* __restrict__ cd3_w,
    const float* __restrict__ cd4_w, const float* __restrict__ cd4_b,
    const float* __restrict__ codebook,
    ushort* __restrict__ wce1b,
    ushort* __restrict__ wce2, ushort* __restrict__ wce3, ushort* __restrict__ wce4,
    ushort* __restrict__ wce5, ushort* __restrict__ wcd0, ushort* __restrict__ wcd1,
    ushort* __restrict__ wcd2, ushort* __restrict__ wcd3, ushort* __restrict__ wcd4,
    float* __restrict__ cd4bp, ushort* __restrict__ cbbf, float* __restrict__ wsq) {
  __shared__ float sh[4];
  int bx = blockIdx.x, tid = threadIdx.x;
  if (bx < 2048) { int i = bx * 256 + tid; cbbf[i] = f2bf(codebook[i]); return; }
  bx -= 2048;
  if (bx < 512) {
    int k = bx;
    float s = 0.f;
    for (int d = tid; d < 1024; d += 256) {
      float v = codebook[k * 1024 + d];
      s = fmaf(v, v, s);
    }
#pragma unroll
    for (int o = 32; o > 0; o >>= 1) s += __shfl_down(s, o);
    if ((tid & 63) == 0) sh[tid >> 6] = s;
    __syncthreads();
    if (tid == 0) wsq[k] = sh[0] + sh[1] + sh[2] + sh[3];
    return;
  }
  bx -= 512;
  if (bx < 2048) { enc_tr(ce4_w, wce4, 256, 128, bx * 256 + tid); return; }
  bx -= 2048;
  if (bx < 2048) { dec_tr(cd1_w, wcd1, 128, 256, bx * 256 + tid); return; }
  bx -= 2048;
  if (bx < 512)  { enc_tr(ce3_w, wce3, 128, 64, bx * 256 + tid); return; }
  bx -= 512;
  if (bx < 512)  { dec_tr(cd2_w, wcd2, 64, 128, bx * 256 + tid); return; }
  bx -= 512;
  if (bx < 128)  { enc_tr(ce2_w, wce2, 64, 32, bx * 256 + tid); return; }
  bx -= 128;
  if (bx < 128)  { dec_tr(cd3_w, wcd3, 32, 64, bx * 256 + tid); return; }
  bx -= 128;
  if (bx < 64)   { int i = bx * 256 + tid; wce5[i] = f2bf(ce5_w[i]); return; }
  bx -= 64;
  if (bx < 64)   { int i = bx * 256 + tid; wcd0[i] = f2bf(cd0_w[i]); return; }
  bx -= 64;
  if (bx < 32) {                // cd4 padded: [16 taps][16 co][32 ci]
    int idx = bx * 256 + tid;   // 32 blocks
    int ci = idx & 31; int r = idx >> 5; int co = r & 15; int pt = r >> 4;
    wcd4[idx] = (co < 3) ? f2bf(dec_comb(cd4_w, 32, co, ci, pt)) : (ushort)0;
    if (bx == 0 && tid < 16) cd4bp[tid] = (tid < 3) ? cd4_b[tid] : 0.f;
    return;
  }
  bx -= 32;
  {                             // ce1 bf16 weights: [32 co][64 k], k>=48 zero; 8 blocks
    int idx = bx * 256 + tid;   // 0..2047
    int k = idx & 63, co = idx >> 6;
    wce1b[idx] = (k < 48) ? f2bf(ce1_w[co * 48 + k]) : (ushort)0;
  }
}

// ===================== VQ ==========
__global__ __launch_bounds__(256) void zprep(const ushort* __restrict__ r5,
    const float* __restrict__ st, const float* __restrict__ g,
    const float* __restrict__ bb, float* __restrict__ Z, ushort* __restrict__ Zbf) {
  __shared__ float lsc[64], lsh[64];
  int tid = threadIdx.x;
  if (tid < 64) {
    float s = 0.f, q = 0.f;
#pragma unroll
    for (int sl = 0; sl < 8; ++sl) { s += st[sl * 128 + tid]; q += st[sl * 128 + 64 + tid]; }
    float m = s * (1.0f / 8192.f);
    float var = fmaf(q, 1.0f / 8192.f, -m * m);
    float sc = g[tid] * rsqrtf(var + 1e-5f);
    lsc[tid] = sc;
    lsh[tid] = fmaf(-m, sc, bb[tid]);
  }
  __syncthreads();
  int i = blockIdx.x * 256 + tid;
  int c = i & 63;
  float f = fmaf(bf2f(r5[i]), lsc[c], lsh[c]);
  f = f > 0.f ? f : 0.01f * f;
  Z[i] = f;
  Zbf[i] = f2bf(f);
}

// S_ks[b][k] partial dot over K-slice ks (4 slices). Grid (8,8,4).
__global__ __launch_bounds__(256) void vq_gemm(const ushort* __restrict__ Zbf,
    const ushort* __restrict__ cbbf, float* __restrict__ S) {
  __shared__ __align__(16) ushort lZ[64 * 40], lW[64 * 40];
  const int tid = threadIdx.x, wave = tid >> 6, ln15 = tid & 15, quad = (tid & 63) >> 4;
  const int b0 = blockIdx.x * 64, k0 = blockIdx.y * 64, ks = blockIdx.z;
  f32x4 acc[4];
#pragma unroll
  for (int j = 0; j < 4; ++j) acc[j] = (f32x4)(0.f);
  const uint4* zs = (const uint4*)Zbf;
  const uint4* ws = (const uint4*)cbbf;
#pragma unroll 1
  for (int c0 = ks * 256; c0 < ks * 256 + 256; c0 += 32) {
    __syncthreads();
    for (int i = tid; i < 512; i += 256) {
      int ciu4 = i & 3; int rl = (i >> 2) & 63; bool isW = i >= 256;
      uint4 v = (isW ? ws : zs)[(size_t)((isW ? k0 : b0) + rl) * 128 + (c0 >> 3) + ciu4];
      *(uint4*)&((uint*)(isW ? lW : lZ))[rl * 20 + ciu4 * 4] = v;
    }
    __syncthreads();
    bf16x8 bfr = *(const bf16x8*)&lZ[(wave * 16 + ln15) * 40 + quad * 8];
#pragma unroll
    for (int j = 0; j < 4; ++j) {
      bf16x8 af = *(const bf16x8*)&lW[(j * 16 + ln15) * 40 + quad * 8];
      acc[j] = __builtin_amdgcn_mfma_f32_16x16x32_bf16(af, bfr, acc[j], 0, 0, 0);
    }
  }
  int b = b0 + wave * 16 + ln15;
  float* Sk = S + (size_t)ks * 262144;
#pragma unroll
  for (int j = 0; j < 4; ++j)
    *(f32x4*)&Sk[(size_t)b * 512 + k0 + j * 16 + quad * 4] = acc[j];
}

// fused: argmin scan + gather Zq + exact fp32 loss + last-block writes losses
__global__ __launch_bounds__(256) void vq_post(const float* __restrict__ S,
    const float* __restrict__ wsq, const float* __restrict__ Z,
    const float* __restrict__ cb, ushort* __restrict__ Zq,
    float* __restrict__ lossAcc, int* __restrict__ cnt, float* __restrict__ out2) {
  int b = blockIdx.x, tid = threadIdx.x;
  float s1 = 0.f, s2 = 0.f;
#pragma unroll
  for (int sl = 0; sl < 4; ++sl) {
    s1 += S[(size_t)sl * 262144 + (size_t)b * 512 + tid];
    s2 += S[(size_t)sl * 262144 + (size_t)b * 512 + tid + 256];
  }
  float d1 = fmaf(-2.f, s1, wsq[tid]);
  float d2 = fmaf(-2.f, s2, wsq[tid + 256]);
  float bv = d1; int bk = tid;
  if (d2 < bv) { bv = d2; bk = tid + 256; }
  __shared__ float vsh[256]; __shared__ int ish[256];
  vsh[tid] = bv; ish[tid] = bk;
  __syncthreads();
  for (int s = 128; s > 0; s >>= 1) {
    if (tid < s) {
      float ov = vsh[tid + s]; int oi = ish[tid + s];
      if (ov < vsh[tid] || (ov == vsh[tid] && oi < ish[tid])) { vsh[tid] = ov; ish[tid] = oi; }
    }
    __syncthreads();
  }
  int k = ish[0];
  const float* w = cb + ((long)k << 10);
  const float* zp = Z + ((long)b << 10);
  float part = 0.f;
  for (int d = tid; d < 1024; d += 256) {
    float wv = w[d];
    float diff = zp[d] - wv;
    part = fmaf(diff, diff, part);
    Zq[(b << 10) + d] = f2bf(wv);
  }
#pragma unroll
  for (int o = 32; o > 0; o >>= 1) part += __shfl_down(part, o);
  __shared__ float sh[4];
  if ((tid & 63) == 0) sh[tid >> 6] = part;
  __syncthreads();
  if (tid == 0) {
    atomicAdd(lossAcc, sh[0] + sh[1] + sh[2] + sh[3]);
    __threadfence();
    int old = atomicAdd(cnt, 1);
    if (old == 511) {
      float v = *(volatile float*)lossAcc * (1.0f / 512.0f);
      out2[0] = v;
      out2[1] = v;
    }
  }
}

// ===================== launch ==========
extern "C" void kernel_launch(void* const* d_in, const int* in_sizes, int n_in,
                              void* d_out, int out_size, void* d_ws, size_t ws_size,
                              hipStream_t stream) {
  const float* x      = (const float*)d_in[0];
  const float* ce1_w  = (const float*)d_in[1];  const float* ce1_b = (const float*)d_in[2];
  const float* ce2_w  = (const float*)d_in[3];  const float* ce2_b = (const float*)d_in[4];
  const float* ce3_w  = (const float*)d_in[5];  const float* ce3_b = (const float*)d_in[6];
  const float* ce4_w  = (const float*)d_in[7];  const float* ce4_b = (const float*)d_in[8];
  const float* ce5_w  = (const float*)d_in[9];  const float* ce5_b = (const float*)d_in[10];
  const float* cd0_w  = (const float*)d_in[11]; const float* cd0_b = (const float*)d_in[12];
  const float* cd1_w  = (const float*)d_in[13]; const float* cd1_b = (const float*)d_in[14];
  const float* cd2_w  = (const float*)d_in[15]; const float* cd2_b = (const float*)d_in[16];
  const float* cd3_w  = (const float*)d_in[17]; const float* cd3_b = (const float*)d_in[18];
  const float* cd4_w  = (const float*)d_in[19]; const float* cd4_b = (const float*)d_in[20];
  const float* bn_e1_g = (const float*)d_in[21]; const float* bn_e1_b = (const float*)d_in[22];
  const float* bn_e2_g = (const float*)d_in[23]; const float* bn_e2_b = (const float*)d_in[24];
  const float* bn_e3_g = (const float*)d_in[25]; const float* bn_e3_b = (const float*)d_in[26];
  const float* bn_e4_g = (const float*)d_in[27]; const float* bn_e4_b = (const float*)d_in[28];
  const float* bn_e5_g = (const float*)d_in[29]; const float* bn_e5_b = (const float*)d_in[30];
  const float* bn_d0_g = (const float*)d_in[31]; const float* bn_d0_b = (const float*)d_in[32];
  const float* bn_d1_g = (const float*)d_in[33]; const float* bn_d1_b = (const float*)d_in[34];
  const float* bn_d2_g = (const float*)d_in[35]; const float* bn_d2_b = (const float*)d_in[36];
  const float* bn_d3_g = (const float*)d_in[37]; const float* bn_d3_b = (const float*)d_in[38];
  const float* codebook = (const float*)d_in[39];

  float* out = (float*)d_out;

  // ---- workspace carve ----
  char* p = (char*)d_ws;
  auto alloc = [&](size_t bytes) { void* r = p; p += (bytes + 255) & ~(size_t)255; return r; };
  ushort* r1 = (ushort*)alloc((size_t)524288 * 32 * 2);
  ushort* r2 = (ushort*)alloc((size_t)131072 * 64 * 2);
  ushort* r3 = (ushort*)alloc((size_t)32768 * 128 * 2);
  ushort* r4 = (ushort*)alloc((size_t)8192 * 256 * 2);
  ushort* r5 = (ushort*)alloc((size_t)8192 * 64 * 2);
  ushort* d0 = (ushort*)alloc((size_t)8192 * 256 * 2);
  ushort* d1 = (ushort*)alloc((size_t)32768 * 128 * 2);
  ushort* d2 = (ushort*)alloc((size_t)131072 * 64 * 2);
  ushort* d3 = (ushort*)alloc((size_t)524288 * 32 * 2);
  float*  Z    = (float*)alloc((size_t)524288 * 4);
  ushort* Zbf  = (ushort*)alloc((size_t)524288 * 2);
  ushort* cbbf = (ushort*)alloc((size_t)524288 * 2);
  float*  S    = (float*)alloc((size_t)4 * 262144 * 4);   // 4 K-slices
  ushort* Zq   = (ushort*)alloc((size_t)524288 * 2);
  float*  wsq  = (float*)alloc((size_t)512 * 4);
  ushort* wce2 = (ushort*)alloc((size_t)16 * 64 * 32 * 2);
  ushort* wce3 = (ushort*)alloc((size_t)16 * 128 * 64 * 2);
  ushort* wce4 = (ushort*)alloc((size_t)16 * 256 * 128 * 2);
  ushort* wce5 = (ushort*)alloc((size_t)64 * 256 * 2);
  ushort* wcd0 = (ushort*)alloc((size_t)256 * 64 * 2);
  ushort* wcd1 = (ushort*)alloc((size_t)16 * 128 * 256 * 2);
  ushort* wcd2 = (ushort*)alloc((size_t)16 * 64 * 128 * 2);
  ushort* wcd3 = (ushort*)alloc((size_t)16 * 32 * 64 * 2);
  ushort* wcd4 = (ushort*)alloc((size_t)16 * 16 * 32 * 2);
  ushort* wce1b = (ushort*)alloc((size_t)32 * 64 * 2);
  float*  cd4bp = (float*)alloc(64);
  float*  statsAll = (float*)alloc((size_t)(9 * 4096 + 64) * 4);
  int*    jbuf = (int*)alloc((size_t)512 * 4);

  float* st_e1 = statsAll + 0 * 4096;
  float* st_e2 = statsAll + 1 * 4096;
  float* st_e3 = statsAll + 2 * 4096;
  float* st_e4 = statsAll + 3 * 4096;
  float* st_e5 = statsAll + 4 * 4096;
  float* st_d0 = statsAll + 5 * 4096;
  float* st_d1 = statsAll + 6 * 4096;
  float* st_d2 = statsAll + 7 * 4096;
  float* st_d3 = statsAll + 8 * 4096;
  float* lossAcc = statsAll + 9 * 4096;
  int*   cnt = (int*)(lossAcc + 1);

  hipMemsetAsync(statsAll, 0, (size_t)(9 * 4096 + 64) * 4, stream);

  prep_all<<<8104, 256, 0, stream>>>(ce1_w, ce2_w, ce3_w, ce4_w, ce5_w, cd0_w, cd1_w,
      cd2_w, cd3_w, cd4_w, cd4_b, codebook,
      wce1b, wce2, wce3, wce4, wce5, wcd0, wcd1, wcd2, wcd3, wcd4, cd4bp, cbbf, wsq);

  // ---- encoder ----
  ce1_mfma<<<2048, 256, 0, stream>>>(x, wce1b, ce1_b, r1, st_e1);
  tconv<1, 32, 64, 32, 8, 4, 2, 1, 1, true, true, false><<<dim3(1024, 1), 256, 0, stream>>>(
      r1, wce2, ce2_b, st_e1, bn_e1_g, bn_e1_b, r2, st_e2);
  tconv<1, 64, 128, 16, 8, 4, 2, 1, 1, true, true, false><<<dim3(512, 1), 256, 0, stream>>>(
      r2, wce3, ce3_b, st_e2, bn_e2_g, bn_e2_b, r3, st_e3);
  // ce4: NB=4 images/block -> WM=4 (4 MFMA per weight load, was 1:1 @ 69us)
  tconv<1, 128, 256, 8, 4, 4, 4, 1, 4, true, true, false><<<dim3(128, 1), 256, 0, stream>>>(
      r3, wce4, ce4_b, st_e3, bn_e3_g, bn_e3_b, r4, st_e4);
  g1x1<256, 64, 16, true, 8192, true><<<dim3(128, 4), 256, 0, stream>>>(
      r4, wce5, ce5_b, st_e4, bn_e4_g, bn_e4_b, r5, st_e5);

  // ---- VQ ----
  zprep<<<2048, 256, 0, stream>>>(r5, st_e5, bn_e5_g, bn_e5_b, Z, Zbf);
  vq_gemm<<<dim3(8, 8, 4), 256, 0, stream>>>(Zbf, cbbf, S);
  vq_post<<<512, 256, 0, stream>>>(S, wsq, Z, codebook, Zq, lossAcc, cnt, out + 6291456);

  // ---- decoder ----
  g1x1<64, 256, 32, false, 1, true><<<dim3(128, 8), 256, 0, stream>>>(
      Zq, wcd0, cd0_b, nullptr, nullptr, nullptr, d0, st_d0);
  tconv<2, 256, 128, 4, 4, 4, 4, 2, 4, true, true, false><<<dim3(128, 2), 256, 0, stream>>>(
      d0, wcd1, cd1_b, st_d0, bn_d0_g, bn_d0_b, d1, st_d1);
  tconv<2, 128, 64, 8, 8, 4, 4, 1, 1, true, true, false><<<dim3(512, 1), 256, 0, stream>>>(
      d1, wcd2, cd2_b, st_d1, bn_d1_g, bn_d1_b, d2, st_d2);
  tconv<2, 64, 32, 16, 8, 8, 2, 1, 1, true, true, false><<<dim3(1024, 1), 256, 0, stream>>>(
      d2, wcd3, cd3_b, st_d2, bn_d2_g, bn_d2_b, d3, st_d3);
  tconv<2, 32, 16, 32, 4, 8, 1, 1, 1, true, false, true><<<dim3(4096, 1), 256, 0, stream>>>(
      d3, wcd4, cd4bp, st_d3, bn_d3_g, bn_d3_b, out, nullptr);
}

// Round 8
// 434.049 us; speedup vs baseline: 1.2314x; 1.0468x over previous
//
#include <hip/hip_runtime.h>
#include <hip/hip_bf16.h>
#include <math.h>

typedef __attribute__((ext_vector_type(8))) short bf16x8;
typedef __attribute__((ext_vector_type(4))) float f32x4;

__device__ __forceinline__ float bf2f(ushort u) {
  union { uint i; float f; } t; t.i = ((uint)u) << 16; return t.f;
}
__device__ __forceinline__ ushort f2bf(float f) {
  __hip_bfloat16 h = __float2bfloat16(f);
  return *reinterpret_cast<ushort*>(&h);
}
__device__ __forceinline__ uint pk(float a, float b) {
  return (uint)f2bf(a) | ((uint)f2bf(b) << 16);
}
constexpr int ilog2c(int v) { int r = 0; while (v > 1) { v >>= 1; ++r; } return r; }

// =====================================================================
// Tiled MFMA conv, fused input-BN+LReLU, fused output batch-stats,
// co-split across blockIdx.y (CS) for occupancy.
// MODE 1: k4s2p1 encoder. MODE 2: up2+3x3 decoder (wave = parity class).
// NB: images per block: raises WM so each weight load feeds WM MFMAs.
// R7: keep ratio >=4:1 BUT grid >=256 (ce4 at grid 128 = half the CUs idle,
// Occupancy 5%, 49.6us). ce4 now NB=4/WM=4/WN=1/CS=4 -> grid 512, 4:1.
// SIG: fp32 NCHW sigmoid output (cd4, Co padded to 16, real 3).
// =====================================================================
template<int MODE, int Ci, int Co, int HIN, int TR, int WM, int WN, int CS,
         int NB, bool BN, bool OSTAT, bool SIG>
__global__ __launch_bounds__(256) void tconv(const ushort* __restrict__ in,
    const ushort* __restrict__ wt, const float* __restrict__ bias,
    const float* __restrict__ st, const float* __restrict__ g,
    const float* __restrict__ bb, void* __restrict__ out_,
    float* __restrict__ stOut) {
  constexpr int W    = (MODE == 1) ? HIN / 2 : HIN;
  constexpr int LW   = ilog2c(W);
  constexpr int R_IN = (MODE == 1) ? 2 * TR + 2 : TR + 2;
  constexpr int W2   = HIN + 2;
  constexpr int MTPI = TR * W / 16;        // M-tiles per image
  constexpr int MT   = NB * MTPI;          // M-tiles per block
  constexpr int NG   = Co / 16;
  constexpr int NGB  = NG / CS;            // co groups per block
  constexpr int COB  = NGB * 16;           // channels per block
  constexpr int TAPS = (MODE == 1) ? 16 : 4;
  constexpr int RB   = W / TR;
  constexpr int CB   = BN ? Ci : 1;
  constexpr int SB   = OSTAT ? COB : 1;
  constexpr int SN4P = R_IN * W2 * 4;      // 16B staging units per image
  static_assert(TR * W % 16 == 0, "mtile");
  static_assert(MODE == 2 ? (WM == MT && WN == NGB)
                          : ((MT % WM == 0) && (NGB % WN == 0) &&
                             (MT / WM) * (NGB / WN) == 4),
                "wave map");

  __shared__ __align__(16) ushort lt[NB * R_IN * W2 * 40];
  __shared__ float lsc[CB], lsh[CB];
  __shared__ float sst[SB], ssq[SB];

  const int tid  = threadIdx.x;
  const int wave = tid >> 6;
  const int ln15 = tid & 15;
  const int quad = (tid & 63) >> 4;
  const int rb = blockIdx.x % RB;
  const int n0 = (blockIdx.x / RB) * NB;
  const int h0 = rb * TR;
  const int cbase = blockIdx.y * NGB;      // co-group base for this block

  if (BN) {
    constexpr float inv_cnt = 1.0f / (float)(512 * HIN * HIN);
    for (int c = tid; c < Ci; c += 256) {
      float s = 0.f, q = 0.f;
#pragma unroll
      for (int sl = 0; sl < 8; ++sl) {
        s += st[sl * 2 * Ci + c];
        q += st[sl * 2 * Ci + Ci + c];
      }
      float m = s * inv_cnt;
      float var = fmaf(q, inv_cnt, -m * m);
      float sc = g[c] * rsqrtf(var + 1e-5f);
      lsc[c] = sc;
      lsh[c] = fmaf(-m, sc, bb[c]);
    }
  }

  int mt0, cg0, ph, pw, pb;
  if (MODE == 2) { mt0 = 0; cg0 = cbase; ph = wave >> 1; pw = wave & 1; pb = wave * 4; }
  else {
    constexpr int MW = MT / WM;
    mt0 = (wave % MW) * WM; cg0 = cbase + (wave / MW) * WN; ph = 0; pw = 0; pb = 0;
  }

  f32x4 acc[WM][WN];
#pragma unroll
  for (int j = 0; j < WN; ++j) {
    f32x4 b4 = *(const f32x4*)&bias[(cg0 + j) * 16 + quad * 4];
#pragma unroll
    for (int i = 0; i < WM; ++i) acc[i][j] = b4;
  }

  const uint4* src4 = (const uint4*)in;
  const int gr0 = (MODE == 1) ? 2 * h0 - 1 : h0 - 1;

#pragma unroll 1
  for (int c0 = 0; c0 < Ci; c0 += 32) {
    __syncthreads();
    for (int i = tid; i < NB * SN4P; i += 256) {
      int img = (NB == 1) ? 0 : (i / SN4P);
      int ii  = (NB == 1) ? i : (i % SN4P);
      int ciu4 = ii & 3; int t2 = ii >> 2; int c = t2 % W2; int r = t2 / W2;
      int gr = gr0 + r, gc = c - 1;
      uint4 v4 = make_uint4(0u, 0u, 0u, 0u);
      if ((unsigned)gr < (unsigned)HIN && (unsigned)gc < (unsigned)HIN) {
        v4 = src4[((size_t)((n0 + img) * HIN + gr) * HIN + gc) * (Ci / 8) + (c0 >> 3) + ciu4];
        if (BN) {
          uint* pu = (uint*)&v4;
#pragma unroll
          for (int k2 = 0; k2 < 4; ++k2) {
            int cc = c0 + ciu4 * 8 + k2 * 2;
            float f0 = fmaf(bf2f((ushort)(pu[k2] & 0xffffu)), lsc[cc], lsh[cc]);
            float f1 = fmaf(bf2f((ushort)(pu[k2] >> 16)), lsc[cc + 1], lsh[cc + 1]);
            f0 = f0 > 0.f ? f0 : 0.01f * f0;
            f1 = f1 > 0.f ? f1 : 0.01f * f1;
            pu[k2] = pk(f0, f1);
          }
        }
      }
      *(uint4*)&((uint*)lt)[((img * R_IN + r) * W2 + c) * 20 + ciu4 * 4] = v4;
    }
    __syncthreads();

#pragma unroll
    for (int t = 0; t < TAPS; ++t) {
      const int kh = (MODE == 1) ? (t >> 2) : (t >> 1);
      const int kw = (MODE == 1) ? (t & 3) : (t & 1);
      bf16x8 af[WN];
      const ushort* wb = wt + (size_t)(pb + t) * Co * Ci;
#pragma unroll
      for (int j = 0; j < WN; ++j)
        af[j] = *(const bf16x8*)&wb[(size_t)((cg0 + j) * 16 + ln15) * Ci + c0 + quad * 8];
      bf16x8 bfr[WM];
#pragma unroll
      for (int i = 0; i < WM; ++i) {
        int mtile = mt0 + i;
        int img = (NB == 1) ? 0 : (mtile / MTPI);
        int lm  = (NB == 1) ? mtile : (mtile % MTPI);
        int m = lm * 16 + ln15;
        int hr = m >> LW, wr = m & (W - 1);
        int row, col;
        if (MODE == 1) { row = 2 * hr + kh; col = 2 * wr + kw; }
        else           { row = hr + kh + ph; col = wr + kw + pw; }
        bfr[i] = *(const bf16x8*)&lt[((img * R_IN + row) * W2 + col) * 40 + quad * 8];
      }
#pragma unroll
      for (int i = 0; i < WM; ++i)
#pragma unroll
        for (int j = 0; j < WN; ++j)
          acc[i][j] = __builtin_amdgcn_mfma_f32_16x16x32_bf16(af[j], bfr[i], acc[i][j], 0, 0, 0);
    }
  }

  if (OSTAT) {
    for (int c = tid; c < COB; c += 256) { sst[c] = 0.f; ssq[c] = 0.f; }
    __syncthreads();
  }

  if (SIG) {
    constexpr int HO2 = 2 * HIN;
    float* outF = (float*)out_;
#pragma unroll
    for (int i = 0; i < WM; ++i) {
      int mtile = mt0 + i;
      int img = (NB == 1) ? 0 : (mtile / MTPI);
      int lm  = (NB == 1) ? mtile : (mtile % MTPI);
      int m = lm * 16 + ln15;
      int hr = m >> LW, wr = m & (W - 1);
      int oh = 2 * (h0 + hr) + ph, ow = 2 * wr + pw;
      size_t base = (size_t)(n0 + img) * 3 * HO2 * HO2 + (size_t)oh * HO2 + ow;
#pragma unroll
      for (int r = 0; r < 4; ++r) {
        int co = quad * 4 + r;
        if (co < 3)
          outF[base + (size_t)co * HO2 * HO2] = 1.f / (1.f + __expf(-acc[i][0][r]));
      }
    }
  } else {
    ushort* out = (ushort*)out_;
#pragma unroll
    for (int i = 0; i < WM; ++i) {
      int mtile = mt0 + i;
      int img = (NB == 1) ? 0 : (mtile / MTPI);
      int lm  = (NB == 1) ? mtile : (mtile % MTPI);
      int m = lm * 16 + ln15;
      int hr = m >> LW, wr = m & (W - 1);
      size_t sp;
      if (MODE == 2) {
        int oh = 2 * (h0 + hr) + ph, ow = 2 * wr + pw;
        sp = ((size_t)(n0 + img) * (2 * HIN) + oh) * (2 * HIN) + ow;
      } else {
        sp = ((size_t)(n0 + img) * W + h0 + hr) * W + wr;
      }
#pragma unroll
      for (int j = 0; j < WN; ++j) {
        f32x4 a = acc[i][j];
        uint2 stv; stv.x = pk(a[0], a[1]); stv.y = pk(a[2], a[3]);
        *(uint2*)&out[sp * Co + (cg0 + j) * 16 + quad * 4] = stv;
      }
    }
  }

  if (OSTAT) {
#pragma unroll
    for (int j = 0; j < WN; ++j)
#pragma unroll
      for (int r = 0; r < 4; ++r) {
        float s = 0.f, q = 0.f;
#pragma unroll
        for (int i = 0; i < WM; ++i) {
          float v = acc[i][j][r];
          s += v; q = fmaf(v, v, q);
        }
#pragma unroll
        for (int mk = 1; mk < 16; mk <<= 1) {
          s += __shfl_xor(s, mk);
          q += __shfl_xor(q, mk);
        }
        if (ln15 == 0) {
          int lc = (cg0 + j) * 16 + quad * 4 + r - cbase * 16;
          atomicAdd(&sst[lc], s);
          atomicAdd(&ssq[lc], q);
        }
      }
    __syncthreads();
    float* d = stOut + (size_t)(blockIdx.x & 7) * 2 * Co;
    for (int c = tid; c < COB; c += 256) {
      atomicAdd(&d[cbase * 16 + c], sst[c]);
      atomicAdd(&d[Co + cbase * 16 + c], ssq[c]);
    }
  }
}

// ===================== 1x1 conv GEMM, fused input-BN + output stats ==========
template<int Ci, int Co, int COT, bool BN, int NPIX, bool OSTAT>
__global__ __launch_bounds__(256) void g1x1(const ushort* __restrict__ in,
    const ushort* __restrict__ wt, const float* __restrict__ bias,
    const float* __restrict__ st, const float* __restrict__ g,
    const float* __restrict__ bb, ushort* __restrict__ out,
    float* __restrict__ stOut) {
  constexpr int NG = COT / 16;
  constexpr int CB = BN ? Ci : 1;
  constexpr int SB = OSTAT ? COT : 1;
  __shared__ __align__(16) ushort lb[64 * 40];
  __shared__ float lsc[CB], lsh[CB];
  __shared__ float sst[SB], ssq[SB];
  const int tid = threadIdx.x, wave = tid >> 6, ln15 = tid & 15, quad = (tid & 63) >> 4;
  const int pixBase = blockIdx.x * 64;
  const int co0 = blockIdx.y * COT;
  if (BN) {
    constexpr float inv_cnt = 1.0f / (float)NPIX;
    for (int c = tid; c < Ci; c += 256) {
      float s = 0.f, q = 0.f;
#pragma unroll
      for (int sl = 0; sl < 8; ++sl) {
        s += st[sl * 2 * Ci + c];
        q += st[sl * 2 * Ci + Ci + c];
      }
      float m = s * inv_cnt;
      float var = fmaf(q, inv_cnt, -m * m);
      float sc = g[c] * rsqrtf(var + 1e-5f);
      lsc[c] = sc;
      lsh[c] = fmaf(-m, sc, bb[c]);
    }
  }
  f32x4 acc[NG];
#pragma unroll
  for (int j = 0; j < NG; ++j) acc[j] = *(const f32x4*)&bias[co0 + j * 16 + quad * 4];
  const uint4* src4 = (const uint4*)in;
#pragma unroll 1
  for (int c0 = 0; c0 < Ci; c0 += 32) {
    __syncthreads();
    {
      int ciu4 = tid & 3, pl = tid >> 2;
      uint4 v4 = src4[(size_t)(pixBase + pl) * (Ci / 8) + (c0 >> 3) + ciu4];
      if (BN) {
        uint* pu = (uint*)&v4;
#pragma unroll
        for (int k2 = 0; k2 < 4; ++k2) {
          int cc = c0 + ciu4 * 8 + k2 * 2;
          float f0 = fmaf(bf2f((ushort)(pu[k2] & 0xffffu)), lsc[cc], lsh[cc]);
          float f1 = fmaf(bf2f((ushort)(pu[k2] >> 16)), lsc[cc + 1], lsh[cc + 1]);
          f0 = f0 > 0.f ? f0 : 0.01f * f0;
          f1 = f1 > 0.f ? f1 : 0.01f * f1;
          pu[k2] = pk(f0, f1);
        }
      }
      *(uint4*)&((uint*)lb)[pl * 20 + ciu4 * 4] = v4;
    }
    __syncthreads();
    bf16x8 bfr = *(const bf16x8*)&lb[(wave * 16 + ln15) * 40 + quad * 8];
#pragma unroll
    for (int j = 0; j < NG; ++j) {
      bf16x8 af = *(const bf16x8*)&wt[(size_t)(co0 + j * 16 + ln15) * Ci + c0 + quad * 8];
      acc[j] = __builtin_amdgcn_mfma_f32_16x16x32_bf16(af, bfr, acc[j], 0, 0, 0);
    }
  }
  if (OSTAT) {
    for (int c = tid; c < COT; c += 256) { sst[c] = 0.f; ssq[c] = 0.f; }
    __syncthreads();
  }
  int pix = pixBase + wave * 16 + ln15;
#pragma unroll
  for (int j = 0; j < NG; ++j) {
    uint2 stv; stv.x = pk(acc[j][0], acc[j][1]); stv.y = pk(acc[j][2], acc[j][3]);
    *(uint2*)&out[(size_t)pix * Co + co0 + j * 16 + quad * 4] = stv;
  }
  if (OSTAT) {
#pragma unroll
    for (int j = 0; j < NG; ++j)
#pragma unroll
      for (int r = 0; r < 4; ++r) {
        float s = acc[j][r];
        float q = s * s;
#pragma unroll
        for (int mk = 1; mk < 16; mk <<= 1) {
          s += __shfl_xor(s, mk);
          q += __shfl_xor(q, mk);
        }
        if (ln15 == 0) {
          int cl = j * 16 + quad * 4 + r;
          atomicAdd(&sst[cl], s);
          atomicAdd(&ssq[cl], q);
        }
      }
    __syncthreads();
    float* d = stOut + (size_t)(blockIdx.x & 7) * 2 * Co;
    for (int c = tid; c < COT; c += 256) {
      atomicAdd(&d[co0 + c], sst[c]);
      atomicAdd(&d[Co + co0 + c], ssq[c]);
    }
  }
}

// ===================== ce1 (MFMA): k4s2p1, Ci=3, fp32 NCHW -> bf16 NHWC + stats ===
__global__ __launch_bounds__(256) void ce1_mfma(const float* __restrict__ x,
    const ushort* __restrict__ wt, const float* __restrict__ bias,
    ushort* __restrict__ out, float* __restrict__ stOut) {
  __shared__ __align__(16) float lt[3 * 18 * 72];   // padded fp32 tile, 15.2 KB
  __shared__ float sst[32], ssq[32];
  const int tid = threadIdx.x, wave = tid >> 6, ln15 = tid & 15, quad = (tid & 63) >> 4;
  const int pixBase = blockIdx.x * 256;     // 8 out rows x 32 cols, one image
  const int n  = pixBase >> 10;
  const int h0 = (pixBase >> 5) & 31;
  if (tid < 32) { sst[tid] = 0.f; ssq[tid] = 0.f; }
  const int gr0 = 2 * h0 - 1;
  for (int i = tid; i < 3 * 18 * 72; i += 256) {
    int c = i % 72; int rem = i / 72; int r = rem % 18; int ci = rem / 18;
    int gr = gr0 + r, gc = c - 1;
    float v = 0.f;
    if ((unsigned)gr < 64u && (unsigned)gc < 64u)
      v = x[(((size_t)n * 3 + ci) << 12) + (gr << 6) + gc];
    lt[i] = v;
  }
  __syncthreads();

  f32x4 acc[4][2];
#pragma unroll
  for (int j = 0; j < 2; ++j) {
    f32x4 b4 = *(const f32x4*)&bias[j * 16 + quad * 4];
#pragma unroll
    for (int i = 0; i < 4; ++i) acc[i][j] = b4;
  }
  bf16x8 af[2][2];
#pragma unroll
  for (int j = 0; j < 2; ++j)
#pragma unroll
    for (int kk = 0; kk < 2; ++kk)
      af[j][kk] = *(const bf16x8*)&wt[(j * 16 + ln15) * 64 + kk * 32 + quad * 8];

  const int mt0 = wave * 4;
#pragma unroll
  for (int i = 0; i < 4; ++i) {
    int p = (mt0 + i) * 16 + ln15;        // px within block
    int h = p >> 5, w = p & 31;           // local out row/col
#pragma unroll
    for (int kk = 0; kk < 2; ++kk) {
      int k0 = kk * 32 + quad * 8;        // k = (ci*16 + kh*4 + kw)
      bf16x8 bfr = (bf16x8)(short)0;
      if (k0 < 48) {
        int ci = k0 >> 4, kh0 = (k0 >> 2) & 3;   // 8 k's = 2 rows x 4 kw
        const float* rp = &lt[(ci * 18 + 2 * h + kh0) * 72 + 2 * w];
        uint4 uu = make_uint4(pk(rp[0], rp[1]), pk(rp[2], rp[3]),
                              pk(rp[72], rp[73]), pk(rp[74], rp[75]));
        bfr = *reinterpret_cast<bf16x8*>(&uu);
      }
#pragma unroll
      for (int j = 0; j < 2; ++j)
        acc[i][j] = __builtin_amdgcn_mfma_f32_16x16x32_bf16(af[j][kk], bfr, acc[i][j], 0, 0, 0);
    }
  }
  // ---- store bf16 NHWC [px][32] ----
#pragma unroll
  for (int i = 0; i < 4; ++i) {
    int sp = pixBase + (mt0 + i) * 16 + ln15;
#pragma unroll
    for (int j = 0; j < 2; ++j) {
      f32x4 a = acc[i][j];
      uint2 stv; stv.x = pk(a[0], a[1]); stv.y = pk(a[2], a[3]);
      *(uint2*)&out[(size_t)sp * 32 + j * 16 + quad * 4] = stv;
    }
  }
  // ---- fused batch stats (16-lane reduce like tconv OSTAT) ----
#pragma unroll
  for (int j = 0; j < 2; ++j)
#pragma unroll
    for (int r = 0; r < 4; ++r) {
      float s = 0.f, q = 0.f;
#pragma unroll
      for (int i = 0; i < 4; ++i) {
        float v = acc[i][j][r];
        s += v; q = fmaf(v, v, q);
      }
#pragma unroll
      for (int mk = 1; mk < 16; mk <<= 1) {
        s += __shfl_xor(s, mk);
        q += __shfl_xor(q, mk);
      }
      if (ln15 == 0) {
        int ch = j * 16 + quad * 4 + r;
        atomicAdd(&sst[ch], s);
        atomicAdd(&ssq[ch], q);
      }
    }
  __syncthreads();
  if (tid < 32) {
    float* d = stOut + (size_t)(blockIdx.x & 7) * 64;
    atomicAdd(&d[tid], sst[tid]);
    atomicAdd(&d[32 + tid], ssq[tid]);
  }
}

// ===================== prep: ALL weight transforms + codebook, one dispatch ======
__device__ __forceinline__ void enc_tr(const float* __restrict__ w,
    ushort* __restrict__ o, int Co, int Ci, int idx) {
  int ci = idx % Ci; int r = idx / Ci; int co = r % Co; int t = r / Co;
  o[idx] = f2bf(w[(co * Ci + ci) * 16 + t]);
}
__device__ __forceinline__ float dec_comb(const float* __restrict__ w,
    int Ci, int co, int ci, int pt) {
  int p = pt >> 2, t = pt & 3;
  int ph = p >> 1, pw = p & 1, rr = t >> 1, cc = t & 1;
  int rs = (rr == 0) ? 0 : (ph == 0 ? 1 : 2);
  int re = (rr == 0) ? (ph == 0 ? 1 : 2) : 3;
  int cs = (cc == 0) ? 0 : (pw == 0 ? 1 : 2);
  int ce = (cc == 0) ? (pw == 0 ? 1 : 2) : 3;
  float s = 0.f;
  for (int kh = rs; kh < re; ++kh)
    for (int kw = cs; kw < ce; ++kw)
      s += w[((co * Ci + ci) * 3 + kh) * 3 + kw];
  return s;
}
__device__ __forceinline__ void dec_tr(const float* __restrict__ w,
    ushort* __restrict__ o, int Co, int Ci, int idx) {
  int ci = idx % Ci; int r = idx / Ci; int co = r % Co; int pt = r / Co;
  o[idx] = f2bf(dec_comb(w, Ci, co, ci, pt));
}

__global__ __launch_bounds__(256) void prep_all(
    const float* __restrict__ ce1_w,
    const float* __restrict__ ce2_w, const float* __restrict__ ce3_w,
    const float* __restrict__ ce4_w, const float* __restrict__ ce5_w,
    const float* __restrict__ cd0_w, const float* __restrict__ cd1_w,
    const float* __restrict__ cd2_w, const float* __restrict__ cd3_w,
    const float* __restrict__ cd4_w, const float* __restrict__ cd4_b,
    const float* __restrict__ codebook,
    ushort* __restrict__ wce1b,
    ushort* __restrict__ wce2, ushort* __restrict__ wce3, ushort* __restrict__ wce4,
    ushort* __restrict__ wce5, ushort* __restrict__ wcd0, ushort* __restrict__ wcd1,
    ushort* __restrict__ wcd2, ushort* __restrict__ wcd3, ushort* __restrict__ wcd4,
    float* __restrict__ cd4bp, ushort* __restrict__ cbbf, float* __restrict__ wsq) {
  __shared__ float sh[4];
  int bx = blockIdx.x, tid = threadIdx.x;
  if (bx < 2048) { int i = bx * 256 + tid; cbbf[i] = f2bf(codebook[i]); return; }
  bx -= 2048;
  if (bx < 512) {
    int k = bx;
    float s = 0.f;
    for (int d = tid; d < 1024; d += 256) {
      float v = codebook[k * 1024 + d];
      s = fmaf(v, v, s);
    }
#pragma unroll
    for (int o = 32; o > 0; o >>= 1) s += __shfl_down(s, o);
    if ((tid & 63) == 0) sh[tid >> 6] = s;
    __syncthreads();
    if (tid == 0) wsq[k] = sh[0] + sh[1] + sh[2] + sh[3];
    return;
  }
  bx -= 512;
  if (bx < 2048) { enc_tr(ce4_w, wce4, 256, 128, bx * 256 + tid); return; }
  bx -= 2048;
  if (bx < 2048) { dec_tr(cd1_w, wcd1, 128, 256, bx * 256 + tid); return; }
  bx -= 2048;
  if (bx < 512)  { enc_tr(ce3_w, wce3, 128, 64, bx * 256 + tid); return; }
  bx -= 512;
  if (bx < 512)  { dec_tr(cd2_w, wcd2, 64, 128, bx * 256 + tid); return; }
  bx -= 512;
  if (bx < 128)  { enc_tr(ce2_w, wce2, 64, 32, bx * 256 + tid); return; }
  bx -= 128;
  if (bx < 128)  { dec_tr(cd3_w, wcd3, 32, 64, bx * 256 + tid); return; }
  bx -= 128;
  if (bx < 64)   { int i = bx * 256 + tid; wce5[i] = f2bf(ce5_w[i]); return; }
  bx -= 64;
  if (bx < 64)   { int i = bx * 256 + tid; wcd0[i] = f2bf(cd0_w[i]); return; }
  bx -= 64;
  if (bx < 32) {                // cd4 padded: [16 taps][16 co][32 ci]
    int idx = bx * 256 + tid;   // 32 blocks
    int ci = idx & 31; int r = idx >> 5; int co = r & 15; int pt = r >> 4;
    wcd4[idx] = (co < 3) ? f2bf(dec_comb(cd4_w, 32, co, ci, pt)) : (ushort)0;
    if (bx == 0 && tid < 16) cd4bp[tid] = (tid < 3) ? cd4_b[tid] : 0.f;
    return;
  }
  bx -= 32;
  {                             // ce1 bf16 weights: [32 co][64 k], k>=48 zero; 8 blocks
    int idx = bx * 256 + tid;   // 0..2047
    int k = idx & 63, co = idx >> 6;
    wce1b[idx] = (k < 48) ? f2bf(ce1_w[co * 48 + k]) : (ushort)0;
  }
}

// ===================== VQ ==========
__global__ __launch_bounds__(256) void zprep(const ushort* __restrict__ r5,
    const float* __restrict__ st, const float* __restrict__ g,
    const float* __restrict__ bb, float* __restrict__ Z, ushort* __restrict__ Zbf) {
  __shared__ float lsc[64], lsh[64];
  int tid = threadIdx.x;
  if (tid < 64) {
    float s = 0.f, q = 0.f;
#pragma unroll
    for (int sl = 0; sl < 8; ++sl) { s += st[sl * 128 + tid]; q += st[sl * 128 + 64 + tid]; }
    float m = s * (1.0f / 8192.f);
    float var = fmaf(q, 1.0f / 8192.f, -m * m);
    float sc = g[tid] * rsqrtf(var + 1e-5f);
    lsc[tid] = sc;
    lsh[tid] = fmaf(-m, sc, bb[tid]);
  }
  __syncthreads();
  int i = blockIdx.x * 256 + tid;
  int c = i & 63;
  float f = fmaf(bf2f(r5[i]), lsc[c], lsh[c]);
  f = f > 0.f ? f : 0.01f * f;
  Z[i] = f;
  Zbf[i] = f2bf(f);
}

// S_ks[b][k] partial dot over K-slice ks (4 slices). Grid (8,8,4).
__global__ __launch_bounds__(256) void vq_gemm(const ushort* __restrict__ Zbf,
    const ushort* __restrict__ cbbf, float* __restrict__ S) {
  __shared__ __align__(16) ushort lZ[64 * 40], lW[64 * 40];
  const int tid = threadIdx.x, wave = tid >> 6, ln15 = tid & 15, quad = (tid & 63) >> 4;
  const int b0 = blockIdx.x * 64, k0 = blockIdx.y * 64, ks = blockIdx.z;
  f32x4 acc[4];
#pragma unroll
  for (int j = 0; j < 4; ++j) acc[j] = (f32x4)(0.f);
  const uint4* zs = (const uint4*)Zbf;
  const uint4* ws = (const uint4*)cbbf;
#pragma unroll 1
  for (int c0 = ks * 256; c0 < ks * 256 + 256; c0 += 32) {
    __syncthreads();
    for (int i = tid; i < 512; i += 256) {
      int ciu4 = i & 3; int rl = (i >> 2) & 63; bool isW = i >= 256;
      uint4 v = (isW ? ws : zs)[(size_t)((isW ? k0 : b0) + rl) * 128 + (c0 >> 3) + ciu4];
      *(uint4*)&((uint*)(isW ? lW : lZ))[rl * 20 + ciu4 * 4] = v;
    }
    __syncthreads();
    bf16x8 bfr = *(const bf16x8*)&lZ[(wave * 16 + ln15) * 40 + quad * 8];
#pragma unroll
    for (int j = 0; j < 4; ++j) {
      bf16x8 af = *(const bf16x8*)&lW[(j * 16 + ln15) * 40 + quad * 8];
      acc[j] = __builtin_amdgcn_mfma_f32_16x16x32_bf16(af, bfr, acc[j], 0, 0, 0);
    }
  }
  int b = b0 + wave * 16 + ln15;
  float* Sk = S + (size_t)ks * 262144;
#pragma unroll
  for (int j = 0; j < 4; ++j)
    *(f32x4*)&Sk[(size_t)b * 512 + k0 + j * 16 + quad * 4] = acc[j];
}

// fused: argmin scan + gather Zq + exact fp32 loss + last-block writes losses
__global__ __launch_bounds__(256) void vq_post(const float* __restrict__ S,
    const float* __restrict__ wsq, const float* __restrict__ Z,
    const float* __restrict__ cb, ushort* __restrict__ Zq,
    float* __restrict__ lossAcc, int* __restrict__ cnt, float* __restrict__ out2) {
  int b = blockIdx.x, tid = threadIdx.x;
  float s1 = 0.f, s2 = 0.f;
#pragma unroll
  for (int sl = 0; sl < 4; ++sl) {
    s1 += S[(size_t)sl * 262144 + (size_t)b * 512 + tid];
    s2 += S[(size_t)sl * 262144 + (size_t)b * 512 + tid + 256];
  }
  float d1 = fmaf(-2.f, s1, wsq[tid]);
  float d2 = fmaf(-2.f, s2, wsq[tid + 256]);
  float bv = d1; int bk = tid;
  if (d2 < bv) { bv = d2; bk = tid + 256; }
  __shared__ float vsh[256]; __shared__ int ish[256];
  vsh[tid] = bv; ish[tid] = bk;
  __syncthreads();
  for (int s = 128; s > 0; s >>= 1) {
    if (tid < s) {
      float ov = vsh[tid + s]; int oi = ish[tid + s];
      if (ov < vsh[tid] || (ov == vsh[tid] && oi < ish[tid])) { vsh[tid] = ov; ish[tid] = oi; }
    }
    __syncthreads();
  }
  int k = ish[0];
  const float* w = cb + ((long)k << 10);
  const float* zp = Z + ((long)b << 10);
  float part = 0.f;
  for (int d = tid; d < 1024; d += 256) {
    float wv = w[d];
    float diff = zp[d] - wv;
    part = fmaf(diff, diff, part);
    Zq[(b << 10) + d] = f2bf(wv);
  }
#pragma unroll
  for (int o = 32; o > 0; o >>= 1) part += __shfl_down(part, o);
  __shared__ float sh[4];
  if ((tid & 63) == 0) sh[tid >> 6] = part;
  __syncthreads();
  if (tid == 0) {
    atomicAdd(lossAcc, sh[0] + sh[1] + sh[2] + sh[3]);
    __threadfence();
    int old = atomicAdd(cnt, 1);
    if (old == 511) {
      float v = *(volatile float*)lossAcc * (1.0f / 512.0f);
      out2[0] = v;
      out2[1] = v;
    }
  }
}

// ===================== launch ==========
extern "C" void kernel_launch(void* const* d_in, const int* in_sizes, int n_in,
                              void* d_out, int out_size, void* d_ws, size_t ws_size,
                              hipStream_t stream) {
  const float* x      = (const float*)d_in[0];
  const float* ce1_w  = (const float*)d_in[1];  const float* ce1_b = (const float*)d_in[2];
  const float* ce2_w  = (const float*)d_in[3];  const float* ce2_b = (const float*)d_in[4];
  const float* ce3_w  = (const float*)d_in[5];  const float* ce3_b = (const float*)d_in[6];
  const float* ce4_w  = (const float*)d_in[7];  const float* ce4_b = (const float*)d_in[8];
  const float* ce5_w  = (const float*)d_in[9];  const float* ce5_b = (const float*)d_in[10];
  const float* cd0_w  = (const float*)d_in[11]; const float* cd0_b = (const float*)d_in[12];
  const float* cd1_w  = (const float*)d_in[13]; const float* cd1_b = (const float*)d_in[14];
  const float* cd2_w  = (const float*)d_in[15]; const float* cd2_b = (const float*)d_in[16];
  const float* cd3_w  = (const float*)d_in[17]; const float* cd3_b = (const float*)d_in[18];
  const float* cd4_w  = (const float*)d_in[19]; const float* cd4_b = (const float*)d_in[20];
  const float* bn_e1_g = (const float*)d_in[21]; const float* bn_e1_b = (const float*)d_in[22];
  const float* bn_e2_g = (const float*)d_in[23]; const float* bn_e2_b = (const float*)d_in[24];
  const float* bn_e3_g = (const float*)d_in[25]; const float* bn_e3_b = (const float*)d_in[26];
  const float* bn_e4_g = (const float*)d_in[27]; const float* bn_e4_b = (const float*)d_in[28];
  const float* bn_e5_g = (const float*)d_in[29]; const float* bn_e5_b = (const float*)d_in[30];
  const float* bn_d0_g = (const float*)d_in[31]; const float* bn_d0_b = (const float*)d_in[32];
  const float* bn_d1_g = (const float*)d_in[33]; const float* bn_d1_b = (const float*)d_in[34];
  const float* bn_d2_g = (const float*)d_in[35]; const float* bn_d2_b = (const float*)d_in[36];
  const float* bn_d3_g = (const float*)d_in[37]; const float* bn_d3_b = (const float*)d_in[38];
  const float* codebook = (const float*)d_in[39];

  float* out = (float*)d_out;

  // ---- workspace carve ----
  char* p = (char*)d_ws;
  auto alloc = [&](size_t bytes) { void* r = p; p += (bytes + 255) & ~(size_t)255; return r; };
  ushort* r1 = (ushort*)alloc((size_t)524288 * 32 * 2);
  ushort* r2 = (ushort*)alloc((size_t)131072 * 64 * 2);
  ushort* r3 = (ushort*)alloc((size_t)32768 * 128 * 2);
  ushort* r4 = (ushort*)alloc((size_t)8192 * 256 * 2);
  ushort* r5 = (ushort*)alloc((size_t)8192 * 64 * 2);
  ushort* d0 = (ushort*)alloc((size_t)8192 * 256 * 2);
  ushort* d1 = (ushort*)alloc((size_t)32768 * 128 * 2);
  ushort* d2 = (ushort*)alloc((size_t)131072 * 64 * 2);
  ushort* d3 = (ushort*)alloc((size_t)524288 * 32 * 2);
  float*  Z    = (float*)alloc((size_t)524288 * 4);
  ushort* Zbf  = (ushort*)alloc((size_t)524288 * 2);
  ushort* cbbf = (ushort*)alloc((size_t)524288 * 2);
  float*  S    = (float*)alloc((size_t)4 * 262144 * 4);   // 4 K-slices
  ushort* Zq   = (ushort*)alloc((size_t)524288 * 2);
  float*  wsq  = (float*)alloc((size_t)512 * 4);
  ushort* wce2 = (ushort*)alloc((size_t)16 * 64 * 32 * 2);
  ushort* wce3 = (ushort*)alloc((size_t)16 * 128 * 64 * 2);
  ushort* wce4 = (ushort*)alloc((size_t)16 * 256 * 128 * 2);
  ushort* wce5 = (ushort*)alloc((size_t)64 * 256 * 2);
  ushort* wcd0 = (ushort*)alloc((size_t)256 * 64 * 2);
  ushort* wcd1 = (ushort*)alloc((size_t)16 * 128 * 256 * 2);
  ushort* wcd2 = (ushort*)alloc((size_t)16 * 64 * 128 * 2);
  ushort* wcd3 = (ushort*)alloc((size_t)16 * 32 * 64 * 2);
  ushort* wcd4 = (ushort*)alloc((size_t)16 * 16 * 32 * 2);
  ushort* wce1b = (ushort*)alloc((size_t)32 * 64 * 2);
  float*  cd4bp = (float*)alloc(64);
  float*  statsAll = (float*)alloc((size_t)(9 * 4096 + 64) * 4);
  int*    jbuf = (int*)alloc((size_t)512 * 4);

  float* st_e1 = statsAll + 0 * 4096;
  float* st_e2 = statsAll + 1 * 4096;
  float* st_e3 = statsAll + 2 * 4096;
  float* st_e4 = statsAll + 3 * 4096;
  float* st_e5 = statsAll + 4 * 4096;
  float* st_d0 = statsAll + 5 * 4096;
  float* st_d1 = statsAll + 6 * 4096;
  float* st_d2 = statsAll + 7 * 4096;
  float* st_d3 = statsAll + 8 * 4096;
  float* lossAcc = statsAll + 9 * 4096;
  int*   cnt = (int*)(lossAcc + 1);

  hipMemsetAsync(statsAll, 0, (size_t)(9 * 4096 + 64) * 4, stream);

  prep_all<<<8104, 256, 0, stream>>>(ce1_w, ce2_w, ce3_w, ce4_w, ce5_w, cd0_w, cd1_w,
      cd2_w, cd3_w, cd4_w, cd4_b, codebook,
      wce1b, wce2, wce3, wce4, wce5, wcd0, wcd1, wcd2, wcd3, wcd4, cd4bp, cbbf, wsq);

  // ---- encoder ----
  ce1_mfma<<<2048, 256, 0, stream>>>(x, wce1b, ce1_b, r1, st_e1);
  tconv<1, 32, 64, 32, 8, 4, 2, 1, 1, true, true, false><<<dim3(1024, 1), 256, 0, stream>>>(
      r1, wce2, ce2_b, st_e1, bn_e1_g, bn_e1_b, r2, st_e2);
  tconv<1, 64, 128, 16, 8, 4, 2, 1, 1, true, true, false><<<dim3(512, 1), 256, 0, stream>>>(
      r2, wce3, ce3_b, st_e2, bn_e2_g, bn_e2_b, r3, st_e3);
  // ce4: NB=4, WM=4, WN=1, CS=4 -> grid 512 (2 blk/CU), 4:1 ratio kept
  tconv<1, 128, 256, 8, 4, 4, 1, 4, 4, true, true, false><<<dim3(128, 4), 256, 0, stream>>>(
      r3, wce4, ce4_b, st_e3, bn_e3_g, bn_e3_b, r4, st_e4);
  g1x1<256, 64, 16, true, 8192, true><<<dim3(128, 4), 256, 0, stream>>>(
      r4, wce5, ce5_b, st_e4, bn_e4_g, bn_e4_b, r5, st_e5);

  // ---- VQ ----
  zprep<<<2048, 256, 0, stream>>>(r5, st_e5, bn_e5_g, bn_e5_b, Z, Zbf);
  vq_gemm<<<dim3(8, 8, 4), 256, 0, stream>>>(Zbf, cbbf, S);
  vq_post<<<512, 256, 0, stream>>>(S, wsq, Z, codebook, Zq, lossAcc, cnt, out + 6291456);

  // ---- decoder ----
  g1x1<64, 256, 32, false, 1, true><<<dim3(128, 8), 256, 0, stream>>>(
      Zq, wcd0, cd0_b, nullptr, nullptr, nullptr, d0, st_d0);
  tconv<2, 256, 128, 4, 4, 4, 4, 2, 4, true, true, false><<<dim3(128, 2), 256, 0, stream>>>(
      d0, wcd1, cd1_b, st_d0, bn_d0_g, bn_d0_b, d1, st_d1);
  tconv<2, 128, 64, 8, 8, 4, 4, 1, 1, true, true, false><<<dim3(512, 1), 256, 0, stream>>>(
      d1, wcd2, cd2_b, st_d1, bn_d1_g, bn_d1_b, d2, st_d2);
  tconv<2, 64, 32, 16, 8, 8, 2, 1, 1, true, true, false><<<dim3(1024, 1), 256, 0, stream>>>(
      d2, wcd3, cd3_b, st_d2, bn_d2_g, bn_d2_b, d3, st_d3);
  tconv<2, 32, 16, 32, 4, 8, 1, 1, 1, true, false, true><<<dim3(4096, 1), 256, 0, stream>>>(
      d3, wcd4, cd4bp, st_d3, bn_d3_g, bn_d3_b, out, nullptr);
}

// Round 9
// 430.093 us; speedup vs baseline: 1.2428x; 1.0092x over previous
//
#include <hip/hip_runtime.h>
#include <hip/hip_bf16.h>
#include <math.h>

typedef __attribute__((ext_vector_type(8))) short bf16x8;
typedef __attribute__((ext_vector_type(4))) float f32x4;

__device__ __forceinline__ float bf2f(ushort u) {
  union { uint i; float f; } t; t.i = ((uint)u) << 16; return t.f;
}
__device__ __forceinline__ ushort f2bf(float f) {
  __hip_bfloat16 h = __float2bfloat16(f);
  return *reinterpret_cast<ushort*>(&h);
}
__device__ __forceinline__ uint pk(float a, float b) {
  return (uint)f2bf(a) | ((uint)f2bf(b) << 16);
}
constexpr int ilog2c(int v) { int r = 0; while (v > 1) { v >>= 1; ++r; } return r; }

// =====================================================================
// Tiled MFMA conv, fused input-BN+LReLU, fused output batch-stats,
// co-split across blockIdx.y (CS) for occupancy.
// MODE 1: k4s2p1 encoder. MODE 2: up2+3x3 decoder (wave = parity class).
// NB: images per block: raises WM so each weight load feeds WM MFMAs.
// R7/R9 lesson: keep ratio >=4:1 AND grid >=512 (>=2 blk/CU). ce4 and cd1
// at 1 blk/CU lose ~40% to zero TLP; split CS to restore coverage.
// SIG: fp32 NCHW sigmoid output (cd4, Co padded to 16, real 3).
// =====================================================================
template<int MODE, int Ci, int Co, int HIN, int TR, int WM, int WN, int CS,
         int NB, bool BN, bool OSTAT, bool SIG>
__global__ __launch_bounds__(256) void tconv(const ushort* __restrict__ in,
    const ushort* __restrict__ wt, const float* __restrict__ bias,
    const float* __restrict__ st, const float* __restrict__ g,
    const float* __restrict__ bb, void* __restrict__ out_,
    float* __restrict__ stOut) {
  constexpr int W    = (MODE == 1) ? HIN / 2 : HIN;
  constexpr int LW   = ilog2c(W);
  constexpr int R_IN = (MODE == 1) ? 2 * TR + 2 : TR + 2;
  constexpr int W2   = HIN + 2;
  constexpr int MTPI = TR * W / 16;        // M-tiles per image
  constexpr int MT   = NB * MTPI;          // M-tiles per block
  constexpr int NG   = Co / 16;
  constexpr int NGB  = NG / CS;            // co groups per block
  constexpr int COB  = NGB * 16;           // channels per block
  constexpr int TAPS = (MODE == 1) ? 16 : 4;
  constexpr int RB   = W / TR;
  constexpr int CB   = BN ? Ci : 1;
  constexpr int SB   = OSTAT ? COB : 1;
  constexpr int SN4P = R_IN * W2 * 4;      // 16B staging units per image
  static_assert(TR * W % 16 == 0, "mtile");
  static_assert(MODE == 2 ? (WM == MT && WN == NGB)
                          : ((MT % WM == 0) && (NGB % WN == 0) &&
                             (MT / WM) * (NGB / WN) == 4),
                "wave map");

  __shared__ __align__(16) ushort lt[NB * R_IN * W2 * 40];
  __shared__ float lsc[CB], lsh[CB];
  __shared__ float sst[SB], ssq[SB];

  const int tid  = threadIdx.x;
  const int wave = tid >> 6;
  const int ln15 = tid & 15;
  const int quad = (tid & 63) >> 4;
  const int rb = blockIdx.x % RB;
  const int n0 = (blockIdx.x / RB) * NB;
  const int h0 = rb * TR;
  const int cbase = blockIdx.y * NGB;      // co-group base for this block

  if (BN) {
    constexpr float inv_cnt = 1.0f / (float)(512 * HIN * HIN);
    for (int c = tid; c < Ci; c += 256) {
      float s = 0.f, q = 0.f;
#pragma unroll
      for (int sl = 0; sl < 8; ++sl) {
        s += st[sl * 2 * Ci + c];
        q += st[sl * 2 * Ci + Ci + c];
      }
      float m = s * inv_cnt;
      float var = fmaf(q, inv_cnt, -m * m);
      float sc = g[c] * rsqrtf(var + 1e-5f);
      lsc[c] = sc;
      lsh[c] = fmaf(-m, sc, bb[c]);
    }
  }

  int mt0, cg0, ph, pw, pb;
  if (MODE == 2) { mt0 = 0; cg0 = cbase; ph = wave >> 1; pw = wave & 1; pb = wave * 4; }
  else {
    constexpr int MW = MT / WM;
    mt0 = (wave % MW) * WM; cg0 = cbase + (wave / MW) * WN; ph = 0; pw = 0; pb = 0;
  }

  f32x4 acc[WM][WN];
#pragma unroll
  for (int j = 0; j < WN; ++j) {
    f32x4 b4 = *(const f32x4*)&bias[(cg0 + j) * 16 + quad * 4];
#pragma unroll
    for (int i = 0; i < WM; ++i) acc[i][j] = b4;
  }

  const uint4* src4 = (const uint4*)in;
  const int gr0 = (MODE == 1) ? 2 * h0 - 1 : h0 - 1;

#pragma unroll 1
  for (int c0 = 0; c0 < Ci; c0 += 32) {
    __syncthreads();
    for (int i = tid; i < NB * SN4P; i += 256) {
      int img = (NB == 1) ? 0 : (i / SN4P);
      int ii  = (NB == 1) ? i : (i % SN4P);
      int ciu4 = ii & 3; int t2 = ii >> 2; int c = t2 % W2; int r = t2 / W2;
      int gr = gr0 + r, gc = c - 1;
      uint4 v4 = make_uint4(0u, 0u, 0u, 0u);
      if ((unsigned)gr < (unsigned)HIN && (unsigned)gc < (unsigned)HIN) {
        v4 = src4[((size_t)((n0 + img) * HIN + gr) * HIN + gc) * (Ci / 8) + (c0 >> 3) + ciu4];
        if (BN) {
          uint* pu = (uint*)&v4;
#pragma unroll
          for (int k2 = 0; k2 < 4; ++k2) {
            int cc = c0 + ciu4 * 8 + k2 * 2;
            float f0 = fmaf(bf2f((ushort)(pu[k2] & 0xffffu)), lsc[cc], lsh[cc]);
            float f1 = fmaf(bf2f((ushort)(pu[k2] >> 16)), lsc[cc + 1], lsh[cc + 1]);
            f0 = f0 > 0.f ? f0 : 0.01f * f0;
            f1 = f1 > 0.f ? f1 : 0.01f * f1;
            pu[k2] = pk(f0, f1);
          }
        }
      }
      *(uint4*)&((uint*)lt)[((img * R_IN + r) * W2 + c) * 20 + ciu4 * 4] = v4;
    }
    __syncthreads();

#pragma unroll
    for (int t = 0; t < TAPS; ++t) {
      const int kh = (MODE == 1) ? (t >> 2) : (t >> 1);
      const int kw = (MODE == 1) ? (t & 3) : (t & 1);
      bf16x8 af[WN];
      const ushort* wb = wt + (size_t)(pb + t) * Co * Ci;
#pragma unroll
      for (int j = 0; j < WN; ++j)
        af[j] = *(const bf16x8*)&wb[(size_t)((cg0 + j) * 16 + ln15) * Ci + c0 + quad * 8];
      bf16x8 bfr[WM];
#pragma unroll
      for (int i = 0; i < WM; ++i) {
        int mtile = mt0 + i;
        int img = (NB == 1) ? 0 : (mtile / MTPI);
        int lm  = (NB == 1) ? mtile : (mtile % MTPI);
        int m = lm * 16 + ln15;
        int hr = m >> LW, wr = m & (W - 1);
        int row, col;
        if (MODE == 1) { row = 2 * hr + kh; col = 2 * wr + kw; }
        else           { row = hr + kh + ph; col = wr + kw + pw; }
        bfr[i] = *(const bf16x8*)&lt[((img * R_IN + row) * W2 + col) * 40 + quad * 8];
      }
#pragma unroll
      for (int i = 0; i < WM; ++i)
#pragma unroll
        for (int j = 0; j < WN; ++j)
          acc[i][j] = __builtin_amdgcn_mfma_f32_16x16x32_bf16(af[j], bfr[i], acc[i][j], 0, 0, 0);
    }
  }

  if (OSTAT) {
    for (int c = tid; c < COB; c += 256) { sst[c] = 0.f; ssq[c] = 0.f; }
    __syncthreads();
  }

  if (SIG) {
    constexpr int HO2 = 2 * HIN;
    float* outF = (float*)out_;
#pragma unroll
    for (int i = 0; i < WM; ++i) {
      int mtile = mt0 + i;
      int img = (NB == 1) ? 0 : (mtile / MTPI);
      int lm  = (NB == 1) ? mtile : (mtile % MTPI);
      int m = lm * 16 + ln15;
      int hr = m >> LW, wr = m & (W - 1);
      int oh = 2 * (h0 + hr) + ph, ow = 2 * wr + pw;
      size_t base = (size_t)(n0 + img) * 3 * HO2 * HO2 + (size_t)oh * HO2 + ow;
#pragma unroll
      for (int r = 0; r < 4; ++r) {
        int co = quad * 4 + r;
        if (co < 3)
          outF[base + (size_t)co * HO2 * HO2] = 1.f / (1.f + __expf(-acc[i][0][r]));
      }
    }
  } else {
    ushort* out = (ushort*)out_;
#pragma unroll
    for (int i = 0; i < WM; ++i) {
      int mtile = mt0 + i;
      int img = (NB == 1) ? 0 : (mtile / MTPI);
      int lm  = (NB == 1) ? mtile : (mtile % MTPI);
      int m = lm * 16 + ln15;
      int hr = m >> LW, wr = m & (W - 1);
      size_t sp;
      if (MODE == 2) {
        int oh = 2 * (h0 + hr) + ph, ow = 2 * wr + pw;
        sp = ((size_t)(n0 + img) * (2 * HIN) + oh) * (2 * HIN) + ow;
      } else {
        sp = ((size_t)(n0 + img) * W + h0 + hr) * W + wr;
      }
#pragma unroll
      for (int j = 0; j < WN; ++j) {
        f32x4 a = acc[i][j];
        uint2 stv; stv.x = pk(a[0], a[1]); stv.y = pk(a[2], a[3]);
        *(uint2*)&out[sp * Co + (cg0 + j) * 16 + quad * 4] = stv;
      }
    }
  }

  if (OSTAT) {
#pragma unroll
    for (int j = 0; j < WN; ++j)
#pragma unroll
      for (int r = 0; r < 4; ++r) {
        float s = 0.f, q = 0.f;
#pragma unroll
        for (int i = 0; i < WM; ++i) {
          float v = acc[i][j][r];
          s += v; q = fmaf(v, v, q);
        }
#pragma unroll
        for (int mk = 1; mk < 16; mk <<= 1) {
          s += __shfl_xor(s, mk);
          q += __shfl_xor(q, mk);
        }
        if (ln15 == 0) {
          int lc = (cg0 + j) * 16 + quad * 4 + r - cbase * 16;
          atomicAdd(&sst[lc], s);
          atomicAdd(&ssq[lc], q);
        }
      }
    __syncthreads();
    float* d = stOut + (size_t)(blockIdx.x & 7) * 2 * Co;
    for (int c = tid; c < COB; c += 256) {
      atomicAdd(&d[cbase * 16 + c], sst[c]);
      atomicAdd(&d[Co + cbase * 16 + c], ssq[c]);
    }
  }
}

// ===================== 1x1 conv GEMM, fused input-BN + output stats ==========
template<int Ci, int Co, int COT, bool BN, int NPIX, bool OSTAT>
__global__ __launch_bounds__(256) void g1x1(const ushort* __restrict__ in,
    const ushort* __restrict__ wt, const float* __restrict__ bias,
    const float* __restrict__ st, const float* __restrict__ g,
    const float* __restrict__ bb, ushort* __restrict__ out,
    float* __restrict__ stOut) {
  constexpr int NG = COT / 16;
  constexpr int CB = BN ? Ci : 1;
  constexpr int SB = OSTAT ? COT : 1;
  __shared__ __align__(16) ushort lb[64 * 40];
  __shared__ float lsc[CB], lsh[CB];
  __shared__ float sst[SB], ssq[SB];
  const int tid = threadIdx.x, wave = tid >> 6, ln15 = tid & 15, quad = (tid & 63) >> 4;
  const int pixBase = blockIdx.x * 64;
  const int co0 = blockIdx.y * COT;
  if (BN) {
    constexpr float inv_cnt = 1.0f / (float)NPIX;
    for (int c = tid; c < Ci; c += 256) {
      float s = 0.f, q = 0.f;
#pragma unroll
      for (int sl = 0; sl < 8; ++sl) {
        s += st[sl * 2 * Ci + c];
        q += st[sl * 2 * Ci + Ci + c];
      }
      float m = s * inv_cnt;
      float var = fmaf(q, inv_cnt, -m * m);
      float sc = g[c] * rsqrtf(var + 1e-5f);
      lsc[c] = sc;
      lsh[c] = fmaf(-m, sc, bb[c]);
    }
  }
  f32x4 acc[NG];
#pragma unroll
  for (int j = 0; j < NG; ++j) acc[j] = *(const f32x4*)&bias[co0 + j * 16 + quad * 4];
  const uint4* src4 = (const uint4*)in;
#pragma unroll 1
  for (int c0 = 0; c0 < Ci; c0 += 32) {
    __syncthreads();
    {
      int ciu4 = tid & 3, pl = tid >> 2;
      uint4 v4 = src4[(size_t)(pixBase + pl) * (Ci / 8) + (c0 >> 3) + ciu4];
      if (BN) {
        uint* pu = (uint*)&v4;
#pragma unroll
        for (int k2 = 0; k2 < 4; ++k2) {
          int cc = c0 + ciu4 * 8 + k2 * 2;
          float f0 = fmaf(bf2f((ushort)(pu[k2] & 0xffffu)), lsc[cc], lsh[cc]);
          float f1 = fmaf(bf2f((ushort)(pu[k2] >> 16)), lsc[cc + 1], lsh[cc + 1]);
          f0 = f0 > 0.f ? f0 : 0.01f * f0;
          f1 = f1 > 0.f ? f1 : 0.01f * f1;
          pu[k2] = pk(f0, f1);
        }
      }
      *(uint4*)&((uint*)lb)[pl * 20 + ciu4 * 4] = v4;
    }
    __syncthreads();
    bf16x8 bfr = *(const bf16x8*)&lb[(wave * 16 + ln15) * 40 + quad * 8];
#pragma unroll
    for (int j = 0; j < NG; ++j) {
      bf16x8 af = *(const bf16x8*)&wt[(size_t)(co0 + j * 16 + ln15) * Ci + c0 + quad * 8];
      acc[j] = __builtin_amdgcn_mfma_f32_16x16x32_bf16(af, bfr, acc[j], 0, 0, 0);
    }
  }
  if (OSTAT) {
    for (int c = tid; c < COT; c += 256) { sst[c] = 0.f; ssq[c] = 0.f; }
    __syncthreads();
  }
  int pix = pixBase + wave * 16 + ln15;
#pragma unroll
  for (int j = 0; j < NG; ++j) {
    uint2 stv; stv.x = pk(acc[j][0], acc[j][1]); stv.y = pk(acc[j][2], acc[j][3]);
    *(uint2*)&out[(size_t)pix * Co + co0 + j * 16 + quad * 4] = stv;
  }
  if (OSTAT) {
#pragma unroll
    for (int j = 0; j < NG; ++j)
#pragma unroll
      for (int r = 0; r < 4; ++r) {
        float s = acc[j][r];
        float q = s * s;
#pragma unroll
        for (int mk = 1; mk < 16; mk <<= 1) {
          s += __shfl_xor(s, mk);
          q += __shfl_xor(q, mk);
        }
        if (ln15 == 0) {
          int cl = j * 16 + quad * 4 + r;
          atomicAdd(&sst[cl], s);
          atomicAdd(&ssq[cl], q);
        }
      }
    __syncthreads();
    float* d = stOut + (size_t)(blockIdx.x & 7) * 2 * Co;
    for (int c = tid; c < COT; c += 256) {
      atomicAdd(&d[co0 + c], sst[c]);
      atomicAdd(&d[Co + co0 + c], ssq[c]);
    }
  }
}

// ===================== ce1 (MFMA): k4s2p1, Ci=3, fp32 NCHW -> bf16 NHWC + stats ===
__global__ __launch_bounds__(256) void ce1_mfma(const float* __restrict__ x,
    const ushort* __restrict__ wt, const float* __restrict__ bias,
    ushort* __restrict__ out, float* __restrict__ stOut) {
  __shared__ __align__(16) float lt[3 * 18 * 72];   // padded fp32 tile, 15.2 KB
  __shared__ float sst[32], ssq[32];
  const int tid = threadIdx.x, wave = tid >> 6, ln15 = tid & 15, quad = (tid & 63) >> 4;
  const int pixBase = blockIdx.x * 256;     // 8 out rows x 32 cols, one image
  const int n  = pixBase >> 10;
  const int h0 = (pixBase >> 5) & 31;
  if (tid < 32) { sst[tid] = 0.f; ssq[tid] = 0.f; }
  const int gr0 = 2 * h0 - 1;
  for (int i = tid; i < 3 * 18 * 72; i += 256) {
    int c = i % 72; int rem = i / 72; int r = rem % 18; int ci = rem / 18;
    int gr = gr0 + r, gc = c - 1;
    float v = 0.f;
    if ((unsigned)gr < 64u && (unsigned)gc < 64u)
      v = x[(((size_t)n * 3 + ci) << 12) + (gr << 6) + gc];
    lt[i] = v;
  }
  __syncthreads();

  f32x4 acc[4][2];
#pragma unroll
  for (int j = 0; j < 2; ++j) {
    f32x4 b4 = *(const f32x4*)&bias[j * 16 + quad * 4];
#pragma unroll
    for (int i = 0; i < 4; ++i) acc[i][j] = b4;
  }
  bf16x8 af[2][2];
#pragma unroll
  for (int j = 0; j < 2; ++j)
#pragma unroll
    for (int kk = 0; kk < 2; ++kk)
      af[j][kk] = *(const bf16x8*)&wt[(j * 16 + ln15) * 64 + kk * 32 + quad * 8];

  const int mt0 = wave * 4;
#pragma unroll
  for (int i = 0; i < 4; ++i) {
    int p = (mt0 + i) * 16 + ln15;        // px within block
    int h = p >> 5, w = p & 31;           // local out row/col
#pragma unroll
    for (int kk = 0; kk < 2; ++kk) {
      int k0 = kk * 32 + quad * 8;        // k = (ci*16 + kh*4 + kw)
      bf16x8 bfr = (bf16x8)(short)0;
      if (k0 < 48) {
        int ci = k0 >> 4, kh0 = (k0 >> 2) & 3;   // 8 k's = 2 rows x 4 kw
        const float* rp = &lt[(ci * 18 + 2 * h + kh0) * 72 + 2 * w];
        uint4 uu = make_uint4(pk(rp[0], rp[1]), pk(rp[2], rp[3]),
                              pk(rp[72], rp[73]), pk(rp[74], rp[75]));
        bfr = *reinterpret_cast<bf16x8*>(&uu);
      }
#pragma unroll
      for (int j = 0; j < 2; ++j)
        acc[i][j] = __builtin_amdgcn_mfma_f32_16x16x32_bf16(af[j][kk], bfr, acc[i][j], 0, 0, 0);
    }
  }
  // ---- store bf16 NHWC [px][32] ----
#pragma unroll
  for (int i = 0; i < 4; ++i) {
    int sp = pixBase + (mt0 + i) * 16 + ln15;
#pragma unroll
    for (int j = 0; j < 2; ++j) {
      f32x4 a = acc[i][j];
      uint2 stv; stv.x = pk(a[0], a[1]); stv.y = pk(a[2], a[3]);
      *(uint2*)&out[(size_t)sp * 32 + j * 16 + quad * 4] = stv;
    }
  }
  // ---- fused batch stats (16-lane reduce like tconv OSTAT) ----
#pragma unroll
  for (int j = 0; j < 2; ++j)
#pragma unroll
    for (int r = 0; r < 4; ++r) {
      float s = 0.f, q = 0.f;
#pragma unroll
      for (int i = 0; i < 4; ++i) {
        float v = acc[i][j][r];
        s += v; q = fmaf(v, v, q);
      }
#pragma unroll
      for (int mk = 1; mk < 16; mk <<= 1) {
        s += __shfl_xor(s, mk);
        q += __shfl_xor(q, mk);
      }
      if (ln15 == 0) {
        int ch = j * 16 + quad * 4 + r;
        atomicAdd(&sst[ch], s);
        atomicAdd(&ssq[ch], q);
      }
    }
  __syncthreads();
  if (tid < 32) {
    float* d = stOut + (size_t)(blockIdx.x & 7) * 64;
    atomicAdd(&d[tid], sst[tid]);
    atomicAdd(&d[32 + tid], ssq[tid]);
  }
}

// ===================== prep: ALL weight transforms + codebook, one dispatch ======
__device__ __forceinline__ void enc_tr(const float* __restrict__ w,
    ushort* __restrict__ o, int Co, int Ci, int idx) {
  int ci = idx % Ci; int r = idx / Ci; int co = r % Co; int t = r / Co;
  o[idx] = f2bf(w[(co * Ci + ci) * 16 + t]);
}
__device__ __forceinline__ float dec_comb(const float* __restrict__ w,
    int Ci, int co, int ci, int pt) {
  int p = pt >> 2, t = pt & 3;
  int ph = p >> 1, pw = p & 1, rr = t >> 1, cc = t & 1;
  int rs = (rr == 0) ? 0 : (ph == 0 ? 1 : 2);
  int re = (rr == 0) ? (ph == 0 ? 1 : 2) : 3;
  int cs = (cc == 0) ? 0 : (pw == 0 ? 1 : 2);
  int ce = (cc == 0) ? (pw == 0 ? 1 : 2) : 3;
  float s = 0.f;
  for (int kh = rs; kh < re; ++kh)
    for (int kw = cs; kw < ce; ++kw)
      s += w[((co * Ci + ci) * 3 + kh) * 3 + kw];
  return s;
}
__device__ __forceinline__ void dec_tr(const float* __restrict__ w,
    ushort* __restrict__ o, int Co, int Ci, int idx) {
  int ci = idx % Ci; int r = idx / Ci; int co = r % Co; int pt = r / Co;
  o[idx] = f2bf(dec_comb(w, Ci, co, ci, pt));
}

__global__ __launch_bounds__(256) void prep_all(
    const float* __restrict__ ce1_w,
    const float* __restrict__ ce2_w, const float* __restrict__ ce3_w,
    const float* __restrict__ ce4_w, const float* __restrict__ ce5_w,
    const float* __restrict__ cd0_w, const float* __restrict__ cd1_w,
    const float* __restrict__ cd2_w, const float* __restrict__ cd3_w,
    const float* __restrict__ cd4_w, const float* __restrict__ cd4_b,
    const float* __restrict__ codebook,
    ushort* __restrict__ wce1b,
    ushort* __restrict__ wce2, ushort* __restrict__ wce3, ushort* __restrict__ wce4,
    ushort* __restrict__ wce5, ushort* __restrict__ wcd0, ushort* __restrict__ wcd1,
    ushort* __restrict__ wcd2, ushort* __restrict__ wcd3, ushort* __restrict__ wcd4,
    float* __restrict__ cd4bp, ushort* __restrict__ cbbf, float* __restrict__ wsq) {
  __shared__ float sh[4];
  int bx = blockIdx.x, tid = threadIdx.x;
  if (bx < 2048) { int i = bx * 256 + tid; cbbf[i] = f2bf(codebook[i]); return; }
  bx -= 2048;
  if (bx < 512) {
    int k = bx;
    float s = 0.f;
    for (int d = tid; d < 1024; d += 256) {
      float v = codebook[k * 1024 + d];
      s = fmaf(v, v, s);
    }
#pragma unroll
    for (int o = 32; o > 0; o >>= 1) s += __shfl_down(s, o);
    if ((tid & 63) == 0) sh[tid >> 6] = s;
    __syncthreads();
    if (tid == 0) wsq[k] = sh[0] + sh[1] + sh[2] + sh[3];
    return;
  }
  bx -= 512;
  if (bx < 2048) { enc_tr(ce4_w, wce4, 256, 128, bx * 256 + tid); return; }
  bx -= 2048;
  if (bx < 2048) { dec_tr(cd1_w, wcd1, 128, 256, bx * 256 + tid); return; }
  bx -= 2048;
  if (bx < 512)  { enc_tr(ce3_w, wce3, 128, 64, bx * 256 + tid); return; }
  bx -= 512;
  if (bx < 512)  { dec_tr(cd2_w, wcd2, 64, 128, bx * 256 + tid); return; }
  bx -= 512;
  if (bx < 128)  { enc_tr(ce2_w, wce2, 64, 32, bx * 256 + tid); return; }
  bx -= 128;
  if (bx < 128)  { dec_tr(cd3_w, wcd3, 32, 64, bx * 256 + tid); return; }
  bx -= 128;
  if (bx < 64)   { int i = bx * 256 + tid; wce5[i] = f2bf(ce5_w[i]); return; }
  bx -= 64;
  if (bx < 64)   { int i = bx * 256 + tid; wcd0[i] = f2bf(cd0_w[i]); return; }
  bx -= 64;
  if (bx < 32) {                // cd4 padded: [16 taps][16 co][32 ci]
    int idx = bx * 256 + tid;   // 32 blocks
    int ci = idx & 31; int r = idx >> 5; int co = r & 15; int pt = r >> 4;
    wcd4[idx] = (co < 3) ? f2bf(dec_comb(cd4_w, 32, co, ci, pt)) : (ushort)0;
    if (bx == 0 && tid < 16) cd4bp[tid] = (tid < 3) ? cd4_b[tid] : 0.f;
    return;
  }
  bx -= 32;
  {                             // ce1 bf16 weights: [32 co][64 k], k>=48 zero; 8 blocks
    int idx = bx * 256 + tid;   // 0..2047
    int k = idx & 63, co = idx >> 6;
    wce1b[idx] = (k < 48) ? f2bf(ce1_w[co * 48 + k]) : (ushort)0;
  }
}

// ===================== VQ ==========
__global__ __launch_bounds__(256) void zprep(const ushort* __restrict__ r5,
    const float* __restrict__ st, const float* __restrict__ g,
    const float* __restrict__ bb, float* __restrict__ Z, ushort* __restrict__ Zbf) {
  __shared__ float lsc[64], lsh[64];
  int tid = threadIdx.x;
  if (tid < 64) {
    float s = 0.f, q = 0.f;
#pragma unroll
    for (int sl = 0; sl < 8; ++sl) { s += st[sl * 128 + tid]; q += st[sl * 128 + 64 + tid]; }
    float m = s * (1.0f / 8192.f);
    float var = fmaf(q, 1.0f / 8192.f, -m * m);
    float sc = g[tid] * rsqrtf(var + 1e-5f);
    lsc[tid] = sc;
    lsh[tid] = fmaf(-m, sc, bb[tid]);
  }
  __syncthreads();
  int i = blockIdx.x * 256 + tid;
  int c = i & 63;
  float f = fmaf(bf2f(r5[i]), lsc[c], lsh[c]);
  f = f > 0.f ? f : 0.01f * f;
  Z[i] = f;
  Zbf[i] = f2bf(f);
}

// S_ks[b][k] partial dot over K-slice ks (4 slices). Grid (8,8,4).
__global__ __launch_bounds__(256) void vq_gemm(const ushort* __restrict__ Zbf,
    const ushort* __restrict__ cbbf, float* __restrict__ S) {
  __shared__ __align__(16) ushort lZ[64 * 40], lW[64 * 40];
  const int tid = threadIdx.x, wave = tid >> 6, ln15 = tid & 15, quad = (tid & 63) >> 4;
  const int b0 = blockIdx.x * 64, k0 = blockIdx.y * 64, ks = blockIdx.z;
  f32x4 acc[4];
#pragma unroll
  for (int j = 0; j < 4; ++j) acc[j] = (f32x4)(0.f);
  const uint4* zs = (const uint4*)Zbf;
  const uint4* ws = (const uint4*)cbbf;
#pragma unroll 1
  for (int c0 = ks * 256; c0 < ks * 256 + 256; c0 += 32) {
    __syncthreads();
    for (int i = tid; i < 512; i += 256) {
      int ciu4 = i & 3; int rl = (i >> 2) & 63; bool isW = i >= 256;
      uint4 v = (isW ? ws : zs)[(size_t)((isW ? k0 : b0) + rl) * 128 + (c0 >> 3) + ciu4];
      *(uint4*)&((uint*)(isW ? lW : lZ))[rl * 20 + ciu4 * 4] = v;
    }
    __syncthreads();
    bf16x8 bfr = *(const bf16x8*)&lZ[(wave * 16 + ln15) * 40 + quad * 8];
#pragma unroll
    for (int j = 0; j < 4; ++j) {
      bf16x8 af = *(const bf16x8*)&lW[(j * 16 + ln15) * 40 + quad * 8];
      acc[j] = __builtin_amdgcn_mfma_f32_16x16x32_bf16(af, bfr, acc[j], 0, 0, 0);
    }
  }
  int b = b0 + wave * 16 + ln15;
  float* Sk = S + (size_t)ks * 262144;
#pragma unroll
  for (int j = 0; j < 4; ++j)
    *(f32x4*)&Sk[(size_t)b * 512 + k0 + j * 16 + quad * 4] = acc[j];
}

// fused: argmin scan + gather Zq + exact fp32 loss + last-block writes losses
__global__ __launch_bounds__(256) void vq_post(const float* __restrict__ S,
    const float* __restrict__ wsq, const float* __restrict__ Z,
    const float* __restrict__ cb, ushort* __restrict__ Zq,
    float* __restrict__ lossAcc, int* __restrict__ cnt, float* __restrict__ out2) {
  int b = blockIdx.x, tid = threadIdx.x;
  float s1 = 0.f, s2 = 0.f;
#pragma unroll
  for (int sl = 0; sl < 4; ++sl) {
    s1 += S[(size_t)sl * 262144 + (size_t)b * 512 + tid];
    s2 += S[(size_t)sl * 262144 + (size_t)b * 512 + tid + 256];
  }
  float d1 = fmaf(-2.f, s1, wsq[tid]);
  float d2 = fmaf(-2.f, s2, wsq[tid + 256]);
  float bv = d1; int bk = tid;
  if (d2 < bv) { bv = d2; bk = tid + 256; }
  __shared__ float vsh[256]; __shared__ int ish[256];
  vsh[tid] = bv; ish[tid] = bk;
  __syncthreads();
  for (int s = 128; s > 0; s >>= 1) {
    if (tid < s) {
      float ov = vsh[tid + s]; int oi = ish[tid + s];
      if (ov < vsh[tid] || (ov == vsh[tid] && oi < ish[tid])) { vsh[tid] = ov; ish[tid] = oi; }
    }
    __syncthreads();
  }
  int k = ish[0];
  const float* w = cb + ((long)k << 10);
  const float* zp = Z + ((long)b << 10);
  float part = 0.f;
  for (int d = tid; d < 1024; d += 256) {
    float wv = w[d];
    float diff = zp[d] - wv;
    part = fmaf(diff, diff, part);
    Zq[(b << 10) + d] = f2bf(wv);
  }
#pragma unroll
  for (int o = 32; o > 0; o >>= 1) part += __shfl_down(part, o);
  __shared__ float sh[4];
  if ((tid & 63) == 0) sh[tid >> 6] = part;
  __syncthreads();
  if (tid == 0) {
    atomicAdd(lossAcc, sh[0] + sh[1] + sh[2] + sh[3]);
    __threadfence();
    int old = atomicAdd(cnt, 1);
    if (old == 511) {
      float v = *(volatile float*)lossAcc * (1.0f / 512.0f);
      out2[0] = v;
      out2[1] = v;
    }
  }
}

// ===================== launch ==========
extern "C" void kernel_launch(void* const* d_in, const int* in_sizes, int n_in,
                              void* d_out, int out_size, void* d_ws, size_t ws_size,
                              hipStream_t stream) {
  const float* x      = (const float*)d_in[0];
  const float* ce1_w  = (const float*)d_in[1];  const float* ce1_b = (const float*)d_in[2];
  const float* ce2_w  = (const float*)d_in[3];  const float* ce2_b = (const float*)d_in[4];
  const float* ce3_w  = (const float*)d_in[5];  const float* ce3_b = (const float*)d_in[6];
  const float* ce4_w  = (const float*)d_in[7];  const float* ce4_b = (const float*)d_in[8];
  const float* ce5_w  = (const float*)d_in[9];  const float* ce5_b = (const float*)d_in[10];
  const float* cd0_w  = (const float*)d_in[11]; const float* cd0_b = (const float*)d_in[12];
  const float* cd1_w  = (const float*)d_in[13]; const float* cd1_b = (const float*)d_in[14];
  const float* cd2_w  = (const float*)d_in[15]; const float* cd2_b = (const float*)d_in[16];
  const float* cd3_w  = (const float*)d_in[17]; const float* cd3_b = (const float*)d_in[18];
  const float* cd4_w  = (const float*)d_in[19]; const float* cd4_b = (const float*)d_in[20];
  const float* bn_e1_g = (const float*)d_in[21]; const float* bn_e1_b = (const float*)d_in[22];
  const float* bn_e2_g = (const float*)d_in[23]; const float* bn_e2_b = (const float*)d_in[24];
  const float* bn_e3_g = (const float*)d_in[25]; const float* bn_e3_b = (const float*)d_in[26];
  const float* bn_e4_g = (const float*)d_in[27]; const float* bn_e4_b = (const float*)d_in[28];
  const float* bn_e5_g = (const float*)d_in[29]; const float* bn_e5_b = (const float*)d_in[30];
  const float* bn_d0_g = (const float*)d_in[31]; const float* bn_d0_b = (const float*)d_in[32];
  const float* bn_d1_g = (const float*)d_in[33]; const float* bn_d1_b = (const float*)d_in[34];
  const float* bn_d2_g = (const float*)d_in[35]; const float* bn_d2_b = (const float*)d_in[36];
  const float* bn_d3_g = (const float*)d_in[37]; const float* bn_d3_b = (const float*)d_in[38];
  const float* codebook = (const float*)d_in[39];

  float* out = (float*)d_out;

  // ---- workspace carve ----
  char* p = (char*)d_ws;
  auto alloc = [&](size_t bytes) { void* r = p; p += (bytes + 255) & ~(size_t)255; return r; };
  ushort* r1 = (ushort*)alloc((size_t)524288 * 32 * 2);
  ushort* r2 = (ushort*)alloc((size_t)131072 * 64 * 2);
  ushort* r3 = (ushort*)alloc((size_t)32768 * 128 * 2);
  ushort* r4 = (ushort*)alloc((size_t)8192 * 256 * 2);
  ushort* r5 = (ushort*)alloc((size_t)8192 * 64 * 2);
  ushort* d0 = (ushort*)alloc((size_t)8192 * 256 * 2);
  ushort* d1 = (ushort*)alloc((size_t)32768 * 128 * 2);
  ushort* d2 = (ushort*)alloc((size_t)131072 * 64 * 2);
  ushort* d3 = (ushort*)alloc((size_t)524288 * 32 * 2);
  float*  Z    = (float*)alloc((size_t)524288 * 4);
  ushort* Zbf  = (ushort*)alloc((size_t)524288 * 2);
  ushort* cbbf = (ushort*)alloc((size_t)524288 * 2);
  float*  S    = (float*)alloc((size_t)4 * 262144 * 4);   // 4 K-slices
  ushort* Zq   = (ushort*)alloc((size_t)524288 * 2);
  float*  wsq  = (float*)alloc((size_t)512 * 4);
  ushort* wce2 = (ushort*)alloc((size_t)16 * 64 * 32 * 2);
  ushort* wce3 = (ushort*)alloc((size_t)16 * 128 * 64 * 2);
  ushort* wce4 = (ushort*)alloc((size_t)16 * 256 * 128 * 2);
  ushort* wce5 = (ushort*)alloc((size_t)64 * 256 * 2);
  ushort* wcd0 = (ushort*)alloc((size_t)256 * 64 * 2);
  ushort* wcd1 = (ushort*)alloc((size_t)16 * 128 * 256 * 2);
  ushort* wcd2 = (ushort*)alloc((size_t)16 * 64 * 128 * 2);
  ushort* wcd3 = (ushort*)alloc((size_t)16 * 32 * 64 * 2);
  ushort* wcd4 = (ushort*)alloc((size_t)16 * 16 * 32 * 2);
  ushort* wce1b = (ushort*)alloc((size_t)32 * 64 * 2);
  float*  cd4bp = (float*)alloc(64);
  float*  statsAll = (float*)alloc((size_t)(9 * 4096 + 64) * 4);
  int*    jbuf = (int*)alloc((size_t)512 * 4);

  float* st_e1 = statsAll + 0 * 4096;
  float* st_e2 = statsAll + 1 * 4096;
  float* st_e3 = statsAll + 2 * 4096;
  float* st_e4 = statsAll + 3 * 4096;
  float* st_e5 = statsAll + 4 * 4096;
  float* st_d0 = statsAll + 5 * 4096;
  float* st_d1 = statsAll + 6 * 4096;
  float* st_d2 = statsAll + 7 * 4096;
  float* st_d3 = statsAll + 8 * 4096;
  float* lossAcc = statsAll + 9 * 4096;
  int*   cnt = (int*)(lossAcc + 1);

  hipMemsetAsync(statsAll, 0, (size_t)(9 * 4096 + 64) * 4, stream);

  prep_all<<<8104, 256, 0, stream>>>(ce1_w, ce2_w, ce3_w, ce4_w, ce5_w, cd0_w, cd1_w,
      cd2_w, cd3_w, cd4_w, cd4_b, codebook,
      wce1b, wce2, wce3, wce4, wce5, wcd0, wcd1, wcd2, wcd3, wcd4, cd4bp, cbbf, wsq);

  // ---- encoder ----
  ce1_mfma<<<2048, 256, 0, stream>>>(x, wce1b, ce1_b, r1, st_e1);
  tconv<1, 32, 64, 32, 8, 4, 2, 1, 1, true, true, false><<<dim3(1024, 1), 256, 0, stream>>>(
      r1, wce2, ce2_b, st_e1, bn_e1_g, bn_e1_b, r2, st_e2);
  tconv<1, 64, 128, 16, 8, 4, 2, 1, 1, true, true, false><<<dim3(512, 1), 256, 0, stream>>>(
      r2, wce3, ce3_b, st_e2, bn_e2_g, bn_e2_b, r3, st_e3);
  tconv<1, 128, 256, 8, 4, 4, 1, 4, 4, true, true, false><<<dim3(128, 4), 256, 0, stream>>>(
      r3, wce4, ce4_b, st_e3, bn_e3_g, bn_e3_b, r4, st_e4);
  g1x1<256, 64, 16, true, 8192, true><<<dim3(128, 4), 256, 0, stream>>>(
      r4, wce5, ce5_b, st_e4, bn_e4_g, bn_e4_b, r5, st_e5);

  // ---- VQ ----
  zprep<<<2048, 256, 0, stream>>>(r5, st_e5, bn_e5_g, bn_e5_b, Z, Zbf);
  vq_gemm<<<dim3(8, 8, 4), 256, 0, stream>>>(Zbf, cbbf, S);
  vq_post<<<512, 256, 0, stream>>>(S, wsq, Z, codebook, Zq, lossAcc, cnt, out + 6291456);

  // ---- decoder ----
  g1x1<64, 256, 32, false, 1, true><<<dim3(128, 8), 256, 0, stream>>>(
      Zq, wcd0, cd0_b, nullptr, nullptr, nullptr, d0, st_d0);
  // cd1: CS=4 -> grid (128,4)=512 blocks, 2 blk/CU (was 256 = 1/CU, zero TLP)
  tconv<2, 256, 128, 4, 4, 4, 2, 4, 4, true, true, false><<<dim3(128, 4), 256, 0, stream>>>(
      d0, wcd1, cd1_b, st_d0, bn_d0_g, bn_d0_b, d1, st_d1);
  tconv<2, 128, 64, 8, 8, 4, 4, 1, 1, true, true, false><<<dim3(512, 1), 256, 0, stream>>>(
      d1, wcd2, cd2_b, st_d1, bn_d1_g, bn_d1_b, d2, st_d2);
  tconv<2, 64, 32, 16, 8, 8, 2, 1, 1, true, true, false><<<dim3(1024, 1), 256, 0, stream>>>(
      d2, wcd3, cd3_b, st_d2, bn_d2_g, bn_d2_b, d3, st_d3);
  tconv<2, 32, 16, 32, 4, 8, 1, 1, 1, true, false, true><<<dim3(4096, 1), 256, 0, stream>>>(
      d3, wcd4, cd4bp, st_d3, bn_d3_g, bn_d3_b, out, nullptr);
}

// Round 10
// 424.895 us; speedup vs baseline: 1.2580x; 1.0122x over previous
//
#include <hip/hip_runtime.h>
#include <hip/hip_bf16.h>
#include <math.h>

typedef __attribute__((ext_vector_type(8))) short bf16x8;
typedef __attribute__((ext_vector_type(4))) float f32x4;

__device__ __forceinline__ float bf2f(ushort u) {
  union { uint i; float f; } t; t.i = ((uint)u) << 16; return t.f;
}
__device__ __forceinline__ ushort f2bf(float f) {
  __hip_bfloat16 h = __float2bfloat16(f);
  return *reinterpret_cast<ushort*>(&h);
}
__device__ __forceinline__ uint pk(float a, float b) {
  return (uint)f2bf(a) | ((uint)f2bf(b) << 16);
}
constexpr int ilog2c(int v) { int r = 0; while (v > 1) { v >>= 1; ++r; } return r; }

// =====================================================================
// Tiled MFMA conv, fused input-BN+LReLU, fused output batch-stats,
// co-split across blockIdx.y (CS) for occupancy.
// MODE 1: k4s2p1 encoder. MODE 2: up2+3x3 decoder (wave = parity class).
// NB: images per block: raises WM so each weight load feeds WM MFMAs.
// Lesson (R4-R9): keep MFMA:load ratio >=4:1 AND grid >=512 (>=2 blk/CU).
// SIG: fp32 NCHW sigmoid output (cd4, Co padded to 16, real 3).
// =====================================================================
template<int MODE, int Ci, int Co, int HIN, int TR, int WM, int WN, int CS,
         int NB, bool BN, bool OSTAT, bool SIG>
__global__ __launch_bounds__(256) void tconv(const ushort* __restrict__ in,
    const ushort* __restrict__ wt, const float* __restrict__ bias,
    const float* __restrict__ st, const float* __restrict__ g,
    const float* __restrict__ bb, void* __restrict__ out_,
    float* __restrict__ stOut) {
  constexpr int W    = (MODE == 1) ? HIN / 2 : HIN;
  constexpr int LW   = ilog2c(W);
  constexpr int R_IN = (MODE == 1) ? 2 * TR + 2 : TR + 2;
  constexpr int W2   = HIN + 2;
  constexpr int MTPI = TR * W / 16;        // M-tiles per image
  constexpr int MT   = NB * MTPI;          // M-tiles per block
  constexpr int NG   = Co / 16;
  constexpr int NGB  = NG / CS;            // co groups per block
  constexpr int COB  = NGB * 16;           // channels per block
  constexpr int TAPS = (MODE == 1) ? 16 : 4;
  constexpr int RB   = W / TR;
  constexpr int CB   = BN ? Ci : 1;
  constexpr int SB   = OSTAT ? COB : 1;
  constexpr int SN4P = R_IN * W2 * 4;      // 16B staging units per image
  static_assert(TR * W % 16 == 0, "mtile");
  static_assert(MODE == 2 ? (WM == MT && WN == NGB)
                          : ((MT % WM == 0) && (NGB % WN == 0) &&
                             (MT / WM) * (NGB / WN) == 4),
                "wave map");

  __shared__ __align__(16) ushort lt[NB * R_IN * W2 * 40];
  __shared__ float lsc[CB], lsh[CB];
  __shared__ float sst[SB], ssq[SB];

  const int tid  = threadIdx.x;
  const int wave = tid >> 6;
  const int ln15 = tid & 15;
  const int quad = (tid & 63) >> 4;
  const int rb = blockIdx.x % RB;
  const int n0 = (blockIdx.x / RB) * NB;
  const int h0 = rb * TR;
  const int cbase = blockIdx.y * NGB;      // co-group base for this block

  if (BN) {
    constexpr float inv_cnt = 1.0f / (float)(512 * HIN * HIN);
    for (int c = tid; c < Ci; c += 256) {
      float s = 0.f, q = 0.f;
#pragma unroll
      for (int sl = 0; sl < 8; ++sl) {
        s += st[sl * 2 * Ci + c];
        q += st[sl * 2 * Ci + Ci + c];
      }
      float m = s * inv_cnt;
      float var = fmaf(q, inv_cnt, -m * m);
      float sc = g[c] * rsqrtf(var + 1e-5f);
      lsc[c] = sc;
      lsh[c] = fmaf(-m, sc, bb[c]);
    }
  }

  int mt0, cg0, ph, pw, pb;
  if (MODE == 2) { mt0 = 0; cg0 = cbase; ph = wave >> 1; pw = wave & 1; pb = wave * 4; }
  else {
    constexpr int MW = MT / WM;
    mt0 = (wave % MW) * WM; cg0 = cbase + (wave / MW) * WN; ph = 0; pw = 0; pb = 0;
  }

  f32x4 acc[WM][WN];
#pragma unroll
  for (int j = 0; j < WN; ++j) {
    f32x4 b4 = *(const f32x4*)&bias[(cg0 + j) * 16 + quad * 4];
#pragma unroll
    for (int i = 0; i < WM; ++i) acc[i][j] = b4;
  }

  const uint4* src4 = (const uint4*)in;
  const int gr0 = (MODE == 1) ? 2 * h0 - 1 : h0 - 1;

#pragma unroll 1
  for (int c0 = 0; c0 < Ci; c0 += 32) {
    __syncthreads();
    for (int i = tid; i < NB * SN4P; i += 256) {
      int img = (NB == 1) ? 0 : (i / SN4P);
      int ii  = (NB == 1) ? i : (i % SN4P);
      int ciu4 = ii & 3; int t2 = ii >> 2; int c = t2 % W2; int r = t2 / W2;
      int gr = gr0 + r, gc = c - 1;
      uint4 v4 = make_uint4(0u, 0u, 0u, 0u);
      if ((unsigned)gr < (unsigned)HIN && (unsigned)gc < (unsigned)HIN) {
        v4 = src4[((size_t)((n0 + img) * HIN + gr) * HIN + gc) * (Ci / 8) + (c0 >> 3) + ciu4];
        if (BN) {
          uint* pu = (uint*)&v4;
#pragma unroll
          for (int k2 = 0; k2 < 4; ++k2) {
            int cc = c0 + ciu4 * 8 + k2 * 2;
            float f0 = fmaf(bf2f((ushort)(pu[k2] & 0xffffu)), lsc[cc], lsh[cc]);
            float f1 = fmaf(bf2f((ushort)(pu[k2] >> 16)), lsc[cc + 1], lsh[cc + 1]);
            f0 = f0 > 0.f ? f0 : 0.01f * f0;
            f1 = f1 > 0.f ? f1 : 0.01f * f1;
            pu[k2] = pk(f0, f1);
          }
        }
      }
      *(uint4*)&((uint*)lt)[((img * R_IN + r) * W2 + c) * 20 + ciu4 * 4] = v4;
    }
    __syncthreads();

#pragma unroll
    for (int t = 0; t < TAPS; ++t) {
      const int kh = (MODE == 1) ? (t >> 2) : (t >> 1);
      const int kw = (MODE == 1) ? (t & 3) : (t & 1);
      bf16x8 af[WN];
      const ushort* wb = wt + (size_t)(pb + t) * Co * Ci;
#pragma unroll
      for (int j = 0; j < WN; ++j)
        af[j] = *(const bf16x8*)&wb[(size_t)((cg0 + j) * 16 + ln15) * Ci + c0 + quad * 8];
      bf16x8 bfr[WM];
#pragma unroll
      for (int i = 0; i < WM; ++i) {
        int mtile = mt0 + i;
        int img = (NB == 1) ? 0 : (mtile / MTPI);
        int lm  = (NB == 1) ? mtile : (mtile % MTPI);
        int m = lm * 16 + ln15;
        int hr = m >> LW, wr = m & (W - 1);
        int row, col;
        if (MODE == 1) { row = 2 * hr + kh; col = 2 * wr + kw; }
        else           { row = hr + kh + ph; col = wr + kw + pw; }
        bfr[i] = *(const bf16x8*)&lt[((img * R_IN + row) * W2 + col) * 40 + quad * 8];
      }
#pragma unroll
      for (int i = 0; i < WM; ++i)
#pragma unroll
        for (int j = 0; j < WN; ++j)
          acc[i][j] = __builtin_amdgcn_mfma_f32_16x16x32_bf16(af[j], bfr[i], acc[i][j], 0, 0, 0);
    }
  }

  if (OSTAT) {
    for (int c = tid; c < COB; c += 256) { sst[c] = 0.f; ssq[c] = 0.f; }
    __syncthreads();
  }

  if (SIG) {
    constexpr int HO2 = 2 * HIN;
    float* outF = (float*)out_;
#pragma unroll
    for (int i = 0; i < WM; ++i) {
      int mtile = mt0 + i;
      int img = (NB == 1) ? 0 : (mtile / MTPI);
      int lm  = (NB == 1) ? mtile : (mtile % MTPI);
      int m = lm * 16 + ln15;
      int hr = m >> LW, wr = m & (W - 1);
      int oh = 2 * (h0 + hr) + ph, ow = 2 * wr + pw;
      size_t base = (size_t)(n0 + img) * 3 * HO2 * HO2 + (size_t)oh * HO2 + ow;
#pragma unroll
      for (int r = 0; r < 4; ++r) {
        int co = quad * 4 + r;
        if (co < 3)
          outF[base + (size_t)co * HO2 * HO2] = 1.f / (1.f + __expf(-acc[i][0][r]));
      }
    }
  } else {
    ushort* out = (ushort*)out_;
#pragma unroll
    for (int i = 0; i < WM; ++i) {
      int mtile = mt0 + i;
      int img = (NB == 1) ? 0 : (mtile / MTPI);
      int lm  = (NB == 1) ? mtile : (mtile % MTPI);
      int m = lm * 16 + ln15;
      int hr = m >> LW, wr = m & (W - 1);
      size_t sp;
      if (MODE == 2) {
        int oh = 2 * (h0 + hr) + ph, ow = 2 * wr + pw;
        sp = ((size_t)(n0 + img) * (2 * HIN) + oh) * (2 * HIN) + ow;
      } else {
        sp = ((size_t)(n0 + img) * W + h0 + hr) * W + wr;
      }
#pragma unroll
      for (int j = 0; j < WN; ++j) {
        f32x4 a = acc[i][j];
        uint2 stv; stv.x = pk(a[0], a[1]); stv.y = pk(a[2], a[3]);
        *(uint2*)&out[sp * Co + (cg0 + j) * 16 + quad * 4] = stv;
      }
    }
  }

  if (OSTAT) {
#pragma unroll
    for (int j = 0; j < WN; ++j)
#pragma unroll
      for (int r = 0; r < 4; ++r) {
        float s = 0.f, q = 0.f;
#pragma unroll
        for (int i = 0; i < WM; ++i) {
          float v = acc[i][j][r];
          s += v; q = fmaf(v, v, q);
        }
#pragma unroll
        for (int mk = 1; mk < 16; mk <<= 1) {
          s += __shfl_xor(s, mk);
          q += __shfl_xor(q, mk);
        }
        if (ln15 == 0) {
          int lc = (cg0 + j) * 16 + quad * 4 + r - cbase * 16;
          atomicAdd(&sst[lc], s);
          atomicAdd(&ssq[lc], q);
        }
      }
    __syncthreads();
    float* d = stOut + (size_t)(blockIdx.x & 7) * 2 * Co;
    for (int c = tid; c < COB; c += 256) {
      atomicAdd(&d[cbase * 16 + c], sst[c]);
      atomicAdd(&d[Co + cbase * 16 + c], ssq[c]);
    }
  }
}

// ===================== 1x1 conv GEMM, fused input-BN + output stats ==========
template<int Ci, int Co, int COT, bool BN, int NPIX, bool OSTAT>
__global__ __launch_bounds__(256) void g1x1(const ushort* __restrict__ in,
    const ushort* __restrict__ wt, const float* __restrict__ bias,
    const float* __restrict__ st, const float* __restrict__ g,
    const float* __restrict__ bb, ushort* __restrict__ out,
    float* __restrict__ stOut) {
  constexpr int NG = COT / 16;
  constexpr int CB = BN ? Ci : 1;
  constexpr int SB = OSTAT ? COT : 1;
  __shared__ __align__(16) ushort lb[64 * 40];
  __shared__ float lsc[CB], lsh[CB];
  __shared__ float sst[SB], ssq[SB];
  const int tid = threadIdx.x, wave = tid >> 6, ln15 = tid & 15, quad = (tid & 63) >> 4;
  const int pixBase = blockIdx.x * 64;
  const int co0 = blockIdx.y * COT;
  if (BN) {
    constexpr float inv_cnt = 1.0f / (float)NPIX;
    for (int c = tid; c < Ci; c += 256) {
      float s = 0.f, q = 0.f;
#pragma unroll
      for (int sl = 0; sl < 8; ++sl) {
        s += st[sl * 2 * Ci + c];
        q += st[sl * 2 * Ci + Ci + c];
      }
      float m = s * inv_cnt;
      float var = fmaf(q, inv_cnt, -m * m);
      float sc = g[c] * rsqrtf(var + 1e-5f);
      lsc[c] = sc;
      lsh[c] = fmaf(-m, sc, bb[c]);
    }
  }
  f32x4 acc[NG];
#pragma unroll
  for (int j = 0; j < NG; ++j) acc[j] = *(const f32x4*)&bias[co0 + j * 16 + quad * 4];
  const uint4* src4 = (const uint4*)in;
#pragma unroll 1
  for (int c0 = 0; c0 < Ci; c0 += 32) {
    __syncthreads();
    {
      int ciu4 = tid & 3, pl = tid >> 2;
      uint4 v4 = src4[(size_t)(pixBase + pl) * (Ci / 8) + (c0 >> 3) + ciu4];
      if (BN) {
        uint* pu = (uint*)&v4;
#pragma unroll
        for (int k2 = 0; k2 < 4; ++k2) {
          int cc = c0 + ciu4 * 8 + k2 * 2;
          float f0 = fmaf(bf2f((ushort)(pu[k2] & 0xffffu)), lsc[cc], lsh[cc]);
          float f1 = fmaf(bf2f((ushort)(pu[k2] >> 16)), lsc[cc + 1], lsh[cc + 1]);
          f0 = f0 > 0.f ? f0 : 0.01f * f0;
          f1 = f1 > 0.f ? f1 : 0.01f * f1;
          pu[k2] = pk(f0, f1);
        }
      }
      *(uint4*)&((uint*)lb)[pl * 20 + ciu4 * 4] = v4;
    }
    __syncthreads();
    bf16x8 bfr = *(const bf16x8*)&lb[(wave * 16 + ln15) * 40 + quad * 8];
#pragma unroll
    for (int j = 0; j < NG; ++j) {
      bf16x8 af = *(const bf16x8*)&wt[(size_t)(co0 + j * 16 + ln15) * Ci + c0 + quad * 8];
      acc[j] = __builtin_amdgcn_mfma_f32_16x16x32_bf16(af, bfr, acc[j], 0, 0, 0);
    }
  }
  if (OSTAT) {
    for (int c = tid; c < COT; c += 256) { sst[c] = 0.f; ssq[c] = 0.f; }
    __syncthreads();
  }
  int pix = pixBase + wave * 16 + ln15;
#pragma unroll
  for (int j = 0; j < NG; ++j) {
    uint2 stv; stv.x = pk(acc[j][0], acc[j][1]); stv.y = pk(acc[j][2], acc[j][3]);
    *(uint2*)&out[(size_t)pix * Co + co0 + j * 16 + quad * 4] = stv;
  }
  if (OSTAT) {
#pragma unroll
    for (int j = 0; j < NG; ++j)
#pragma unroll
      for (int r = 0; r < 4; ++r) {
        float s = acc[j][r];
        float q = s * s;
#pragma unroll
        for (int mk = 1; mk < 16; mk <<= 1) {
          s += __shfl_xor(s, mk);
          q += __shfl_xor(q, mk);
        }
        if (ln15 == 0) {
          int cl = j * 16 + quad * 4 + r;
          atomicAdd(&sst[cl], s);
          atomicAdd(&ssq[cl], q);
        }
      }
    __syncthreads();
    float* d = stOut + (size_t)(blockIdx.x & 7) * 2 * Co;
    for (int c = tid; c < COT; c += 256) {
      atomicAdd(&d[co0 + c], sst[c]);
      atomicAdd(&d[Co + co0 + c], ssq[c]);
    }
  }
}

// ===================== ce1 (MFMA): k4s2p1, Ci=3, fp32 NCHW -> bf16 NHWC + stats ===
__global__ __launch_bounds__(256) void ce1_mfma(const float* __restrict__ x,
    const ushort* __restrict__ wt, const float* __restrict__ bias,
    ushort* __restrict__ out, float* __restrict__ stOut) {
  __shared__ __align__(16) float lt[3 * 18 * 72];   // padded fp32 tile, 15.2 KB
  __shared__ float sst[32], ssq[32];
  const int tid = threadIdx.x, wave = tid >> 6, ln15 = tid & 15, quad = (tid & 63) >> 4;
  const int pixBase = blockIdx.x * 256;     // 8 out rows x 32 cols, one image
  const int n  = pixBase >> 10;
  const int h0 = (pixBase >> 5) & 31;
  if (tid < 32) { sst[tid] = 0.f; ssq[tid] = 0.f; }
  const int gr0 = 2 * h0 - 1;
  for (int i = tid; i < 3 * 18 * 72; i += 256) {
    int c = i % 72; int rem = i / 72; int r = rem % 18; int ci = rem / 18;
    int gr = gr0 + r, gc = c - 1;
    float v = 0.f;
    if ((unsigned)gr < 64u && (unsigned)gc < 64u)
      v = x[(((size_t)n * 3 + ci) << 12) + (gr << 6) + gc];
    lt[i] = v;
  }
  __syncthreads();

  f32x4 acc[4][2];
#pragma unroll
  for (int j = 0; j < 2; ++j) {
    f32x4 b4 = *(const f32x4*)&bias[j * 16 + quad * 4];
#pragma unroll
    for (int i = 0; i < 4; ++i) acc[i][j] = b4;
  }
  bf16x8 af[2][2];
#pragma unroll
  for (int j = 0; j < 2; ++j)
#pragma unroll
    for (int kk = 0; kk < 2; ++kk)
      af[j][kk] = *(const bf16x8*)&wt[(j * 16 + ln15) * 64 + kk * 32 + quad * 8];

  const int mt0 = wave * 4;
#pragma unroll
  for (int i = 0; i < 4; ++i) {
    int p = (mt0 + i) * 16 + ln15;        // px within block
    int h = p >> 5, w = p & 31;           // local out row/col
#pragma unroll
    for (int kk = 0; kk < 2; ++kk) {
      int k0 = kk * 32 + quad * 8;        // k = (ci*16 + kh*4 + kw)
      bf16x8 bfr = (bf16x8)(short)0;
      if (k0 < 48) {
        int ci = k0 >> 4, kh0 = (k0 >> 2) & 3;   // 8 k's = 2 rows x 4 kw
        const float* rp = &lt[(ci * 18 + 2 * h + kh0) * 72 + 2 * w];
        uint4 uu = make_uint4(pk(rp[0], rp[1]), pk(rp[2], rp[3]),
                              pk(rp[72], rp[73]), pk(rp[74], rp[75]));
        bfr = *reinterpret_cast<bf16x8*>(&uu);
      }
#pragma unroll
      for (int j = 0; j < 2; ++j)
        acc[i][j] = __builtin_amdgcn_mfma_f32_16x16x32_bf16(af[j][kk], bfr, acc[i][j], 0, 0, 0);
    }
  }
  // ---- store bf16 NHWC [px][32] ----
#pragma unroll
  for (int i = 0; i < 4; ++i) {
    int sp = pixBase + (mt0 + i) * 16 + ln15;
#pragma unroll
    for (int j = 0; j < 2; ++j) {
      f32x4 a = acc[i][j];
      uint2 stv; stv.x = pk(a[0], a[1]); stv.y = pk(a[2], a[3]);
      *(uint2*)&out[(size_t)sp * 32 + j * 16 + quad * 4] = stv;
    }
  }
  // ---- fused batch stats (16-lane reduce like tconv OSTAT) ----
#pragma unroll
  for (int j = 0; j < 2; ++j)
#pragma unroll
    for (int r = 0; r < 4; ++r) {
      float s = 0.f, q = 0.f;
#pragma unroll
      for (int i = 0; i < 4; ++i) {
        float v = acc[i][j][r];
        s += v; q = fmaf(v, v, q);
      }
#pragma unroll
      for (int mk = 1; mk < 16; mk <<= 1) {
        s += __shfl_xor(s, mk);
        q += __shfl_xor(q, mk);
      }
      if (ln15 == 0) {
        int ch = j * 16 + quad * 4 + r;
        atomicAdd(&sst[ch], s);
        atomicAdd(&ssq[ch], q);
      }
    }
  __syncthreads();
  if (tid < 32) {
    float* d = stOut + (size_t)(blockIdx.x & 7) * 64;
    atomicAdd(&d[tid], sst[tid]);
    atomicAdd(&d[32 + tid], ssq[tid]);
  }
}

// ===================== prep: ALL weight transforms + codebook, one dispatch ======
__device__ __forceinline__ void enc_tr(const float* __restrict__ w,
    ushort* __restrict__ o, int Co, int Ci, int idx) {
  int ci = idx % Ci; int r = idx / Ci; int co = r % Co; int t = r / Co;
  o[idx] = f2bf(w[(co * Ci + ci) * 16 + t]);
}
__device__ __forceinline__ float dec_comb(const float* __restrict__ w,
    int Ci, int co, int ci, int pt) {
  int p = pt >> 2, t = pt & 3;
  int ph = p >> 1, pw = p & 1, rr = t >> 1, cc = t & 1;
  int rs = (rr == 0) ? 0 : (ph == 0 ? 1 : 2);
  int re = (rr == 0) ? (ph == 0 ? 1 : 2) : 3;
  int cs = (cc == 0) ? 0 : (pw == 0 ? 1 : 2);
  int ce = (cc == 0) ? (pw == 0 ? 1 : 2) : 3;
  float s = 0.f;
  for (int kh = rs; kh < re; ++kh)
    for (int kw = cs; kw < ce; ++kw)
      s += w[((co * Ci + ci) * 3 + kh) * 3 + kw];
  return s;
}
__device__ __forceinline__ void dec_tr(const float* __restrict__ w,
    ushort* __restrict__ o, int Co, int Ci, int idx) {
  int ci = idx % Ci; int r = idx / Ci; int co = r % Co; int pt = r / Co;
  o[idx] = f2bf(dec_comb(w, Ci, co, ci, pt));
}

__global__ __launch_bounds__(256) void prep_all(
    const float* __restrict__ ce1_w,
    const float* __restrict__ ce2_w, const float* __restrict__ ce3_w,
    const float* __restrict__ ce4_w, const float* __restrict__ ce5_w,
    const float* __restrict__ cd0_w, const float* __restrict__ cd1_w,
    const float* __restrict__ cd2_w, const float* __restrict__ cd3_w,
    const float* __restrict__ cd4_w, const float* __restrict__ cd4_b,
    const float* __restrict__ codebook,
    ushort* __restrict__ wce1b,
    ushort* __restrict__ wce2, ushort* __restrict__ wce3, ushort* __restrict__ wce4,
    ushort* __restrict__ wce5, ushort* __restrict__ wcd0, ushort* __restrict__ wcd1,
    ushort* __restrict__ wcd2, ushort* __restrict__ wcd3, ushort* __restrict__ wcd4,
    float* __restrict__ cd4bp, ushort* __restrict__ cbbf, float* __restrict__ wsq) {
  __shared__ float sh[4];
  int bx = blockIdx.x, tid = threadIdx.x;
  if (bx < 2048) { int i = bx * 256 + tid; cbbf[i] = f2bf(codebook[i]); return; }
  bx -= 2048;
  if (bx < 512) {
    int k = bx;
    float s = 0.f;
    for (int d = tid; d < 1024; d += 256) {
      float v = codebook[k * 1024 + d];
      s = fmaf(v, v, s);
    }
#pragma unroll
    for (int o = 32; o > 0; o >>= 1) s += __shfl_down(s, o);
    if ((tid & 63) == 0) sh[tid >> 6] = s;
    __syncthreads();
    if (tid == 0) wsq[k] = sh[0] + sh[1] + sh[2] + sh[3];
    return;
  }
  bx -= 512;
  if (bx < 2048) { enc_tr(ce4_w, wce4, 256, 128, bx * 256 + tid); return; }
  bx -= 2048;
  if (bx < 2048) { dec_tr(cd1_w, wcd1, 128, 256, bx * 256 + tid); return; }
  bx -= 2048;
  if (bx < 512)  { enc_tr(ce3_w, wce3, 128, 64, bx * 256 + tid); return; }
  bx -= 512;
  if (bx < 512)  { dec_tr(cd2_w, wcd2, 64, 128, bx * 256 + tid); return; }
  bx -= 512;
  if (bx < 128)  { enc_tr(ce2_w, wce2, 64, 32, bx * 256 + tid); return; }
  bx -= 128;
  if (bx < 128)  { dec_tr(cd3_w, wcd3, 32, 64, bx * 256 + tid); return; }
  bx -= 128;
  if (bx < 64)   { int i = bx * 256 + tid; wce5[i] = f2bf(ce5_w[i]); return; }
  bx -= 64;
  if (bx < 64)   { int i = bx * 256 + tid; wcd0[i] = f2bf(cd0_w[i]); return; }
  bx -= 64;
  if (bx < 32) {                // cd4 padded: [16 taps][16 co][32 ci]
    int idx = bx * 256 + tid;   // 32 blocks
    int ci = idx & 31; int r = idx >> 5; int co = r & 15; int pt = r >> 4;
    wcd4[idx] = (co < 3) ? f2bf(dec_comb(cd4_w, 32, co, ci, pt)) : (ushort)0;
    if (bx == 0 && tid < 16) cd4bp[tid] = (tid < 3) ? cd4_b[tid] : 0.f;
    return;
  }
  bx -= 32;
  {                             // ce1 bf16 weights: [32 co][64 k], k>=48 zero; 8 blocks
    int idx = bx * 256 + tid;   // 0..2047
    int k = idx & 63, co = idx >> 6;
    wce1b[idx] = (k < 48) ? f2bf(ce1_w[co * 48 + k]) : (ushort)0;
  }
}

// ===================== VQ ==========
// vq_gemm with fused zprep: stages Z directly from r5 applying BN+LReLU
// (r5 layout [8192 px][64 ch] == Z rows [512][1024], ch = d & 63).
// Blocks with k0==0 also write fp32 Z (single writer per element).
// KS=8 K-slices -> grid (8,8,8)=512 blocks (2 blk/CU).
__global__ __launch_bounds__(256) void vq_gemm(const ushort* __restrict__ r5,
    const ushort* __restrict__ cbbf, const float* __restrict__ st,
    const float* __restrict__ g, const float* __restrict__ bb,
    float* __restrict__ Z, float* __restrict__ S) {
  __shared__ __align__(16) ushort lZ[64 * 40], lW[64 * 40];
  __shared__ float lsc[64], lsh[64];
  const int tid = threadIdx.x, wave = tid >> 6, ln15 = tid & 15, quad = (tid & 63) >> 4;
  const int b0 = blockIdx.x * 64, k0 = blockIdx.y * 64, ks = blockIdx.z;
  if (tid < 64) {
    float s = 0.f, q = 0.f;
#pragma unroll
    for (int sl = 0; sl < 8; ++sl) { s += st[sl * 128 + tid]; q += st[sl * 128 + 64 + tid]; }
    float m = s * (1.0f / 8192.f);
    float var = fmaf(q, 1.0f / 8192.f, -m * m);
    float sc = g[tid] * rsqrtf(var + 1e-5f);
    lsc[tid] = sc;
    lsh[tid] = fmaf(-m, sc, bb[tid]);
  }
  f32x4 acc[4];
#pragma unroll
  for (int j = 0; j < 4; ++j) acc[j] = (f32x4)(0.f);
  const uint4* zs = (const uint4*)r5;
  const uint4* ws = (const uint4*)cbbf;
  const bool wrZ = (blockIdx.y == 0);
#pragma unroll 1
  for (int c0 = ks * 128; c0 < ks * 128 + 128; c0 += 32) {
    __syncthreads();
    for (int i = tid; i < 512; i += 256) {
      int ciu4 = i & 3; int rl = (i >> 2) & 63; bool isW = i >= 256;
      uint4 v = (isW ? ws : zs)[(size_t)((isW ? k0 : b0) + rl) * 128 + (c0 >> 3) + ciu4];
      if (!isW) {
        uint* pu = (uint*)&v;
        float zf[8];
#pragma unroll
        for (int k2 = 0; k2 < 4; ++k2) {
          int cc = (c0 + ciu4 * 8 + k2 * 2) & 63;
          float f0 = fmaf(bf2f((ushort)(pu[k2] & 0xffffu)), lsc[cc], lsh[cc]);
          float f1 = fmaf(bf2f((ushort)(pu[k2] >> 16)), lsc[cc + 1], lsh[cc + 1]);
          f0 = f0 > 0.f ? f0 : 0.01f * f0;
          f1 = f1 > 0.f ? f1 : 0.01f * f1;
          pu[k2] = pk(f0, f1);
          zf[2 * k2] = f0; zf[2 * k2 + 1] = f1;
        }
        if (wrZ) {
          float* zp = &Z[(size_t)(b0 + rl) * 1024 + c0 + ciu4 * 8];
          *(float4*)zp       = make_float4(zf[0], zf[1], zf[2], zf[3]);
          *(float4*)(zp + 4) = make_float4(zf[4], zf[5], zf[6], zf[7]);
        }
      }
      *(uint4*)&((uint*)(isW ? lW : lZ))[rl * 20 + ciu4 * 4] = v;
    }
    __syncthreads();
    bf16x8 bfr = *(const bf16x8*)&lZ[(wave * 16 + ln15) * 40 + quad * 8];
#pragma unroll
    for (int j = 0; j < 4; ++j) {
      bf16x8 af = *(const bf16x8*)&lW[(j * 16 + ln15) * 40 + quad * 8];
      acc[j] = __builtin_amdgcn_mfma_f32_16x16x32_bf16(af, bfr, acc[j], 0, 0, 0);
    }
  }
  int b = b0 + wave * 16 + ln15;
  float* Sk = S + (size_t)ks * 262144;
#pragma unroll
  for (int j = 0; j < 4; ++j)
    *(f32x4*)&Sk[(size_t)b * 512 + k0 + j * 16 + quad * 4] = acc[j];
}

// fused: argmin scan + gather Zq + exact fp32 loss + last-block writes losses
__global__ __launch_bounds__(256) void vq_post(const float* __restrict__ S,
    const float* __restrict__ wsq, const float* __restrict__ Z,
    const float* __restrict__ cb, ushort* __restrict__ Zq,
    float* __restrict__ lossAcc, int* __restrict__ cnt, float* __restrict__ out2) {
  int b = blockIdx.x, tid = threadIdx.x;
  float s1 = 0.f, s2 = 0.f;
#pragma unroll
  for (int sl = 0; sl < 8; ++sl) {
    s1 += S[(size_t)sl * 262144 + (size_t)b * 512 + tid];
    s2 += S[(size_t)sl * 262144 + (size_t)b * 512 + tid + 256];
  }
  float d1 = fmaf(-2.f, s1, wsq[tid]);
  float d2 = fmaf(-2.f, s2, wsq[tid + 256]);
  float bv = d1; int bk = tid;
  if (d2 < bv) { bv = d2; bk = tid + 256; }
  __shared__ float vsh[256]; __shared__ int ish[256];
  vsh[tid] = bv; ish[tid] = bk;
  __syncthreads();
  for (int s = 128; s > 0; s >>= 1) {
    if (tid < s) {
      float ov = vsh[tid + s]; int oi = ish[tid + s];
      if (ov < vsh[tid] || (ov == vsh[tid] && oi < ish[tid])) { vsh[tid] = ov; ish[tid] = oi; }
    }
    __syncthreads();
  }
  int k = ish[0];
  const float* w = cb + ((long)k << 10);
  const float* zp = Z + ((long)b << 10);
  float part = 0.f;
  for (int d = tid; d < 1024; d += 256) {
    float wv = w[d];
    float diff = zp[d] - wv;
    part = fmaf(diff, diff, part);
    Zq[(b << 10) + d] = f2bf(wv);
  }
#pragma unroll
  for (int o = 32; o > 0; o >>= 1) part += __shfl_down(part, o);
  __shared__ float sh[4];
  if ((tid & 63) == 0) sh[tid >> 6] = part;
  __syncthreads();
  if (tid == 0) {
    atomicAdd(lossAcc, sh[0] + sh[1] + sh[2] + sh[3]);
    __threadfence();
    int old = atomicAdd(cnt, 1);
    if (old == 511) {
      float v = *(volatile float*)lossAcc * (1.0f / 512.0f);
      out2[0] = v;
      out2[1] = v;
    }
  }
}

// ===================== launch ==========
extern "C" void kernel_launch(void* const* d_in, const int* in_sizes, int n_in,
                              void* d_out, int out_size, void* d_ws, size_t ws_size,
                              hipStream_t stream) {
  const float* x      = (const float*)d_in[0];
  const float* ce1_w  = (const float*)d_in[1];  const float* ce1_b = (const float*)d_in[2];
  const float* ce2_w  = (const float*)d_in[3];  const float* ce2_b = (const float*)d_in[4];
  const float* ce3_w  = (const float*)d_in[5];  const float* ce3_b = (const float*)d_in[6];
  const float* ce4_w  = (const float*)d_in[7];  const float* ce4_b = (const float*)d_in[8];
  const float* ce5_w  = (const float*)d_in[9];  const float* ce5_b = (const float*)d_in[10];
  const float* cd0_w  = (const float*)d_in[11]; const float* cd0_b = (const float*)d_in[12];
  const float* cd1_w  = (const float*)d_in[13]; const float* cd1_b = (const float*)d_in[14];
  const float* cd2_w  = (const float*)d_in[15]; const float* cd2_b = (const float*)d_in[16];
  const float* cd3_w  = (const float*)d_in[17]; const float* cd3_b = (const float*)d_in[18];
  const float* cd4_w  = (const float*)d_in[19]; const float* cd4_b = (const float*)d_in[20];
  const float* bn_e1_g = (const float*)d_in[21]; const float* bn_e1_b = (const float*)d_in[22];
  const float* bn_e2_g = (const float*)d_in[23]; const float* bn_e2_b = (const float*)d_in[24];
  const float* bn_e3_g = (const float*)d_in[25]; const float* bn_e3_b = (const float*)d_in[26];
  const float* bn_e4_g = (const float*)d_in[27]; const float* bn_e4_b = (const float*)d_in[28];
  const float* bn_e5_g = (const float*)d_in[29]; const float* bn_e5_b = (const float*)d_in[30];
  const float* bn_d0_g = (const float*)d_in[31]; const float* bn_d0_b = (const float*)d_in[32];
  const float* bn_d1_g = (const float*)d_in[33]; const float* bn_d1_b = (const float*)d_in[34];
  const float* bn_d2_g = (const float*)d_in[35]; const float* bn_d2_b = (const float*)d_in[36];
  const float* bn_d3_g = (const float*)d_in[37]; const float* bn_d3_b = (const float*)d_in[38];
  const float* codebook = (const float*)d_in[39];

  float* out = (float*)d_out;

  // ---- workspace carve ----
  char* p = (char*)d_ws;
  auto alloc = [&](size_t bytes) { void* r = p; p += (bytes + 255) & ~(size_t)255; return r; };
  ushort* r1 = (ushort*)alloc((size_t)524288 * 32 * 2);
  ushort* r2 = (ushort*)alloc((size_t)131072 * 64 * 2);
  ushort* r3 = (ushort*)alloc((size_t)32768 * 128 * 2);
  ushort* r4 = (ushort*)alloc((size_t)8192 * 256 * 2);
  ushort* r5 = (ushort*)alloc((size_t)8192 * 64 * 2);
  ushort* d0 = (ushort*)alloc((size_t)8192 * 256 * 2);
  ushort* d1 = (ushort*)alloc((size_t)32768 * 128 * 2);
  ushort* d2 = (ushort*)alloc((size_t)131072 * 64 * 2);
  ushort* d3 = (ushort*)alloc((size_t)524288 * 32 * 2);
  float*  Z    = (float*)alloc((size_t)524288 * 4);
  ushort* cbbf = (ushort*)alloc((size_t)524288 * 2);
  float*  S    = (float*)alloc((size_t)8 * 262144 * 4);   // 8 K-slices
  ushort* Zq   = (ushort*)alloc((size_t)524288 * 2);
  float*  wsq  = (float*)alloc((size_t)512 * 4);
  ushort* wce2 = (ushort*)alloc((size_t)16 * 64 * 32 * 2);
  ushort* wce3 = (ushort*)alloc((size_t)16 * 128 * 64 * 2);
  ushort* wce4 = (ushort*)alloc((size_t)16 * 256 * 128 * 2);
  ushort* wce5 = (ushort*)alloc((size_t)64 * 256 * 2);
  ushort* wcd0 = (ushort*)alloc((size_t)256 * 64 * 2);
  ushort* wcd1 = (ushort*)alloc((size_t)16 * 128 * 256 * 2);
  ushort* wcd2 = (ushort*)alloc((size_t)16 * 64 * 128 * 2);
  ushort* wcd3 = (ushort*)alloc((size_t)16 * 32 * 64 * 2);
  ushort* wcd4 = (ushort*)alloc((size_t)16 * 16 * 32 * 2);
  ushort* wce1b = (ushort*)alloc((size_t)32 * 64 * 2);
  float*  cd4bp = (float*)alloc(64);
  float*  statsAll = (float*)alloc((size_t)(9 * 4096 + 64) * 4);
  int*    jbuf = (int*)alloc((size_t)512 * 4);

  float* st_e1 = statsAll + 0 * 4096;
  float* st_e2 = statsAll + 1 * 4096;
  float* st_e3 = statsAll + 2 * 4096;
  float* st_e4 = statsAll + 3 * 4096;
  float* st_e5 = statsAll + 4 * 4096;
  float* st_d0 = statsAll + 5 * 4096;
  float* st_d1 = statsAll + 6 * 4096;
  float* st_d2 = statsAll + 7 * 4096;
  float* st_d3 = statsAll + 8 * 4096;
  float* lossAcc = statsAll + 9 * 4096;
  int*   cnt = (int*)(lossAcc + 1);

  hipMemsetAsync(statsAll, 0, (size_t)(9 * 4096 + 64) * 4, stream);

  prep_all<<<8104, 256, 0, stream>>>(ce1_w, ce2_w, ce3_w, ce4_w, ce5_w, cd0_w, cd1_w,
      cd2_w, cd3_w, cd4_w, cd4_b, codebook,
      wce1b, wce2, wce3, wce4, wce5, wcd0, wcd1, wcd2, wcd3, wcd4, cd4bp, cbbf, wsq);

  // ---- encoder ----
  ce1_mfma<<<2048, 256, 0, stream>>>(x, wce1b, ce1_b, r1, st_e1);
  tconv<1, 32, 64, 32, 8, 4, 2, 1, 1, true, true, false><<<dim3(1024, 1), 256, 0, stream>>>(
      r1, wce2, ce2_b, st_e1, bn_e1_g, bn_e1_b, r2, st_e2);
  tconv<1, 64, 128, 16, 8, 4, 2, 1, 1, true, true, false><<<dim3(512, 1), 256, 0, stream>>>(
      r2, wce3, ce3_b, st_e2, bn_e2_g, bn_e2_b, r3, st_e3);
  tconv<1, 128, 256, 8, 4, 4, 1, 4, 4, true, true, false><<<dim3(128, 4), 256, 0, stream>>>(
      r3, wce4, ce4_b, st_e3, bn_e3_g, bn_e3_b, r4, st_e4);
  g1x1<256, 64, 16, true, 8192, true><<<dim3(128, 4), 256, 0, stream>>>(
      r4, wce5, ce5_b, st_e4, bn_e4_g, bn_e4_b, r5, st_e5);

  // ---- VQ (zprep fused into vq_gemm; 8 K-slices for 2 blk/CU) ----
  vq_gemm<<<dim3(8, 8, 8), 256, 0, stream>>>(r5, cbbf, st_e5, bn_e5_g, bn_e5_b, Z, S);
  vq_post<<<512, 256, 0, stream>>>(S, wsq, Z, codebook, Zq, lossAcc, cnt, out + 6291456);

  // ---- decoder ----
  g1x1<64, 256, 32, false, 1, true><<<dim3(128, 8), 256, 0, stream>>>(
      Zq, wcd0, cd0_b, nullptr, nullptr, nullptr, d0, st_d0);
  tconv<2, 256, 128, 4, 4, 4, 2, 4, 4, true, true, false><<<dim3(128, 4), 256, 0, stream>>>(
      d0, wcd1, cd1_b, st_d0, bn_d0_g, bn_d0_b, d1, st_d1);
  tconv<2, 128, 64, 8, 8, 4, 4, 1, 1, true, true, false><<<dim3(512, 1), 256, 0, stream>>>(
      d1, wcd2, cd2_b, st_d1, bn_d1_g, bn_d1_b, d2, st_d2);
  tconv<2, 64, 32, 16, 8, 8, 2, 1, 1, true, true, false><<<dim3(1024, 1), 256, 0, stream>>>(
      d2, wcd3, cd3_b, st_d2, bn_d2_g, bn_d2_b, d3, st_d3);
  tconv<2, 32, 16, 32, 4, 8, 1, 1, 1, true, false, true><<<dim3(4096, 1), 256, 0, stream>>>(
      d3, wcd4, cd4bp, st_d3, bn_d3_g, bn_d3_b, out, nullptr);
}

// Round 11
// 417.651 us; speedup vs baseline: 1.2798x; 1.0173x over previous
//
#include <hip/hip_runtime.h>
#include <hip/hip_bf16.h>
#include <math.h>

typedef __attribute__((ext_vector_type(8))) short bf16x8;
typedef __attribute__((ext_vector_type(4))) float f32x4;

__device__ __forceinline__ float bf2f(ushort u) {
  union { uint i; float f; } t; t.i = ((uint)u) << 16; return t.f;
}
__device__ __forceinline__ ushort f2bf(float f) {
  __hip_bfloat16 h = __float2bfloat16(f);
  return *reinterpret_cast<ushort*>(&h);
}
__device__ __forceinline__ uint pk(float a, float b) {
  return (uint)f2bf(a) | ((uint)f2bf(b) << 16);
}
constexpr int ilog2c(int v) { int r = 0; while (v > 1) { v >>= 1; ++r; } return r; }

// =====================================================================
// Tiled MFMA conv, fused input-BN+LReLU, fused output batch-stats,
// co-split across blockIdx.y (CS) for occupancy.
// MODE 1: k4s2p1 encoder. MODE 2: up2+3x3 decoder (wave = parity class).
// NB: images per block: raises WM so each weight load feeds WM MFMAs.
// Lesson (R4-R9): keep MFMA:load ratio >=4:1 AND grid >=512 (>=2 blk/CU).
// SIG (R11): fp32 NCHW sigmoid output staged through LDS -> coalesced
// row writes (direct scatter was stride-2 dwords with 48/64 lanes idle).
// =====================================================================
template<int MODE, int Ci, int Co, int HIN, int TR, int WM, int WN, int CS,
         int NB, bool BN, bool OSTAT, bool SIG>
__global__ __launch_bounds__(256) void tconv(const ushort* __restrict__ in,
    const ushort* __restrict__ wt, const float* __restrict__ bias,
    const float* __restrict__ st, const float* __restrict__ g,
    const float* __restrict__ bb, void* __restrict__ out_,
    float* __restrict__ stOut) {
  constexpr int W    = (MODE == 1) ? HIN / 2 : HIN;
  constexpr int LW   = ilog2c(W);
  constexpr int R_IN = (MODE == 1) ? 2 * TR + 2 : TR + 2;
  constexpr int W2   = HIN + 2;
  constexpr int MTPI = TR * W / 16;        // M-tiles per image
  constexpr int MT   = NB * MTPI;          // M-tiles per block
  constexpr int NG   = Co / 16;
  constexpr int NGB  = NG / CS;            // co groups per block
  constexpr int COB  = NGB * 16;           // channels per block
  constexpr int TAPS = (MODE == 1) ? 16 : 4;
  constexpr int RB   = W / TR;
  constexpr int CB   = BN ? Ci : 1;
  constexpr int SB   = OSTAT ? COB : 1;
  constexpr int SGB  = SIG ? (3 * 2 * TR * 2 * W) : 1;  // staged sigmoid tile
  constexpr int SN4P = R_IN * W2 * 4;      // 16B staging units per image
  static_assert(TR * W % 16 == 0, "mtile");
  static_assert(!SIG || NB == 1, "SIG assumes NB==1");
  static_assert(MODE == 2 ? (WM == MT && WN == NGB)
                          : ((MT % WM == 0) && (NGB % WN == 0) &&
                             (MT / WM) * (NGB / WN) == 4),
                "wave map");

  __shared__ __align__(16) ushort lt[NB * R_IN * W2 * 40];
  __shared__ float lsc[CB], lsh[CB];
  __shared__ float sst[SB], ssq[SB];
  __shared__ float sgb[SGB];

  const int tid  = threadIdx.x;
  const int wave = tid >> 6;
  const int ln15 = tid & 15;
  const int quad = (tid & 63) >> 4;
  const int rb = blockIdx.x % RB;
  const int n0 = (blockIdx.x / RB) * NB;
  const int h0 = rb * TR;
  const int cbase = blockIdx.y * NGB;      // co-group base for this block

  if (BN) {
    constexpr float inv_cnt = 1.0f / (float)(512 * HIN * HIN);
    for (int c = tid; c < Ci; c += 256) {
      float s = 0.f, q = 0.f;
#pragma unroll
      for (int sl = 0; sl < 8; ++sl) {
        s += st[sl * 2 * Ci + c];
        q += st[sl * 2 * Ci + Ci + c];
      }
      float m = s * inv_cnt;
      float var = fmaf(q, inv_cnt, -m * m);
      float sc = g[c] * rsqrtf(var + 1e-5f);
      lsc[c] = sc;
      lsh[c] = fmaf(-m, sc, bb[c]);
    }
  }

  int mt0, cg0, ph, pw, pb;
  if (MODE == 2) { mt0 = 0; cg0 = cbase; ph = wave >> 1; pw = wave & 1; pb = wave * 4; }
  else {
    constexpr int MW = MT / WM;
    mt0 = (wave % MW) * WM; cg0 = cbase + (wave / MW) * WN; ph = 0; pw = 0; pb = 0;
  }

  f32x4 acc[WM][WN];
#pragma unroll
  for (int j = 0; j < WN; ++j) {
    f32x4 b4 = *(const f32x4*)&bias[(cg0 + j) * 16 + quad * 4];
#pragma unroll
    for (int i = 0; i < WM; ++i) acc[i][j] = b4;
  }

  const uint4* src4 = (const uint4*)in;
  const int gr0 = (MODE == 1) ? 2 * h0 - 1 : h0 - 1;

#pragma unroll 1
  for (int c0 = 0; c0 < Ci; c0 += 32) {
    __syncthreads();
    for (int i = tid; i < NB * SN4P; i += 256) {
      int img = (NB == 1) ? 0 : (i / SN4P);
      int ii  = (NB == 1) ? i : (i % SN4P);
      int ciu4 = ii & 3; int t2 = ii >> 2; int c = t2 % W2; int r = t2 / W2;
      int gr = gr0 + r, gc = c - 1;
      uint4 v4 = make_uint4(0u, 0u, 0u, 0u);
      if ((unsigned)gr < (unsigned)HIN && (unsigned)gc < (unsigned)HIN) {
        v4 = src4[((size_t)((n0 + img) * HIN + gr) * HIN + gc) * (Ci / 8) + (c0 >> 3) + ciu4];
        if (BN) {
          uint* pu = (uint*)&v4;
#pragma unroll
          for (int k2 = 0; k2 < 4; ++k2) {
            int cc = c0 + ciu4 * 8 + k2 * 2;
            float f0 = fmaf(bf2f((ushort)(pu[k2] & 0xffffu)), lsc[cc], lsh[cc]);
            float f1 = fmaf(bf2f((ushort)(pu[k2] >> 16)), lsc[cc + 1], lsh[cc + 1]);
            f0 = f0 > 0.f ? f0 : 0.01f * f0;
            f1 = f1 > 0.f ? f1 : 0.01f * f1;
            pu[k2] = pk(f0, f1);
          }
        }
      }
      *(uint4*)&((uint*)lt)[((img * R_IN + r) * W2 + c) * 20 + ciu4 * 4] = v4;
    }
    __syncthreads();

#pragma unroll
    for (int t = 0; t < TAPS; ++t) {
      const int kh = (MODE == 1) ? (t >> 2) : (t >> 1);
      const int kw = (MODE == 1) ? (t & 3) : (t & 1);
      bf16x8 af[WN];
      const ushort* wb = wt + (size_t)(pb + t) * Co * Ci;
#pragma unroll
      for (int j = 0; j < WN; ++j)
        af[j] = *(const bf16x8*)&wb[(size_t)((cg0 + j) * 16 + ln15) * Ci + c0 + quad * 8];
      bf16x8 bfr[WM];
#pragma unroll
      for (int i = 0; i < WM; ++i) {
        int mtile = mt0 + i;
        int img = (NB == 1) ? 0 : (mtile / MTPI);
        int lm  = (NB == 1) ? mtile : (mtile % MTPI);
        int m = lm * 16 + ln15;
        int hr = m >> LW, wr = m & (W - 1);
        int row, col;
        if (MODE == 1) { row = 2 * hr + kh; col = 2 * wr + kw; }
        else           { row = hr + kh + ph; col = wr + kw + pw; }
        bfr[i] = *(const bf16x8*)&lt[((img * R_IN + row) * W2 + col) * 40 + quad * 8];
      }
#pragma unroll
      for (int i = 0; i < WM; ++i)
#pragma unroll
        for (int j = 0; j < WN; ++j)
          acc[i][j] = __builtin_amdgcn_mfma_f32_16x16x32_bf16(af[j], bfr[i], acc[i][j], 0, 0, 0);
    }
  }

  if (OSTAT) {
    for (int c = tid; c < COB; c += 256) { sst[c] = 0.f; ssq[c] = 0.f; }
    __syncthreads();
  }

  if (SIG) {
    // stage [3][2*TR][2*W] tile in LDS, then coalesced fp32 NCHW row writes
    constexpr int HO2 = 2 * HIN;
    constexpr int OW  = 2 * W;
    constexpr int OR  = 2 * TR;
#pragma unroll
    for (int i = 0; i < WM; ++i) {
      int m = (mt0 + i) * 16 + ln15;
      int hr = m >> LW, wr = m & (W - 1);
      int lrow = 2 * hr + ph, lcol = 2 * wr + pw;
#pragma unroll
      for (int r = 0; r < 4; ++r) {
        int co = quad * 4 + r;
        if (co < 3)
          sgb[(co * OR + lrow) * OW + lcol] = acc[i][0][r];
      }
    }
    __syncthreads();
    float* outF = (float*)out_;
    const size_t nb = (size_t)n0 * 3 * HO2 * HO2;
    for (int idx = tid; idx < 3 * OR * OW; idx += 256) {
      int col = idx & (OW - 1);
      int rem = idx / OW;
      int row = rem % OR;
      int co  = rem / OR;
      float v = sgb[(co * OR + row) * OW + col];
      outF[nb + (size_t)co * HO2 * HO2 + (size_t)(2 * h0 + row) * HO2 + col] =
          1.f / (1.f + __expf(-v));
    }
  } else {
    ushort* out = (ushort*)out_;
#pragma unroll
    for (int i = 0; i < WM; ++i) {
      int mtile = mt0 + i;
      int img = (NB == 1) ? 0 : (mtile / MTPI);
      int lm  = (NB == 1) ? mtile : (mtile % MTPI);
      int m = lm * 16 + ln15;
      int hr = m >> LW, wr = m & (W - 1);
      size_t sp;
      if (MODE == 2) {
        int oh = 2 * (h0 + hr) + ph, ow = 2 * wr + pw;
        sp = ((size_t)(n0 + img) * (2 * HIN) + oh) * (2 * HIN) + ow;
      } else {
        sp = ((size_t)(n0 + img) * W + h0 + hr) * W + wr;
      }
#pragma unroll
      for (int j = 0; j < WN; ++j) {
        f32x4 a = acc[i][j];
        uint2 stv; stv.x = pk(a[0], a[1]); stv.y = pk(a[2], a[3]);
        *(uint2*)&out[sp * Co + (cg0 + j) * 16 + quad * 4] = stv;
      }
    }
  }

  if (OSTAT) {
#pragma unroll
    for (int j = 0; j < WN; ++j)
#pragma unroll
      for (int r = 0; r < 4; ++r) {
        float s = 0.f, q = 0.f;
#pragma unroll
        for (int i = 0; i < WM; ++i) {
          float v = acc[i][j][r];
          s += v; q = fmaf(v, v, q);
        }
#pragma unroll
        for (int mk = 1; mk < 16; mk <<= 1) {
          s += __shfl_xor(s, mk);
          q += __shfl_xor(q, mk);
        }
        if (ln15 == 0) {
          int lc = (cg0 + j) * 16 + quad * 4 + r - cbase * 16;
          atomicAdd(&sst[lc], s);
          atomicAdd(&ssq[lc], q);
        }
      }
    __syncthreads();
    float* d = stOut + (size_t)(blockIdx.x & 7) * 2 * Co;
    for (int c = tid; c < COB; c += 256) {
      atomicAdd(&d[cbase * 16 + c], sst[c]);
      atomicAdd(&d[Co + cbase * 16 + c], ssq[c]);
    }
  }
}

// ===================== 1x1 conv GEMM, fused input-BN + output stats ==========
template<int Ci, int Co, int COT, bool BN, int NPIX, bool OSTAT>
__global__ __launch_bounds__(256) void g1x1(const ushort* __restrict__ in,
    const ushort* __restrict__ wt, const float* __restrict__ bias,
    const float* __restrict__ st, const float* __restrict__ g,
    const float* __restrict__ bb, ushort* __restrict__ out,
    float* __restrict__ stOut) {
  constexpr int NG = COT / 16;
  constexpr int CB = BN ? Ci : 1;
  constexpr int SB = OSTAT ? COT : 1;
  __shared__ __align__(16) ushort lb[64 * 40];
  __shared__ float lsc[CB], lsh[CB];
  __shared__ float sst[SB], ssq[SB];
  const int tid = threadIdx.x, wave = tid >> 6, ln15 = tid & 15, quad = (tid & 63) >> 4;
  const int pixBase = blockIdx.x * 64;
  const int co0 = blockIdx.y * COT;
  if (BN) {
    constexpr float inv_cnt = 1.0f / (float)NPIX;
    for (int c = tid; c < Ci; c += 256) {
      float s = 0.f, q = 0.f;
#pragma unroll
      for (int sl = 0; sl < 8; ++sl) {
        s += st[sl * 2 * Ci + c];
        q += st[sl * 2 * Ci + Ci + c];
      }
      float m = s * inv_cnt;
      float var = fmaf(q, inv_cnt, -m * m);
      float sc = g[c] * rsqrtf(var + 1e-5f);
      lsc[c] = sc;
      lsh[c] = fmaf(-m, sc, bb[c]);
    }
  }
  f32x4 acc[NG];
#pragma unroll
  for (int j = 0; j < NG; ++j) acc[j] = *(const f32x4*)&bias[co0 + j * 16 + quad * 4];
  const uint4* src4 = (const uint4*)in;
#pragma unroll 1
  for (int c0 = 0; c0 < Ci; c0 += 32) {
    __syncthreads();
    {
      int ciu4 = tid & 3, pl = tid >> 2;
      uint4 v4 = src4[(size_t)(pixBase + pl) * (Ci / 8) + (c0 >> 3) + ciu4];
      if (BN) {
        uint* pu = (uint*)&v4;
#pragma unroll
        for (int k2 = 0; k2 < 4; ++k2) {
          int cc = c0 + ciu4 * 8 + k2 * 2;
          float f0 = fmaf(bf2f((ushort)(pu[k2] & 0xffffu)), lsc[cc], lsh[cc]);
          float f1 = fmaf(bf2f((ushort)(pu[k2] >> 16)), lsc[cc + 1], lsh[cc + 1]);
          f0 = f0 > 0.f ? f0 : 0.01f * f0;
          f1 = f1 > 0.f ? f1 : 0.01f * f1;
          pu[k2] = pk(f0, f1);
        }
      }
      *(uint4*)&((uint*)lb)[pl * 20 + ciu4 * 4] = v4;
    }
    __syncthreads();
    bf16x8 bfr = *(const bf16x8*)&lb[(wave * 16 + ln15) * 40 + quad * 8];
#pragma unroll
    for (int j = 0; j < NG; ++j) {
      bf16x8 af = *(const bf16x8*)&wt[(size_t)(co0 + j * 16 + ln15) * Ci + c0 + quad * 8];
      acc[j] = __builtin_amdgcn_mfma_f32_16x16x32_bf16(af, bfr, acc[j], 0, 0, 0);
    }
  }
  if (OSTAT) {
    for (int c = tid; c < COT; c += 256) { sst[c] = 0.f; ssq[c] = 0.f; }
    __syncthreads();
  }
  int pix = pixBase + wave * 16 + ln15;
#pragma unroll
  for (int j = 0; j < NG; ++j) {
    uint2 stv; stv.x = pk(acc[j][0], acc[j][1]); stv.y = pk(acc[j][2], acc[j][3]);
    *(uint2*)&out[(size_t)pix * Co + co0 + j * 16 + quad * 4] = stv;
  }
  if (OSTAT) {
#pragma unroll
    for (int j = 0; j < NG; ++j)
#pragma unroll
      for (int r = 0; r < 4; ++r) {
        float s = acc[j][r];
        float q = s * s;
#pragma unroll
        for (int mk = 1; mk < 16; mk <<= 1) {
          s += __shfl_xor(s, mk);
          q += __shfl_xor(q, mk);
        }
        if (ln15 == 0) {
          int cl = j * 16 + quad * 4 + r;
          atomicAdd(&sst[cl], s);
          atomicAdd(&ssq[cl], q);
        }
      }
    __syncthreads();
    float* d = stOut + (size_t)(blockIdx.x & 7) * 2 * Co;
    for (int c = tid; c < COT; c += 256) {
      atomicAdd(&d[co0 + c], sst[c]);
      atomicAdd(&d[Co + co0 + c], ssq[c]);
    }
  }
}

// ===================== ce1 (MFMA): k4s2p1, Ci=3, fp32 NCHW -> bf16 NHWC + stats ===
__global__ __launch_bounds__(256) void ce1_mfma(const float* __restrict__ x,
    const ushort* __restrict__ wt, const float* __restrict__ bias,
    ushort* __restrict__ out, float* __restrict__ stOut) {
  __shared__ __align__(16) float lt[3 * 18 * 72];   // padded fp32 tile, 15.2 KB
  __shared__ float sst[32], ssq[32];
  const int tid = threadIdx.x, wave = tid >> 6, ln15 = tid & 15, quad = (tid & 63) >> 4;
  const int pixBase = blockIdx.x * 256;     // 8 out rows x 32 cols, one image
  const int n  = pixBase >> 10;
  const int h0 = (pixBase >> 5) & 31;
  if (tid < 32) { sst[tid] = 0.f; ssq[tid] = 0.f; }
  const int gr0 = 2 * h0 - 1;
  for (int i = tid; i < 3 * 18 * 72; i += 256) {
    int c = i % 72; int rem = i / 72; int r = rem % 18; int ci = rem / 18;
    int gr = gr0 + r, gc = c - 1;
    float v = 0.f;
    if ((unsigned)gr < 64u && (unsigned)gc < 64u)
      v = x[(((size_t)n * 3 + ci) << 12) + (gr << 6) + gc];
    lt[i] = v;
  }
  __syncthreads();

  f32x4 acc[4][2];
#pragma unroll
  for (int j = 0; j < 2; ++j) {
    f32x4 b4 = *(const f32x4*)&bias[j * 16 + quad * 4];
#pragma unroll
    for (int i = 0; i < 4; ++i) acc[i][j] = b4;
  }
  bf16x8 af[2][2];
#pragma unroll
  for (int j = 0; j < 2; ++j)
#pragma unroll
    for (int kk = 0; kk < 2; ++kk)
      af[j][kk] = *(const bf16x8*)&wt[(j * 16 + ln15) * 64 + kk * 32 + quad * 8];

  const int mt0 = wave * 4;
#pragma unroll
  for (int i = 0; i < 4; ++i) {
    int p = (mt0 + i) * 16 + ln15;        // px within block
    int h = p >> 5, w = p & 31;           // local out row/col
#pragma unroll
    for (int kk = 0; kk < 2; ++kk) {
      int k0 = kk * 32 + quad * 8;        // k = (ci*16 + kh*4 + kw)
      bf16x8 bfr = (bf16x8)(short)0;
      if (k0 < 48) {
        int ci = k0 >> 4, kh0 = (k0 >> 2) & 3;   // 8 k's = 2 rows x 4 kw
        const float* rp = &lt[(ci * 18 + 2 * h + kh0) * 72 + 2 * w];
        uint4 uu = make_uint4(pk(rp[0], rp[1]), pk(rp[2], rp[3]),
                              pk(rp[72], rp[73]), pk(rp[74], rp[75]));
        bfr = *reinterpret_cast<bf16x8*>(&uu);
      }
#pragma unroll
      for (int j = 0; j < 2; ++j)
        acc[i][j] = __builtin_amdgcn_mfma_f32_16x16x32_bf16(af[j][kk], bfr, acc[i][j], 0, 0, 0);
    }
  }
  // ---- store bf16 NHWC [px][32] ----
#pragma unroll
  for (int i = 0; i < 4; ++i) {
    int sp = pixBase + (mt0 + i) * 16 + ln15;
#pragma unroll
    for (int j = 0; j < 2; ++j) {
      f32x4 a = acc[i][j];
      uint2 stv; stv.x = pk(a[0], a[1]); stv.y = pk(a[2], a[3]);
      *(uint2*)&out[(size_t)sp * 32 + j * 16 + quad * 4] = stv;
    }
  }
  // ---- fused batch stats (16-lane reduce like tconv OSTAT) ----
#pragma unroll
  for (int j = 0; j < 2; ++j)
#pragma unroll
    for (int r = 0; r < 4; ++r) {
      float s = 0.f, q = 0.f;
#pragma unroll
      for (int i = 0; i < 4; ++i) {
        float v = acc[i][j][r];
        s += v; q = fmaf(v, v, q);
      }
#pragma unroll
      for (int mk = 1; mk < 16; mk <<= 1) {
        s += __shfl_xor(s, mk);
        q += __shfl_xor(q, mk);
      }
      if (ln15 == 0) {
        int ch = j * 16 + quad * 4 + r;
        atomicAdd(&sst[ch], s);
        atomicAdd(&ssq[ch], q);
      }
    }
  __syncthreads();
  if (tid < 32) {
    float* d = stOut + (size_t)(blockIdx.x & 7) * 64;
    atomicAdd(&d[tid], sst[tid]);
    atomicAdd(&d[32 + tid], ssq[tid]);
  }
}

// ===================== prep: ALL weight transforms + codebook, one dispatch ======
__device__ __forceinline__ void enc_tr(const float* __restrict__ w,
    ushort* __restrict__ o, int Co, int Ci, int idx) {
  int ci = idx % Ci; int r = idx / Ci; int co = r % Co; int t = r / Co;
  o[idx] = f2bf(w[(co * Ci + ci) * 16 + t]);
}
__device__ __forceinline__ float dec_comb(const float* __restrict__ w,
    int Ci, int co, int ci, int pt) {
  int p = pt >> 2, t = pt & 3;
  int ph = p >> 1, pw = p & 1, rr = t >> 1, cc = t & 1;
  int rs = (rr == 0) ? 0 : (ph == 0 ? 1 : 2);
  int re = (rr == 0) ? (ph == 0 ? 1 : 2) : 3;
  int cs = (cc == 0) ? 0 : (pw == 0 ? 1 : 2);
  int ce = (cc == 0) ? (pw == 0 ? 1 : 2) : 3;
  float s = 0.f;
  for (int kh = rs; kh < re; ++kh)
    for (int kw = cs; kw < ce; ++kw)
      s += w[((co * Ci + ci) * 3 + kh) * 3 + kw];
  return s;
}
__device__ __forceinline__ void dec_tr(const float* __restrict__ w,
    ushort* __restrict__ o, int Co, int Ci, int idx) {
  int ci = idx % Ci; int r = idx / Ci; int co = r % Co; int pt = r / Co;
  o[idx] = f2bf(dec_comb(w, Ci, co, ci, pt));
}

__global__ __launch_bounds__(256) void prep_all(
    const float* __restrict__ ce1_w,
    const float* __restrict__ ce2_w, const float* __restrict__ ce3_w,
    const float* __restrict__ ce4_w, const float* __restrict__ ce5_w,
    const float* __restrict__ cd0_w, const float* __restrict__ cd1_w,
    const float* __restrict__ cd2_w, const float* __restrict__ cd3_w,
    const float* __restrict__ cd4_w, const float* __restrict__ cd4_b,
    const float* __restrict__ codebook,
    ushort* __restrict__ wce1b,
    ushort* __restrict__ wce2, ushort* __restrict__ wce3, ushort* __restrict__ wce4,
    ushort* __restrict__ wce5, ushort* __restrict__ wcd0, ushort* __restrict__ wcd1,
    ushort* __restrict__ wcd2, ushort* __restrict__ wcd3, ushort* __restrict__ wcd4,
    float* __restrict__ cd4bp, ushort* __restrict__ cbbf, float* __restrict__ wsq) {
  __shared__ float sh[4];
  int bx = blockIdx.x, tid = threadIdx.x;
  if (bx < 2048) { int i = bx * 256 + tid; cbbf[i] = f2bf(codebook[i]); return; }
  bx -= 2048;
  if (bx < 512) {
    int k = bx;
    float s = 0.f;
    for (int d = tid; d < 1024; d += 256) {
      float v = codebook[k * 1024 + d];
      s = fmaf(v, v, s);
    }
#pragma unroll
    for (int o = 32; o > 0; o >>= 1) s += __shfl_down(s, o);
    if ((tid & 63) == 0) sh[tid >> 6] = s;
    __syncthreads();
    if (tid == 0) wsq[k] = sh[0] + sh[1] + sh[2] + sh[3];
    return;
  }
  bx -= 512;
  if (bx < 2048) { enc_tr(ce4_w, wce4, 256, 128, bx * 256 + tid); return; }
  bx -= 2048;
  if (bx < 2048) { dec_tr(cd1_w, wcd1, 128, 256, bx * 256 + tid); return; }
  bx -= 2048;
  if (bx < 512)  { enc_tr(ce3_w, wce3, 128, 64, bx * 256 + tid); return; }
  bx -= 512;
  if (bx < 512)  { dec_tr(cd2_w, wcd2, 64, 128, bx * 256 + tid); return; }
  bx -= 512;
  if (bx < 128)  { enc_tr(ce2_w, wce2, 64, 32, bx * 256 + tid); return; }
  bx -= 128;
  if (bx < 128)  { dec_tr(cd3_w, wcd3, 32, 64, bx * 256 + tid); return; }
  bx -= 128;
  if (bx < 64)   { int i = bx * 256 + tid; wce5[i] = f2bf(ce5_w[i]); return; }
  bx -= 64;
  if (bx < 64)   { int i = bx * 256 + tid; wcd0[i] = f2bf(cd0_w[i]); return; }
  bx -= 64;
  if (bx < 32) {                // cd4 padded: [16 taps][16 co][32 ci]
    int idx = bx * 256 + tid;   // 32 blocks
    int ci = idx & 31; int r = idx >> 5; int co = r & 15; int pt = r >> 4;
    wcd4[idx] = (co < 3) ? f2bf(dec_comb(cd4_w, 32, co, ci, pt)) : (ushort)0;
    if (bx == 0 && tid < 16) cd4bp[tid] = (tid < 3) ? cd4_b[tid] : 0.f;
    return;
  }
  bx -= 32;
  {                             // ce1 bf16 weights: [32 co][64 k], k>=48 zero; 8 blocks
    int idx = bx * 256 + tid;   // 0..2047
    int k = idx & 63, co = idx >> 6;
    wce1b[idx] = (k < 48) ? f2bf(ce1_w[co * 48 + k]) : (ushort)0;
  }
}

// ===================== VQ ==========
// vq_gemm with fused zprep: stages Z directly from r5 applying BN+LReLU
// (r5 layout [8192 px][64 ch] == Z rows [512][1024], ch = d & 63).
// Blocks with k0==0 also write fp32 Z (single writer per element).
// KS=8 K-slices -> grid (8,8,8)=512 blocks (2 blk/CU).
__global__ __launch_bounds__(256) void vq_gemm(const ushort* __restrict__ r5,
    const ushort* __restrict__ cbbf, const float* __restrict__ st,
    const float* __restrict__ g, const float* __restrict__ bb,
    float* __restrict__ Z, float* __restrict__ S) {
  __shared__ __align__(16) ushort lZ[64 * 40], lW[64 * 40];
  __shared__ float lsc[64], lsh[64];
  const int tid = threadIdx.x, wave = tid >> 6, ln15 = tid & 15, quad = (tid & 63) >> 4;
  const int b0 = blockIdx.x * 64, k0 = blockIdx.y * 64, ks = blockIdx.z;
  if (tid < 64) {
    float s = 0.f, q = 0.f;
#pragma unroll
    for (int sl = 0; sl < 8; ++sl) { s += st[sl * 128 + tid]; q += st[sl * 128 + 64 + tid]; }
    float m = s * (1.0f / 8192.f);
    float var = fmaf(q, 1.0f / 8192.f, -m * m);
    float sc = g[tid] * rsqrtf(var + 1e-5f);
    lsc[tid] = sc;
    lsh[tid] = fmaf(-m, sc, bb[tid]);
  }
  f32x4 acc[4];
#pragma unroll
  for (int j = 0; j < 4; ++j) acc[j] = (f32x4)(0.f);
  const uint4* zs = (const uint4*)r5;
  const uint4* ws = (const uint4*)cbbf;
  const bool wrZ = (blockIdx.y == 0);
#pragma unroll 1
  for (int c0 = ks * 128; c0 < ks * 128 + 128; c0 += 32) {
    __syncthreads();
    for (int i = tid; i < 512; i += 256) {
      int ciu4 = i & 3; int rl = (i >> 2) & 63; bool isW = i >= 256;
      uint4 v = (isW ? ws : zs)[(size_t)((isW ? k0 : b0) + rl) * 128 + (c0 >> 3) + ciu4];
      if (!isW) {
        uint* pu = (uint*)&v;
        float zf[8];
#pragma unroll
        for (int k2 = 0; k2 < 4; ++k2) {
          int cc = (c0 + ciu4 * 8 + k2 * 2) & 63;
          float f0 = fmaf(bf2f((ushort)(pu[k2] & 0xffffu)), lsc[cc], lsh[cc]);
          float f1 = fmaf(bf2f((ushort)(pu[k2] >> 16)), lsc[cc + 1], lsh[cc + 1]);
          f0 = f0 > 0.f ? f0 : 0.01f * f0;
          f1 = f1 > 0.f ? f1 : 0.01f * f1;
          pu[k2] = pk(f0, f1);
          zf[2 * k2] = f0; zf[2 * k2 + 1] = f1;
        }
        if (wrZ) {
          float* zp = &Z[(size_t)(b0 + rl) * 1024 + c0 + ciu4 * 8];
          *(float4*)zp       = make_float4(zf[0], zf[1], zf[2], zf[3]);
          *(float4*)(zp + 4) = make_float4(zf[4], zf[5], zf[6], zf[7]);
        }
      }
      *(uint4*)&((uint*)(isW ? lW : lZ))[rl * 20 + ciu4 * 4] = v;
    }
    __syncthreads();
    bf16x8 bfr = *(const bf16x8*)&lZ[(wave * 16 + ln15) * 40 + quad * 8];
#pragma unroll
    for (int j = 0; j < 4; ++j) {
      bf16x8 af = *(const bf16x8*)&lW[(j * 16 + ln15) * 40 + quad * 8];
      acc[j] = __builtin_amdgcn_mfma_f32_16x16x32_bf16(af, bfr, acc[j], 0, 0, 0);
    }
  }
  int b = b0 + wave * 16 + ln15;
  float* Sk = S + (size_t)ks * 262144;
#pragma unroll
  for (int j = 0; j < 4; ++j)
    *(f32x4*)&Sk[(size_t)b * 512 + k0 + j * 16 + quad * 4] = acc[j];
}

// fused: argmin scan + gather Zq + exact fp32 loss + last-block writes losses
__global__ __launch_bounds__(256) void vq_post(const float* __restrict__ S,
    const float* __restrict__ wsq, const float* __restrict__ Z,
    const float* __restrict__ cb, ushort* __restrict__ Zq,
    float* __restrict__ lossAcc, int* __restrict__ cnt, float* __restrict__ out2) {
  int b = blockIdx.x, tid = threadIdx.x;
  float s1 = 0.f, s2 = 0.f;
#pragma unroll
  for (int sl = 0; sl < 8; ++sl) {
    s1 += S[(size_t)sl * 262144 + (size_t)b * 512 + tid];
    s2 += S[(size_t)sl * 262144 + (size_t)b * 512 + tid + 256];
  }
  float d1 = fmaf(-2.f, s1, wsq[tid]);
  float d2 = fmaf(-2.f, s2, wsq[tid + 256]);
  float bv = d1; int bk = tid;
  if (d2 < bv) { bv = d2; bk = tid + 256; }
  __shared__ float vsh[256]; __shared__ int ish[256];
  vsh[tid] = bv; ish[tid] = bk;
  __syncthreads();
  for (int s = 128; s > 0; s >>= 1) {
    if (tid < s) {
      float ov = vsh[tid + s]; int oi = ish[tid + s];
      if (ov < vsh[tid] || (ov == vsh[tid] && oi < ish[tid])) { vsh[tid] = ov; ish[tid] = oi; }
    }
    __syncthreads();
  }
  int k = ish[0];
  const float* w = cb + ((long)k << 10);
  const float* zp = Z + ((long)b << 10);
  float part = 0.f;
  for (int d = tid; d < 1024; d += 256) {
    float wv = w[d];
    float diff = zp[d] - wv;
    part = fmaf(diff, diff, part);
    Zq[(b << 10) + d] = f2bf(wv);
  }
#pragma unroll
  for (int o = 32; o > 0; o >>= 1) part += __shfl_down(part, o);
  __shared__ float sh[4];
  if ((tid & 63) == 0) sh[tid >> 6] = part;
  __syncthreads();
  if (tid == 0) {
    atomicAdd(lossAcc, sh[0] + sh[1] + sh[2] + sh[3]);
    __threadfence();
    int old = atomicAdd(cnt, 1);
    if (old == 511) {
      float v = *(volatile float*)lossAcc * (1.0f / 512.0f);
      out2[0] = v;
      out2[1] = v;
    }
  }
}

// ===================== launch ==========
extern "C" void kernel_launch(void* const* d_in, const int* in_sizes, int n_in,
                              void* d_out, int out_size, void* d_ws, size_t ws_size,
                              hipStream_t stream) {
  const float* x      = (const float*)d_in[0];
  const float* ce1_w  = (const float*)d_in[1];  const float* ce1_b = (const float*)d_in[2];
  const float* ce2_w  = (const float*)d_in[3];  const float* ce2_b = (const float*)d_in[4];
  const float* ce3_w  = (const float*)d_in[5];  const float* ce3_b = (const float*)d_in[6];
  const float* ce4_w  = (const float*)d_in[7];  const float* ce4_b = (const float*)d_in[8];
  const float* ce5_w  = (const float*)d_in[9];  const float* ce5_b = (const float*)d_in[10];
  const float* cd0_w  = (const float*)d_in[11]; const float* cd0_b = (const float*)d_in[12];
  const float* cd1_w  = (const float*)d_in[13]; const float* cd1_b = (const float*)d_in[14];
  const float* cd2_w  = (const float*)d_in[15]; const float* cd2_b = (const float*)d_in[16];
  const float* cd3_w  = (const float*)d_in[17]; const float* cd3_b = (const float*)d_in[18];
  const float* cd4_w  = (const float*)d_in[19]; const float* cd4_b = (const float*)d_in[20];
  const float* bn_e1_g = (const float*)d_in[21]; const float* bn_e1_b = (const float*)d_in[22];
  const float* bn_e2_g = (const float*)d_in[23]; const float* bn_e2_b = (const float*)d_in[24];
  const float* bn_e3_g = (const float*)d_in[25]; const float* bn_e3_b = (const float*)d_in[26];
  const float* bn_e4_g = (const float*)d_in[27]; const float* bn_e4_b = (const float*)d_in[28];
  const float* bn_e5_g = (const float*)d_in[29]; const float* bn_e5_b = (const float*)d_in[30];
  const float* bn_d0_g = (const float*)d_in[31]; const float* bn_d0_b = (const float*)d_in[32];
  const float* bn_d1_g = (const float*)d_in[33]; const float* bn_d1_b = (const float*)d_in[34];
  const float* bn_d2_g = (const float*)d_in[35]; const float* bn_d2_b = (const float*)d_in[36];
  const float* bn_d3_g = (const float*)d_in[37]; const float* bn_d3_b = (const float*)d_in[38];
  const float* codebook = (const float*)d_in[39];

  float* out = (float*)d_out;

  // ---- workspace carve ----
  char* p = (char*)d_ws;
  auto alloc = [&](size_t bytes) { void* r = p; p += (bytes + 255) & ~(size_t)255; return r; };
  ushort* r1 = (ushort*)alloc((size_t)524288 * 32 * 2);
  ushort* r2 = (ushort*)alloc((size_t)131072 * 64 * 2);
  ushort* r3 = (ushort*)alloc((size_t)32768 * 128 * 2);
  ushort* r4 = (ushort*)alloc((size_t)8192 * 256 * 2);
  ushort* r5 = (ushort*)alloc((size_t)8192 * 64 * 2);
  ushort* d0 = (ushort*)alloc((size_t)8192 * 256 * 2);
  ushort* d1 = (ushort*)alloc((size_t)32768 * 128 * 2);
  ushort* d2 = (ushort*)alloc((size_t)131072 * 64 * 2);
  ushort* d3 = (ushort*)alloc((size_t)524288 * 32 * 2);
  float*  Z    = (float*)alloc((size_t)524288 * 4);
  ushort* cbbf = (ushort*)alloc((size_t)524288 * 2);
  float*  S    = (float*)alloc((size_t)8 * 262144 * 4);   // 8 K-slices
  ushort* Zq   = (ushort*)alloc((size_t)524288 * 2);
  float*  wsq  = (float*)alloc((size_t)512 * 4);
  ushort* wce2 = (ushort*)alloc((size_t)16 * 64 * 32 * 2);
  ushort* wce3 = (ushort*)alloc((size_t)16 * 128 * 64 * 2);
  ushort* wce4 = (ushort*)alloc((size_t)16 * 256 * 128 * 2);
  ushort* wce5 = (ushort*)alloc((size_t)64 * 256 * 2);
  ushort* wcd0 = (ushort*)alloc((size_t)256 * 64 * 2);
  ushort* wcd1 = (ushort*)alloc((size_t)16 * 128 * 256 * 2);
  ushort* wcd2 = (ushort*)alloc((size_t)16 * 64 * 128 * 2);
  ushort* wcd3 = (ushort*)alloc((size_t)16 * 32 * 64 * 2);
  ushort* wcd4 = (ushort*)alloc((size_t)16 * 16 * 32 * 2);
  ushort* wce1b = (ushort*)alloc((size_t)32 * 64 * 2);
  float*  cd4bp = (float*)alloc(64);
  float*  statsAll = (float*)alloc((size_t)(9 * 4096 + 64) * 4);
  int*    jbuf = (int*)alloc((size_t)512 * 4);

  float* st_e1 = statsAll + 0 * 4096;
  float* st_e2 = statsAll + 1 * 4096;
  float* st_e3 = statsAll + 2 * 4096;
  float* st_e4 = statsAll + 3 * 4096;
  float* st_e5 = statsAll + 4 * 4096;
  float* st_d0 = statsAll + 5 * 4096;
  float* st_d1 = statsAll + 6 * 4096;
  float* st_d2 = statsAll + 7 * 4096;
  float* st_d3 = statsAll + 8 * 4096;
  float* lossAcc = statsAll + 9 * 4096;
  int*   cnt = (int*)(lossAcc + 1);

  hipMemsetAsync(statsAll, 0, (size_t)(9 * 4096 + 64) * 4, stream);

  prep_all<<<8104, 256, 0, stream>>>(ce1_w, ce2_w, ce3_w, ce4_w, ce5_w, cd0_w, cd1_w,
      cd2_w, cd3_w, cd4_w, cd4_b, codebook,
      wce1b, wce2, wce3, wce4, wce5, wcd0, wcd1, wcd2, wcd3, wcd4, cd4bp, cbbf, wsq);

  // ---- encoder ----
  ce1_mfma<<<2048, 256, 0, stream>>>(x, wce1b, ce1_b, r1, st_e1);
  tconv<1, 32, 64, 32, 8, 4, 2, 1, 1, true, true, false><<<dim3(1024, 1), 256, 0, stream>>>(
      r1, wce2, ce2_b, st_e1, bn_e1_g, bn_e1_b, r2, st_e2);
  tconv<1, 64, 128, 16, 8, 4, 2, 1, 1, true, true, false><<<dim3(512, 1), 256, 0, stream>>>(
      r2, wce3, ce3_b, st_e2, bn_e2_g, bn_e2_b, r3, st_e3);
  tconv<1, 128, 256, 8, 4, 4, 1, 4, 4, true, true, false><<<dim3(128, 4), 256, 0, stream>>>(
      r3, wce4, ce4_b, st_e3, bn_e3_g, bn_e3_b, r4, st_e4);
  g1x1<256, 64, 16, true, 8192, true><<<dim3(128, 4), 256, 0, stream>>>(
      r4, wce5, ce5_b, st_e4, bn_e4_g, bn_e4_b, r5, st_e5);

  // ---- VQ (zprep fused into vq_gemm; 8 K-slices for 2 blk/CU) ----
  vq_gemm<<<dim3(8, 8, 8), 256, 0, stream>>>(r5, cbbf, st_e5, bn_e5_g, bn_e5_b, Z, S);
  vq_post<<<512, 256, 0, stream>>>(S, wsq, Z, codebook, Zq, lossAcc, cnt, out + 6291456);

  // ---- decoder ----
  g1x1<64, 256, 32, false, 1, true><<<dim3(128, 8), 256, 0, stream>>>(
      Zq, wcd0, cd0_b, nullptr, nullptr, nullptr, d0, st_d0);
  tconv<2, 256, 128, 4, 4, 4, 2, 4, 4, true, true, false><<<dim3(128, 4), 256, 0, stream>>>(
      d0, wcd1, cd1_b, st_d0, bn_d0_g, bn_d0_b, d1, st_d1);
  tconv<2, 128, 64, 8, 8, 4, 4, 1, 1, true, true, false><<<dim3(512, 1), 256, 0, stream>>>(
      d1, wcd2, cd2_b, st_d1, bn_d1_g, bn_d1_b, d2, st_d2);
  tconv<2, 64, 32, 16, 8, 8, 2, 1, 1, true, true, false><<<dim3(1024, 1), 256, 0, stream>>>(
      d2, wcd3, cd3_b, st_d2, bn_d2_g, bn_d2_b, d3, st_d3);
  tconv<2, 32, 16, 32, 4, 8, 1, 1, 1, true, false, true><<<dim3(4096, 1), 256, 0, stream>>>(
      d3, wcd4, cd4bp, st_d3, bn_d3_g, bn_d3_b, out, nullptr);
}